// Round 1
// baseline (7935.299 us; speedup 1.0000x reference)
//
#include <hip/hip_runtime.h>
#include <hip/hip_bf16.h>
#include <math.h>

#define B_EP 256
#define NT 175
#define NWAYS 20
#define KSHOT 5
#define NKS 100          // N_WAYS * N_SHOTS
#define NQ 75
#define DIM 512
#define NLAYERS 4
#define TAU_INV 10.0f
#define LOGIT_SCALE 5.0f
#define KNEI 5

__device__ __forceinline__ float waveReduceSum(float v) {
#pragma unroll
  for (int off = 32; off >= 1; off >>= 1) v += __shfl_xor(v, off);
  return v;
}

__global__ void init_accum_kernel(float* acc) {
  if (threadIdx.x < 16) acc[threadIdx.x] = 0.f;
}

// l2-normalize each row of `in` (rows x 512), write to out and out0.
__global__ void l2n_init_kernel(const float* __restrict__ in,
                                float* __restrict__ out,
                                float* __restrict__ out0) {
  const size_t row = blockIdx.x;
  const int lane = threadIdx.x;
  const float* src = in + row * DIM;
  float x[8];
  float ss = 0.f;
#pragma unroll
  for (int t = 0; t < 8; ++t) {
    float y = src[lane + 64 * t];
    x[t] = y;
    ss += y * y;
  }
  ss = waveReduceSum(ss);
  const float inv = 1.f / fmaxf(sqrtf(ss), 1e-12f);
#pragma unroll
  for (int t = 0; t < 8; ++t) {
    float y = x[t] * inv;
    out[row * DIM + lane + 64 * t] = y;
    out0[row * DIM + lane + 64 * t] = y;
  }
}

// SIM[b,i,j] = dot(V[b,i], V[b,j]) — tiled 32x32, guards at 175.
__global__ __launch_bounds__(256) void sim_kernel(const float* __restrict__ V,
                                                  float* __restrict__ SIM) {
  const int b = blockIdx.z;
  const int it = blockIdx.y, jt = blockIdx.x;
  const int tid = threadIdx.x;
  const int tx = tid & 31, ty = tid >> 5;  // ty 0..7
  __shared__ float As[32][33];
  __shared__ float Bs[32][33];
  const float* Vb = V + (size_t)b * NT * DIM;
  float acc[4] = {0.f, 0.f, 0.f, 0.f};
  for (int kc = 0; kc < DIM; kc += 32) {
#pragma unroll
    for (int s = 0; s < 4; ++s) {
      int r = it * 32 + ty + 8 * s;
      As[ty + 8 * s][tx] = (r < NT) ? Vb[(size_t)r * DIM + kc + tx] : 0.f;
      int c = jt * 32 + ty + 8 * s;
      Bs[ty + 8 * s][tx] = (c < NT) ? Vb[(size_t)c * DIM + kc + tx] : 0.f;
    }
    __syncthreads();
#pragma unroll
    for (int k = 0; k < 32; ++k) {
      float bv = Bs[tx][k];
#pragma unroll
      for (int s = 0; s < 4; ++s) acc[s] += As[ty + 8 * s][k] * bv;
    }
    __syncthreads();
  }
#pragma unroll
  for (int s = 0; s < 4; ++s) {
    int r = it * 32 + ty + 8 * s, c = jt * 32 + tx;
    if (r < NT && c < NT) SIM[((size_t)b * NT + r) * NT + c] = acc[s];
  }
}

// Per (b,i): top-5 of SIM row (jax tie-break: lower index), softmax/tau,
// MSG[b,i,:] = sum_k w_k * V[b, idx_k, :]
__global__ void topk_msg_kernel(const float* __restrict__ SIM,
                                const float* __restrict__ V,
                                float* __restrict__ MSG) {
  const int row = blockIdx.x;  // b*NT + i
  const int b = row / NT;
  const int lane = threadIdx.x;
  const float* srow = SIM + (size_t)row * NT;
  float sv[3];
  int si[3];
#pragma unroll
  for (int t = 0; t < 3; ++t) {
    int j = lane + 64 * t;
    sv[t] = (j < NT) ? srow[j] : -INFINITY;
    si[t] = j;
  }
  float topv[KNEI];
  int topi[KNEI];
#pragma unroll
  for (int t = 0; t < KNEI; ++t) {
    float bv = sv[0];
    int bi = si[0];
    if (sv[1] > bv) { bv = sv[1]; bi = si[1]; }
    if (sv[2] > bv) { bv = sv[2]; bi = si[2]; }
#pragma unroll
    for (int off = 32; off >= 1; off >>= 1) {
      float ov = __shfl_xor(bv, off);
      int oi = __shfl_xor(bi, off);
      if (ov > bv || (ov == bv && oi < bi)) { bv = ov; bi = oi; }
    }
    topv[t] = bv;
    topi[t] = bi;
#pragma unroll
    for (int u = 0; u < 3; ++u)
      if (si[u] == bi) sv[u] = -INFINITY;
  }
  float w[KNEI];
  float wsum = 0.f;
#pragma unroll
  for (int t = 0; t < KNEI; ++t) {
    w[t] = expf((topv[t] - topv[0]) * TAU_INV);
    wsum += w[t];
  }
  const float invs = 1.f / wsum;
  const float* Vb = V + (size_t)b * NT * DIM;
  float* mrow = MSG + (size_t)row * DIM;
#pragma unroll
  for (int t8 = 0; t8 < 8; ++t8) {
    int d = lane + 64 * t8;
    float a = 0.f;
#pragma unroll
    for (int t = 0; t < KNEI; ++t) a += w[t] * Vb[(size_t)topi[t] * DIM + d];
    mrow[d] = a * invs;
  }
}

// Vio[r,c] += scale * tanh( dot(A[r,:], W[c,:]) + bias[c] )
// 64x64 tile, 256 threads, 4x4 micro-tile. rows must be multiple of 64.
__global__ __launch_bounds__(256) void gemm_tanh_res_kernel(
    const float* __restrict__ A, const float* __restrict__ W,
    const float* __restrict__ bias, const float* __restrict__ scale_ptr,
    float* __restrict__ Vio) {
  const int mt = blockIdx.x, nt = blockIdx.y;
  const int tid = threadIdx.x;
  const int tx = tid & 15, ty = tid >> 4;
  __shared__ float As[32][65];
  __shared__ float Bs[32][65];
  float acc[4][4] = {{0.f}};
  const int row0 = mt * 64, col0 = nt * 64;
  for (int kc = 0; kc < DIM; kc += 32) {
#pragma unroll
    for (int e = 0; e < 8; ++e) {
      int lin = tid + 256 * e;
      int k = lin & 31, m = lin >> 5;
      As[k][m] = A[(size_t)(row0 + m) * DIM + kc + k];
      Bs[k][m] = W[(size_t)(col0 + m) * DIM + kc + k];
    }
    __syncthreads();
#pragma unroll
    for (int k = 0; k < 32; ++k) {
      float av[4], bv[4];
#pragma unroll
      for (int u = 0; u < 4; ++u) {
        av[u] = As[k][ty * 4 + u];
        bv[u] = Bs[k][tx * 4 + u];
      }
#pragma unroll
      for (int u = 0; u < 4; ++u)
#pragma unroll
        for (int v = 0; v < 4; ++v) acc[u][v] += av[u] * bv[v];
    }
    __syncthreads();
  }
  const float s = *scale_ptr;
#pragma unroll
  for (int u = 0; u < 4; ++u) {
    const int r = row0 + ty * 4 + u;
#pragma unroll
    for (int v = 0; v < 4; ++v) {
      const int c = col0 + tx * 4 + v;
      const size_t off = (size_t)r * DIM + c;
      Vio[off] = Vio[off] + s * tanhf(acc[u][v] + bias[c]);
    }
  }
}

// Vio = l2n(0.8*Vio + 0.2*V0)
__global__ void resid_l2n_kernel(float* __restrict__ Vio,
                                 const float* __restrict__ V0) {
  const size_t row = blockIdx.x;
  const int lane = threadIdx.x;
  float* v = Vio + row * DIM;
  const float* v0 = V0 + row * DIM;
  float x[8];
  float ss = 0.f;
#pragma unroll
  for (int t = 0; t < 8; ++t) {
    int d = lane + 64 * t;
    float y = 0.8f * v[d] + 0.2f * v0[d];
    x[t] = y;
    ss += y * y;
  }
  ss = waveReduceSum(ss);
  const float inv = 1.f / fmaxf(sqrtf(ss), 1e-12f);
#pragma unroll
  for (int t = 0; t < 8; ++t) v[lane + 64 * t] = x[t] * inv;
}

// Prototype branch adjacency + message (20 nodes, fused, no SIM buffer).
__global__ void p_adj_msg_kernel(const float* __restrict__ P,
                                 float* __restrict__ PMSG) {
  const int row = blockIdx.x;  // b*NWAYS + n
  const int b = row / NWAYS;
  const int lane = threadIdx.x;
  const float* Pb = P + (size_t)b * NWAYS * DIM;
  const float* q = P + (size_t)row * DIM;
  float qv[8];
#pragma unroll
  for (int t = 0; t < 8; ++t) qv[t] = q[lane + 64 * t];
  float sims[NWAYS];
#pragma unroll
  for (int m = 0; m < NWAYS; ++m) {
    const float* pm = Pb + (size_t)m * DIM;
    float p = 0.f;
#pragma unroll
    for (int t = 0; t < 8; ++t) p += qv[t] * pm[lane + 64 * t];
    sims[m] = waveReduceSum(p);
  }
  float topv[KNEI];
  int topi[KNEI];
  bool used[NWAYS];
#pragma unroll
  for (int m = 0; m < NWAYS; ++m) used[m] = false;
#pragma unroll
  for (int t = 0; t < KNEI; ++t) {
    float bv = -INFINITY;
    int bi = 0;
#pragma unroll
    for (int m = 0; m < NWAYS; ++m)
      if (!used[m] && sims[m] > bv) { bv = sims[m]; bi = m; }
    used[bi] = true;
    topv[t] = bv;
    topi[t] = bi;
  }
  float w[KNEI];
  float wsum = 0.f;
#pragma unroll
  for (int t = 0; t < KNEI; ++t) {
    w[t] = expf((topv[t] - topv[0]) * TAU_INV);
    wsum += w[t];
  }
  const float invs = 1.f / wsum;
  float* mrow = PMSG + (size_t)row * DIM;
#pragma unroll
  for (int t8 = 0; t8 < 8; ++t8) {
    int d = lane + 64 * t8;
    float a = 0.f;
#pragma unroll
    for (int t = 0; t < KNEI; ++t) a += w[t] * Pb[(size_t)topi[t] * DIM + d];
    mrow[d] = a * invs;
  }
}

// VC[b,n] = l2n(mean_k V[b, n*5+k])
__global__ void vc_kernel(const float* __restrict__ V, float* __restrict__ VC) {
  const int row = blockIdx.x;  // b*NWAYS + n
  const int b = row / NWAYS, n = row - b * NWAYS;
  const int lane = threadIdx.x;
  const float* base = V + ((size_t)b * NT + (size_t)n * KSHOT) * DIM;
  float x[8];
  float ss = 0.f;
#pragma unroll
  for (int t = 0; t < 8; ++t) {
    int d = lane + 64 * t;
    float a = 0.f;
#pragma unroll
    for (int k = 0; k < KSHOT; ++k) a += base[(size_t)k * DIM + d];
    a *= 0.2f;
    x[t] = a;
    ss += a * a;
  }
  ss = waveReduceSum(ss);
  const float inv = 1.f / fmaxf(sqrtf(ss), 1e-12f);
#pragma unroll
  for (int t = 0; t < 8; ++t) VC[(size_t)row * DIM + lane + 64 * t] = x[t] * inv;
}

// Pa = l2n(alpha*P + (1-alpha)*VC)
__global__ void pa_kernel(const float* __restrict__ P,
                          const float* __restrict__ VC,
                          const float* __restrict__ alpha_ptr,
                          float* __restrict__ Pa) {
  const size_t row = blockIdx.x;
  const int lane = threadIdx.x;
  const float alpha = *alpha_ptr;
  float x[8];
  float ss = 0.f;
#pragma unroll
  for (int t = 0; t < 8; ++t) {
    size_t off = row * DIM + lane + 64 * t;
    float y = alpha * P[off] + (1.f - alpha) * VC[off];
    x[t] = y;
    ss += y * y;
  }
  ss = waveReduceSum(ss);
  const float inv = 1.f / fmaxf(sqrtf(ss), 1e-12f);
#pragma unroll
  for (int t = 0; t < 8; ++t) Pa[row * DIM + lane + 64 * t] = x[t] * inv;
}

// Per (b,i): softmax-guided update of V; for query rows also logits + CE (+acc).
__global__ void guide_kernel(float* __restrict__ V, const float* __restrict__ Pa,
                             const int* __restrict__ qy,
                             const float* __restrict__ beta_ptr,
                             float* __restrict__ accum, int is_last) {
  const int row = blockIdx.x;  // b*NT + i
  const int b = row / NT, i = row - b * NT;
  const int lane = threadIdx.x;
  const float* PaB = Pa + (size_t)b * NWAYS * DIM;
  float* vrow = V + (size_t)row * DIM;
  float qv[8];
#pragma unroll
  for (int t = 0; t < 8; ++t) qv[t] = vrow[lane + 64 * t];
  float w[NWAYS];
  float mx = -INFINITY;
#pragma unroll
  for (int m = 0; m < NWAYS; ++m) {
    const float* pm = PaB + (size_t)m * DIM;
    float p = 0.f;
#pragma unroll
    for (int t = 0; t < 8; ++t) p += qv[t] * pm[lane + 64 * t];
    p = waveReduceSum(p);
    w[m] = p;
    mx = fmaxf(mx, p);
  }
  float wsum = 0.f;
#pragma unroll
  for (int m = 0; m < NWAYS; ++m) {
    w[m] = expf((w[m] - mx) * TAU_INV);
    wsum += w[m];
  }
  const float invs = 1.f / wsum;
  const float beta = *beta_ptr;
  float nv[8];
  float ss = 0.f;
#pragma unroll
  for (int t = 0; t < 8; ++t) {
    int d = lane + 64 * t;
    float g = 0.f;
#pragma unroll
    for (int m = 0; m < NWAYS; ++m) g += w[m] * PaB[(size_t)m * DIM + d];
    float y = beta * qv[t] + (1.f - beta) * g * invs;
    nv[t] = y;
    ss += y * y;
  }
  ss = waveReduceSum(ss);
  const float inv = 1.f / fmaxf(sqrtf(ss), 1e-12f);
#pragma unroll
  for (int t = 0; t < 8; ++t) {
    nv[t] *= inv;
    vrow[lane + 64 * t] = nv[t];
  }
  if (i >= NKS) {
    float lg[NWAYS];
#pragma unroll
    for (int m = 0; m < NWAYS; ++m) {
      const float* pm = PaB + (size_t)m * DIM;
      float p = 0.f;
#pragma unroll
      for (int t = 0; t < 8; ++t) p += nv[t] * pm[lane + 64 * t];
      lg[m] = LOGIT_SCALE * waveReduceSum(p);
    }
    if (lane == 0) {
      const int y = qy[b * NQ + (i - NKS)];
      float m2 = lg[0];
      int am = 0;
#pragma unroll
      for (int m = 1; m < NWAYS; ++m)
        if (lg[m] > m2) { m2 = lg[m]; am = m; }
      float se = 0.f;
#pragma unroll
      for (int m = 0; m < NWAYS; ++m) se += expf(lg[m] - m2);
      const float ce = m2 + logf(se) - lg[y];
      atomicAdd(&accum[0], ce);
      if (is_last) atomicAdd(&accum[1], (am == y) ? 1.f : 0.f);
    }
  }
}

__global__ void finalize_kernel(const float* __restrict__ acc,
                                float* __restrict__ out) {
  out[0] = acc[0] / (float)(NLAYERS * B_EP * NQ);
  out[1] = acc[1] / (float)(B_EP * NQ);
}

extern "C" void kernel_launch(void* const* d_in, const int* in_sizes, int n_in,
                              void* d_out, int out_size, void* d_ws,
                              size_t ws_size, hipStream_t stream) {
  const float* V_feat = (const float*)d_in[0];
  const float* P_feat = (const float*)d_in[1];
  const int* query_y = (const int*)d_in[2];
  const float* igb_W = (const float*)d_in[3];
  const float* igb_b = (const float*)d_in[4];
  const float* igb_s = (const float*)d_in[5];
  const float* pgb_W = (const float*)d_in[6];
  const float* pgb_b = (const float*)d_in[7];
  const float* pgb_s = (const float*)d_in[8];
  const float* alpha = (const float*)d_in[9];
  const float* beta = (const float*)d_in[10];
  float* out = (float*)d_out;

  float* ws = (float*)d_ws;
  const size_t vsz = (size_t)B_EP * NT * DIM;
  const size_t psz = (size_t)B_EP * NWAYS * DIM;
  const size_t ssz = (size_t)B_EP * NT * NT;
  float* ACC = ws;
  float* V = ws + 16;
  float* V0 = V + vsz;
  float* MSG = V0 + vsz;
  float* SIM = MSG + vsz;
  float* P = SIM + ssz;
  float* P0 = P + psz;
  float* PMSG = P0 + psz;
  float* VC = PMSG + psz;
  float* PA = VC + psz;

  init_accum_kernel<<<1, 64, 0, stream>>>(ACC);
  l2n_init_kernel<<<B_EP * NT, 64, 0, stream>>>(V_feat, V, V0);
  l2n_init_kernel<<<B_EP * NWAYS, 64, 0, stream>>>(P_feat, P, P0);

  for (int i = 0; i < NLAYERS; ++i) {
    sim_kernel<<<dim3(6, 6, B_EP), 256, 0, stream>>>(V, SIM);
    topk_msg_kernel<<<B_EP * NT, 64, 0, stream>>>(SIM, V, MSG);
    gemm_tanh_res_kernel<<<dim3(B_EP * NT / 64, 8), 256, 0, stream>>>(
        MSG, igb_W + (size_t)i * DIM * DIM, igb_b + (size_t)i * DIM, igb_s + i, V);
    resid_l2n_kernel<<<B_EP * NT, 64, 0, stream>>>(V, V0);

    p_adj_msg_kernel<<<B_EP * NWAYS, 64, 0, stream>>>(P, PMSG);
    gemm_tanh_res_kernel<<<dim3(B_EP * NWAYS / 64, 8), 256, 0, stream>>>(
        PMSG, pgb_W + (size_t)i * DIM * DIM, pgb_b + (size_t)i * DIM, pgb_s + i, P);
    resid_l2n_kernel<<<B_EP * NWAYS, 64, 0, stream>>>(P, P0);

    vc_kernel<<<B_EP * NWAYS, 64, 0, stream>>>(V, VC);
    pa_kernel<<<B_EP * NWAYS, 64, 0, stream>>>(P, VC, alpha, PA);
    guide_kernel<<<B_EP * NT, 64, 0, stream>>>(V, PA, query_y, beta, ACC,
                                               (i == NLAYERS - 1) ? 1 : 0);
  }
  finalize_kernel<<<1, 1, 0, stream>>>(ACC, out);
}

// Round 2
// 4051.389 us; speedup vs baseline: 1.9587x; 1.9587x over previous
//
#include <hip/hip_runtime.h>
#include <math.h>

#define B_EP 256
#define NT 175
#define NWAYS 20
#define KSHOT 5
#define NKS 100          // N_WAYS * N_SHOTS
#define NQ 75
#define DIM 512
#define NLAYERS 4
#define TAU_INV 10.0f
#define LOGIT_SCALE 5.0f
#define KNEI 5

typedef unsigned int u32;
typedef unsigned short u16;
typedef __attribute__((ext_vector_type(8))) short s16x8;   // 8 bf16 in 4 VGPRs
typedef __attribute__((ext_vector_type(4))) float f32x4;

__device__ __forceinline__ float waveReduceSum(float v) {
#pragma unroll
  for (int off = 32; off >= 1; off >>= 1) v += __shfl_xor(v, off);
  return v;
}

__device__ __forceinline__ u32 pack2bf(float a, float b) {
  u32 ua = __float_as_uint(a), ub = __float_as_uint(b);
  ua = (ua + 0x7FFFu + ((ua >> 16) & 1u)) >> 16;
  ub = (ub + 0x7FFFu + ((ub >> 16) & 1u)) >> 16;
  return ua | (ub << 16);
}

__device__ __forceinline__ float tanh_fast(float x) {
  float e = __expf(2.f * x);
  return 1.f - 2.f * __builtin_amdgcn_rcpf(e + 1.f);
}

__device__ __forceinline__ s16x8 ldfrag(const u16* p) {
  return __builtin_bit_cast(s16x8, *(const uint4*)p);
}

__global__ void init_accum_kernel(float* acc) {
  if (threadIdx.x < 16) acc[threadIdx.x] = 0.f;
}

// f32 -> bf16 (RNE), 8 elems/thread
__global__ void cvt_bf16_kernel(const float* __restrict__ in,
                                u16* __restrict__ out, int n8) {
  int t = blockIdx.x * 256 + threadIdx.x;
  if (t >= n8) return;
  const float4* p = (const float4*)(in + (size_t)t * 8);
  float4 a = p[0], b = p[1];
  uint4 r;
  r.x = pack2bf(a.x, a.y);
  r.y = pack2bf(a.z, a.w);
  r.z = pack2bf(b.x, b.y);
  r.w = pack2bf(b.z, b.w);
  *(uint4*)(out + (size_t)t * 8) = r;
}

// l2-normalize rows (512 wide), vectorized
__global__ void l2n_init_kernel(const float* __restrict__ in,
                                float* __restrict__ out,
                                float* __restrict__ out0) {
  const size_t row = blockIdx.x;
  const int lane = threadIdx.x;
  const float* src = in + row * DIM;
  float4 a = *(const float4*)(src + 4 * lane);
  float4 b = *(const float4*)(src + 256 + 4 * lane);
  float ss = a.x * a.x + a.y * a.y + a.z * a.z + a.w * a.w +
             b.x * b.x + b.y * b.y + b.z * b.z + b.w * b.w;
  ss = waveReduceSum(ss);
  const float inv = 1.f / fmaxf(sqrtf(ss), 1e-12f);
  a.x *= inv; a.y *= inv; a.z *= inv; a.w *= inv;
  b.x *= inv; b.y *= inv; b.z *= inv; b.w *= inv;
  *(float4*)(out + row * DIM + 4 * lane) = a;
  *(float4*)(out + row * DIM + 256 + 4 * lane) = b;
  *(float4*)(out0 + row * DIM + 4 * lane) = a;
  *(float4*)(out0 + row * DIM + 256 + 4 * lane) = b;
}

// SIM = V·V^T per episode via bf16 MFMA, 64x64 tile per 1-wave block.
__global__ __launch_bounds__(64) void sim_mfma_kernel(
    const u16* __restrict__ VB, float* __restrict__ SIM) {
  const int b = blockIdx.z, it = blockIdx.y, jt = blockIdx.x;
  const int lane = threadIdx.x;
  __shared__ __align__(16) u16 As[64][32];
  __shared__ __align__(16) u16 Bs[64][32];
  const u16* Vb = VB + (size_t)b * NT * DIM;
  f32x4 acc[4][4];
#pragma unroll
  for (int m = 0; m < 4; ++m)
#pragma unroll
    for (int n = 0; n < 4; ++n) acc[m][n] = (f32x4){0.f, 0.f, 0.f, 0.f};
  const int ra = it * 64 + lane, rb = jt * 64 + lane;
  for (int kk = 0; kk < DIM; kk += 32) {
    if (ra < NT) {
      const uint4* g = (const uint4*)(Vb + (size_t)ra * DIM + kk);
#pragma unroll
      for (int q = 0; q < 4; ++q) *(uint4*)&As[lane][8 * q] = g[q];
    } else {
      uint4 z = {0, 0, 0, 0};
#pragma unroll
      for (int q = 0; q < 4; ++q) *(uint4*)&As[lane][8 * q] = z;
    }
    if (rb < NT) {
      const uint4* g = (const uint4*)(Vb + (size_t)rb * DIM + kk);
#pragma unroll
      for (int q = 0; q < 4; ++q) *(uint4*)&Bs[lane][8 * q] = g[q];
    } else {
      uint4 z = {0, 0, 0, 0};
#pragma unroll
      for (int q = 0; q < 4; ++q) *(uint4*)&Bs[lane][8 * q] = z;
    }
    __syncthreads();
    s16x8 fa[4], fb[4];
#pragma unroll
    for (int m = 0; m < 4; ++m)
      fa[m] = ldfrag(&As[m * 16 + (lane & 15)][(lane >> 4) * 8]);
#pragma unroll
    for (int n = 0; n < 4; ++n)
      fb[n] = ldfrag(&Bs[n * 16 + (lane & 15)][(lane >> 4) * 8]);
#pragma unroll
    for (int m = 0; m < 4; ++m)
#pragma unroll
      for (int n = 0; n < 4; ++n)
        acc[m][n] = __builtin_amdgcn_mfma_f32_16x16x32_bf16(fa[m], fb[n],
                                                            acc[m][n], 0, 0, 0);
    __syncthreads();
  }
  const int r_ = (lane >> 4) * 4, c_ = lane & 15;
#pragma unroll
  for (int m = 0; m < 4; ++m)
#pragma unroll
    for (int n = 0; n < 4; ++n)
#pragma unroll
      for (int j = 0; j < 4; ++j) {
        int r = it * 64 + m * 16 + r_ + j, c = jt * 64 + n * 16 + c_;
        if (r < NT && c < NT) SIM[((size_t)b * NT + r) * NT + c] = acc[m][n][j];
      }
}

// Per (b,i): top-5 of SIM row, softmax/tau, MSGB[b,i,:] = sum w_k*V[idx_k] (bf16)
__global__ void topk_msg_kernel(const float* __restrict__ SIM,
                                const float* __restrict__ V,
                                u16* __restrict__ MSGB) {
  const int row = blockIdx.x;  // b*NT + i
  const int b = row / NT;
  const int lane = threadIdx.x;
  const float* srow = SIM + (size_t)row * NT;
  float sv[3];
  int si[3];
#pragma unroll
  for (int t = 0; t < 3; ++t) {
    int j = lane + 64 * t;
    sv[t] = (j < NT) ? srow[j] : -INFINITY;
    si[t] = j;
  }
  float topv[KNEI];
  int topi[KNEI];
#pragma unroll
  for (int t = 0; t < KNEI; ++t) {
    float bv = sv[0];
    int bi = si[0];
    if (sv[1] > bv) { bv = sv[1]; bi = si[1]; }
    if (sv[2] > bv) { bv = sv[2]; bi = si[2]; }
#pragma unroll
    for (int off = 32; off >= 1; off >>= 1) {
      float ov = __shfl_xor(bv, off);
      int oi = __shfl_xor(bi, off);
      if (ov > bv || (ov == bv && oi < bi)) { bv = ov; bi = oi; }
    }
    topv[t] = bv;
    topi[t] = bi;
#pragma unroll
    for (int u = 0; u < 3; ++u)
      if (si[u] == bi) sv[u] = -INFINITY;
  }
  float w[KNEI];
  float wsum = 0.f;
#pragma unroll
  for (int t = 0; t < KNEI; ++t) {
    w[t] = expf((topv[t] - topv[0]) * TAU_INV);
    wsum += w[t];
  }
  const float invs = 1.f / wsum;
  const float* Vb = V + (size_t)b * NT * DIM;
  float a8[8] = {0.f, 0.f, 0.f, 0.f, 0.f, 0.f, 0.f, 0.f};
#pragma unroll
  for (int t = 0; t < KNEI; ++t) {
    const float4* pp = (const float4*)(Vb + (size_t)topi[t] * DIM + 8 * lane);
    float4 x0 = pp[0], x1 = pp[1];
    a8[0] += w[t] * x0.x; a8[1] += w[t] * x0.y;
    a8[2] += w[t] * x0.z; a8[3] += w[t] * x0.w;
    a8[4] += w[t] * x1.x; a8[5] += w[t] * x1.y;
    a8[6] += w[t] * x1.z; a8[7] += w[t] * x1.w;
  }
  uint4 r;
  r.x = pack2bf(a8[0] * invs, a8[1] * invs);
  r.y = pack2bf(a8[2] * invs, a8[3] * invs);
  r.z = pack2bf(a8[4] * invs, a8[5] * invs);
  r.w = pack2bf(a8[6] * invs, a8[7] * invs);
  *(uint4*)(MSGB + (size_t)row * DIM + 8 * lane) = r;
}

// C = A·W^T fused tanh + scaled residual into Vio. M % 128 == 0, N = 512.
__global__ __launch_bounds__(256) void gemm_mfma_kernel(
    const u16* __restrict__ A, const u16* __restrict__ W,
    const float* __restrict__ bias, const float* __restrict__ scale_ptr,
    float* __restrict__ Vio) {
  const int mt = blockIdx.x, nt = blockIdx.y;
  const int tid = threadIdx.x;
  const int lane = tid & 63, wave = tid >> 6;
  const int wr = wave >> 1, wc = wave & 1;
  __shared__ __align__(16) u16 As[128][32];
  __shared__ __align__(16) u16 Bs[128][32];
  const int row0 = mt * 128, col0 = nt * 128;
  f32x4 acc[4][4];
#pragma unroll
  for (int m = 0; m < 4; ++m)
#pragma unroll
    for (int n = 0; n < 4; ++n) acc[m][n] = (f32x4){0.f, 0.f, 0.f, 0.f};
  for (int kk = 0; kk < DIM; kk += 32) {
#pragma unroll
    for (int s = 0; s < 2; ++s) {
      int c = tid + 256 * s;
      int r = c >> 2, ko = (c & 3) * 8;
      *(uint4*)&As[r][ko] = *(const uint4*)(A + (size_t)(row0 + r) * DIM + kk + ko);
      *(uint4*)&Bs[r][ko] = *(const uint4*)(W + (size_t)(col0 + r) * DIM + kk + ko);
    }
    __syncthreads();
    s16x8 fa[4], fb[4];
#pragma unroll
    for (int m = 0; m < 4; ++m)
      fa[m] = ldfrag(&As[wr * 64 + m * 16 + (lane & 15)][(lane >> 4) * 8]);
#pragma unroll
    for (int n = 0; n < 4; ++n)
      fb[n] = ldfrag(&Bs[wc * 64 + n * 16 + (lane & 15)][(lane >> 4) * 8]);
#pragma unroll
    for (int m = 0; m < 4; ++m)
#pragma unroll
      for (int n = 0; n < 4; ++n)
        acc[m][n] = __builtin_amdgcn_mfma_f32_16x16x32_bf16(fa[m], fb[n],
                                                            acc[m][n], 0, 0, 0);
    __syncthreads();
  }
  const float s = *scale_ptr;
  const int r_ = (lane >> 4) * 4, c_ = lane & 15;
#pragma unroll
  for (int m = 0; m < 4; ++m)
#pragma unroll
    for (int n = 0; n < 4; ++n) {
      const int c = col0 + wc * 64 + n * 16 + c_;
      const float bc = bias[c];
#pragma unroll
      for (int j = 0; j < 4; ++j) {
        const int r = row0 + wr * 64 + m * 16 + r_ + j;
        const size_t off = (size_t)r * DIM + c;
        Vio[off] = Vio[off] + s * tanh_fast(acc[m][n][j] + bc);
      }
    }
}

// Vio = l2n(0.8*Vio + 0.2*V0), vectorized
__global__ void resid_l2n_kernel(float* __restrict__ Vio,
                                 const float* __restrict__ V0) {
  const size_t row = blockIdx.x;
  const int lane = threadIdx.x;
  float* v = Vio + row * DIM;
  const float* v0 = V0 + row * DIM;
  float4 a = *(const float4*)(v + 4 * lane);
  float4 b = *(const float4*)(v + 256 + 4 * lane);
  float4 a0 = *(const float4*)(v0 + 4 * lane);
  float4 b0 = *(const float4*)(v0 + 256 + 4 * lane);
  a.x = 0.8f * a.x + 0.2f * a0.x; a.y = 0.8f * a.y + 0.2f * a0.y;
  a.z = 0.8f * a.z + 0.2f * a0.z; a.w = 0.8f * a.w + 0.2f * a0.w;
  b.x = 0.8f * b.x + 0.2f * b0.x; b.y = 0.8f * b.y + 0.2f * b0.y;
  b.z = 0.8f * b.z + 0.2f * b0.z; b.w = 0.8f * b.w + 0.2f * b0.w;
  float ss = a.x * a.x + a.y * a.y + a.z * a.z + a.w * a.w +
             b.x * b.x + b.y * b.y + b.z * b.z + b.w * b.w;
  ss = waveReduceSum(ss);
  const float inv = 1.f / fmaxf(sqrtf(ss), 1e-12f);
  a.x *= inv; a.y *= inv; a.z *= inv; a.w *= inv;
  b.x *= inv; b.y *= inv; b.z *= inv; b.w *= inv;
  *(float4*)(v + 4 * lane) = a;
  *(float4*)(v + 256 + 4 * lane) = b;
}

// Prototype adjacency + message (20 nodes), writes bf16 PMSGB.
__global__ void p_adj_msg_kernel(const float* __restrict__ P,
                                 u16* __restrict__ PMSGB) {
  const int row = blockIdx.x;  // b*NWAYS + n
  const int b = row / NWAYS;
  const int lane = threadIdx.x;
  const float* Pb = P + (size_t)b * NWAYS * DIM;
  const float* q = P + (size_t)row * DIM;
  float qv[8];
#pragma unroll
  for (int t = 0; t < 8; ++t) qv[t] = q[lane + 64 * t];
  float sims[NWAYS];
#pragma unroll
  for (int m = 0; m < NWAYS; ++m) {
    const float* pm = Pb + (size_t)m * DIM;
    float p = 0.f;
#pragma unroll
    for (int t = 0; t < 8; ++t) p += qv[t] * pm[lane + 64 * t];
    sims[m] = waveReduceSum(p);
  }
  float topv[KNEI];
  int topi[KNEI];
  bool used[NWAYS];
#pragma unroll
  for (int m = 0; m < NWAYS; ++m) used[m] = false;
#pragma unroll
  for (int t = 0; t < KNEI; ++t) {
    float bv = -INFINITY;
    int bi = 0;
#pragma unroll
    for (int m = 0; m < NWAYS; ++m)
      if (!used[m] && sims[m] > bv) { bv = sims[m]; bi = m; }
    used[bi] = true;
    topv[t] = bv;
    topi[t] = bi;
  }
  float w[KNEI];
  float wsum = 0.f;
#pragma unroll
  for (int t = 0; t < KNEI; ++t) {
    w[t] = expf((topv[t] - topv[0]) * TAU_INV);
    wsum += w[t];
  }
  const float invs = 1.f / wsum;
  float a8[8] = {0.f, 0.f, 0.f, 0.f, 0.f, 0.f, 0.f, 0.f};
#pragma unroll
  for (int t = 0; t < KNEI; ++t) {
    const float4* pp = (const float4*)(Pb + (size_t)topi[t] * DIM + 8 * lane);
    float4 x0 = pp[0], x1 = pp[1];
    a8[0] += w[t] * x0.x; a8[1] += w[t] * x0.y;
    a8[2] += w[t] * x0.z; a8[3] += w[t] * x0.w;
    a8[4] += w[t] * x1.x; a8[5] += w[t] * x1.y;
    a8[6] += w[t] * x1.z; a8[7] += w[t] * x1.w;
  }
  uint4 r;
  r.x = pack2bf(a8[0] * invs, a8[1] * invs);
  r.y = pack2bf(a8[2] * invs, a8[3] * invs);
  r.z = pack2bf(a8[4] * invs, a8[5] * invs);
  r.w = pack2bf(a8[6] * invs, a8[7] * invs);
  *(uint4*)(PMSGB + (size_t)row * DIM + 8 * lane) = r;
}

// VC[b,n] = l2n(mean_k V[b, n*5+k])
__global__ void vc_kernel(const float* __restrict__ V, float* __restrict__ VC) {
  const int row = blockIdx.x;  // b*NWAYS + n
  const int b = row / NWAYS, n = row - b * NWAYS;
  const int lane = threadIdx.x;
  const float* base = V + ((size_t)b * NT + (size_t)n * KSHOT) * DIM;
  float x[8];
  float ss = 0.f;
#pragma unroll
  for (int t = 0; t < 8; ++t) {
    int d = lane + 64 * t;
    float a = 0.f;
#pragma unroll
    for (int k = 0; k < KSHOT; ++k) a += base[(size_t)k * DIM + d];
    a *= 0.2f;
    x[t] = a;
    ss += a * a;
  }
  ss = waveReduceSum(ss);
  const float inv = 1.f / fmaxf(sqrtf(ss), 1e-12f);
#pragma unroll
  for (int t = 0; t < 8; ++t) VC[(size_t)row * DIM + lane + 64 * t] = x[t] * inv;
}

// Pa = l2n(alpha*P + (1-alpha)*VC)
__global__ void pa_kernel(const float* __restrict__ P,
                          const float* __restrict__ VC,
                          const float* __restrict__ alpha_ptr,
                          float* __restrict__ Pa) {
  const size_t row = blockIdx.x;
  const int lane = threadIdx.x;
  const float alpha = *alpha_ptr;
  float x[8];
  float ss = 0.f;
#pragma unroll
  for (int t = 0; t < 8; ++t) {
    size_t off = row * DIM + lane + 64 * t;
    float y = alpha * P[off] + (1.f - alpha) * VC[off];
    x[t] = y;
    ss += y * y;
  }
  ss = waveReduceSum(ss);
  const float inv = 1.f / fmaxf(sqrtf(ss), 1e-12f);
#pragma unroll
  for (int t = 0; t < 8; ++t) Pa[row * DIM + lane + 64 * t] = x[t] * inv;
}

// Guidance: Pa staged in LDS; batched butterfly reductions; per-query CE.
__global__ __launch_bounds__(512) void guide_kernel(
    float* __restrict__ V, const float* __restrict__ Pa,
    const int* __restrict__ qy, const float* __restrict__ beta_ptr,
    float* __restrict__ accum, int is_last) {
  const int b = blockIdx.x;
  const int par = blockIdx.y;  // row parity
  const int tid = threadIdx.x;
  const int wave = tid >> 6, lane = tid & 63;
  __shared__ __align__(16) float palds[NWAYS][DIM + 4];
  const float* PaB = Pa + (size_t)b * NWAYS * DIM;
  for (int c = tid; c < NWAYS * (DIM / 4); c += 512) {
    int m = c >> 7, ko = (c & 127) * 4;
    *(float4*)&palds[m][ko] = *(const float4*)(PaB + m * DIM + ko);
  }
  __syncthreads();
  const float beta = *beta_ptr;
  for (int i = par + 2 * wave; i < NT; i += 16) {
    float* vrow = V + ((size_t)b * NT + i) * DIM;
    float4 vl = *(const float4*)(vrow + 4 * lane);
    float4 vh = *(const float4*)(vrow + 256 + 4 * lane);
    float s[NWAYS];
#pragma unroll
    for (int m = 0; m < NWAYS; ++m) {
      float4 pl = *(const float4*)&palds[m][4 * lane];
      float4 ph = *(const float4*)&palds[m][256 + 4 * lane];
      s[m] = vl.x * pl.x + vl.y * pl.y + vl.z * pl.z + vl.w * pl.w +
             vh.x * ph.x + vh.y * ph.y + vh.z * ph.z + vh.w * ph.w;
    }
#pragma unroll
    for (int off = 32; off >= 1; off >>= 1)
#pragma unroll
      for (int m = 0; m < NWAYS; ++m) s[m] += __shfl_xor(s[m], off);
    float mx = s[0];
#pragma unroll
    for (int m = 1; m < NWAYS; ++m) mx = fmaxf(mx, s[m]);
    float w[NWAYS], wsum = 0.f;
#pragma unroll
    for (int m = 0; m < NWAYS; ++m) {
      w[m] = __expf((s[m] - mx) * TAU_INV);
      wsum += w[m];
    }
    const float ci = (1.f - beta) / wsum;
    float4 gl = {0.f, 0.f, 0.f, 0.f}, gh = {0.f, 0.f, 0.f, 0.f};
#pragma unroll
    for (int m = 0; m < NWAYS; ++m) {
      float4 pl = *(const float4*)&palds[m][4 * lane];
      float4 ph = *(const float4*)&palds[m][256 + 4 * lane];
      gl.x += w[m] * pl.x; gl.y += w[m] * pl.y;
      gl.z += w[m] * pl.z; gl.w += w[m] * pl.w;
      gh.x += w[m] * ph.x; gh.y += w[m] * ph.y;
      gh.z += w[m] * ph.z; gh.w += w[m] * ph.w;
    }
    float4 yl, yh;
    yl.x = beta * vl.x + ci * gl.x; yl.y = beta * vl.y + ci * gl.y;
    yl.z = beta * vl.z + ci * gl.z; yl.w = beta * vl.w + ci * gl.w;
    yh.x = beta * vh.x + ci * gh.x; yh.y = beta * vh.y + ci * gh.y;
    yh.z = beta * vh.z + ci * gh.z; yh.w = beta * vh.w + ci * gh.w;
    float ss = yl.x * yl.x + yl.y * yl.y + yl.z * yl.z + yl.w * yl.w +
               yh.x * yh.x + yh.y * yh.y + yh.z * yh.z + yh.w * yh.w;
    ss = waveReduceSum(ss);
    const float inv = 1.f / fmaxf(sqrtf(ss), 1e-12f);
    yl.x *= inv; yl.y *= inv; yl.z *= inv; yl.w *= inv;
    yh.x *= inv; yh.y *= inv; yh.z *= inv; yh.w *= inv;
    *(float4*)(vrow + 4 * lane) = yl;
    *(float4*)(vrow + 256 + 4 * lane) = yh;
    if (i >= NKS) {
      float lg[NWAYS];
#pragma unroll
      for (int m = 0; m < NWAYS; ++m) {
        float4 pl = *(const float4*)&palds[m][4 * lane];
        float4 ph = *(const float4*)&palds[m][256 + 4 * lane];
        lg[m] = yl.x * pl.x + yl.y * pl.y + yl.z * pl.z + yl.w * pl.w +
                yh.x * ph.x + yh.y * ph.y + yh.z * ph.z + yh.w * ph.w;
      }
#pragma unroll
      for (int off = 32; off >= 1; off >>= 1)
#pragma unroll
        for (int m = 0; m < NWAYS; ++m) lg[m] += __shfl_xor(lg[m], off);
      if (lane == 0) {
        const int yt = qy[b * NQ + (i - NKS)];
        float m2 = lg[0] * LOGIT_SCALE;
        int am = 0;
#pragma unroll
        for (int m = 0; m < NWAYS; ++m) lg[m] *= LOGIT_SCALE;
#pragma unroll
        for (int m = 1; m < NWAYS; ++m)
          if (lg[m] > m2) { m2 = lg[m]; am = m; }
        float se = 0.f;
#pragma unroll
        for (int m = 0; m < NWAYS; ++m) se += __expf(lg[m] - m2);
        const float ce = m2 + __logf(se) - lg[yt];
        atomicAdd(&accum[0], ce);
        if (is_last) atomicAdd(&accum[1], (am == yt) ? 1.f : 0.f);
      }
    }
  }
}

__global__ void finalize_kernel(const float* __restrict__ acc,
                                float* __restrict__ out) {
  out[0] = acc[0] / (float)(NLAYERS * B_EP * NQ);
  out[1] = acc[1] / (float)(B_EP * NQ);
}

extern "C" void kernel_launch(void* const* d_in, const int* in_sizes, int n_in,
                              void* d_out, int out_size, void* d_ws,
                              size_t ws_size, hipStream_t stream) {
  const float* V_feat = (const float*)d_in[0];
  const float* P_feat = (const float*)d_in[1];
  const int* query_y = (const int*)d_in[2];
  const float* igb_W = (const float*)d_in[3];
  const float* igb_b = (const float*)d_in[4];
  const float* igb_s = (const float*)d_in[5];
  const float* pgb_W = (const float*)d_in[6];
  const float* pgb_b = (const float*)d_in[7];
  const float* pgb_s = (const float*)d_in[8];
  const float* alpha = (const float*)d_in[9];
  const float* beta = (const float*)d_in[10];
  float* out = (float*)d_out;

  float* ws = (float*)d_ws;
  const size_t vsz = (size_t)B_EP * NT * DIM;       // 22,937,600
  const size_t psz = (size_t)B_EP * NWAYS * DIM;    // 2,621,440
  const size_t ssz = (size_t)B_EP * NT * NT;        // 7,840,000
  const size_t wsz = (size_t)NLAYERS * DIM * DIM;   // 1,048,576
  float* ACC = ws;
  float* V = ws + 16;
  float* V0 = V + vsz;
  float* SIM = V0 + vsz;
  float* P = SIM + ssz;
  float* P0 = P + psz;
  float* VC = P0 + psz;
  float* PA = VC + psz;
  u16* VB = (u16*)(PA + psz);
  u16* MSGB = VB + vsz;
  u16* PMSGB = MSGB + vsz;
  u16* WB = PMSGB + psz;
  u16* WPB = WB + wsz;

  init_accum_kernel<<<1, 64, 0, stream>>>(ACC);
  l2n_init_kernel<<<B_EP * NT, 64, 0, stream>>>(V_feat, V, V0);
  l2n_init_kernel<<<B_EP * NWAYS, 64, 0, stream>>>(P_feat, P, P0);
  cvt_bf16_kernel<<<(int)(wsz / 8 / 256), 256, 0, stream>>>(igb_W, WB,
                                                            (int)(wsz / 8));
  cvt_bf16_kernel<<<(int)(wsz / 8 / 256), 256, 0, stream>>>(pgb_W, WPB,
                                                            (int)(wsz / 8));

  for (int i = 0; i < NLAYERS; ++i) {
    cvt_bf16_kernel<<<(int)(vsz / 8 / 256), 256, 0, stream>>>(V, VB,
                                                              (int)(vsz / 8));
    sim_mfma_kernel<<<dim3(3, 3, B_EP), 64, 0, stream>>>(VB, SIM);
    topk_msg_kernel<<<B_EP * NT, 64, 0, stream>>>(SIM, V, MSGB);
    gemm_mfma_kernel<<<dim3(B_EP * NT / 128, 4), 256, 0, stream>>>(
        MSGB, WB + (size_t)i * DIM * DIM, igb_b + (size_t)i * DIM, igb_s + i, V);
    resid_l2n_kernel<<<B_EP * NT, 64, 0, stream>>>(V, V0);

    p_adj_msg_kernel<<<B_EP * NWAYS, 64, 0, stream>>>(P, PMSGB);
    gemm_mfma_kernel<<<dim3(B_EP * NWAYS / 128, 4), 256, 0, stream>>>(
        PMSGB, WPB + (size_t)i * DIM * DIM, pgb_b + (size_t)i * DIM, pgb_s + i, P);
    resid_l2n_kernel<<<B_EP * NWAYS, 64, 0, stream>>>(P, P0);

    vc_kernel<<<B_EP * NWAYS, 64, 0, stream>>>(V, VC);
    pa_kernel<<<B_EP * NWAYS, 64, 0, stream>>>(P, VC, alpha, PA);
    guide_kernel<<<dim3(B_EP, 2), 512, 0, stream>>>(V, PA, query_y, beta, ACC,
                                                    (i == NLAYERS - 1) ? 1 : 0);
  }
  finalize_kernel<<<1, 1, 0, stream>>>(ACC, out);
}

// Round 3
// 2562.680 us; speedup vs baseline: 3.0965x; 1.5809x over previous
//
#include <hip/hip_runtime.h>
#include <math.h>

#define B_EP 256
#define NT 175
#define NWAYS 20
#define KSHOT 5
#define NKS 100          // N_WAYS * N_SHOTS
#define NQ 75
#define DIM 512
#define NLAYERS 4
#define TAU_INV 10.0f
#define LOGIT_SCALE 5.0f
#define KNEI 5

typedef unsigned int u32;
typedef unsigned short u16;
typedef __attribute__((ext_vector_type(8))) short s16x8;   // 8 bf16 in 4 VGPRs
typedef __attribute__((ext_vector_type(4))) float f32x4;

__device__ __forceinline__ float waveReduceSum(float v) {
#pragma unroll
  for (int off = 32; off >= 1; off >>= 1) v += __shfl_xor(v, off);
  return v;
}

__device__ __forceinline__ u32 pack2bf(float a, float b) {
  u32 ua = __float_as_uint(a), ub = __float_as_uint(b);
  ua = (ua + 0x7FFFu + ((ua >> 16) & 1u)) >> 16;
  ub = (ub + 0x7FFFu + ((ub >> 16) & 1u)) >> 16;
  return ua | (ub << 16);
}

__device__ __forceinline__ u16 pack1bf(float a) {
  u32 ua = __float_as_uint(a);
  return (u16)((ua + 0x7FFFu + ((ua >> 16) & 1u)) >> 16);
}

__device__ __forceinline__ float bflo(u32 u) { return __uint_as_float(u << 16); }
__device__ __forceinline__ float bfhi(u32 u) { return __uint_as_float(u & 0xFFFF0000u); }
__device__ __forceinline__ float bf1(u16 h) { return __uint_as_float((u32)h << 16); }

__device__ __forceinline__ float tanh_fast(float x) {
  float e = __expf(2.f * x);
  return 1.f - 2.f * __builtin_amdgcn_rcpf(e + 1.f);
}

__device__ __forceinline__ s16x8 ldfrag(const u16* p) {
  return __builtin_bit_cast(s16x8, *(const uint4*)p);
}

__global__ void init_accum_kernel(float* acc) {
  if (threadIdx.x < 16) acc[threadIdx.x] = 0.f;
}

// f32 -> bf16 (RNE), 8 elems/thread (weights only now)
__global__ void cvt_bf16_kernel(const float* __restrict__ in,
                                u16* __restrict__ out, int n8) {
  int t = blockIdx.x * 256 + threadIdx.x;
  if (t >= n8) return;
  const float4* p = (const float4*)(in + (size_t)t * 8);
  float4 a = p[0], b = p[1];
  uint4 r;
  r.x = pack2bf(a.x, a.y);
  r.y = pack2bf(a.z, a.w);
  r.z = pack2bf(b.x, b.y);
  r.w = pack2bf(b.z, b.w);
  *(uint4*)(out + (size_t)t * 8) = r;
}

// l2-normalize rows (512 wide); optionally emit bf16 copy.
__global__ void l2n_init_kernel(const float* __restrict__ in,
                                float* __restrict__ out,
                                float* __restrict__ out0,
                                u16* __restrict__ outb) {
  const size_t row = blockIdx.x;
  const int lane = threadIdx.x;
  const float* src = in + row * DIM;
  float4 a = *(const float4*)(src + 4 * lane);
  float4 b = *(const float4*)(src + 256 + 4 * lane);
  float ss = a.x * a.x + a.y * a.y + a.z * a.z + a.w * a.w +
             b.x * b.x + b.y * b.y + b.z * b.z + b.w * b.w;
  ss = waveReduceSum(ss);
  const float inv = 1.f / fmaxf(sqrtf(ss), 1e-12f);
  a.x *= inv; a.y *= inv; a.z *= inv; a.w *= inv;
  b.x *= inv; b.y *= inv; b.z *= inv; b.w *= inv;
  *(float4*)(out + row * DIM + 4 * lane) = a;
  *(float4*)(out + row * DIM + 256 + 4 * lane) = b;
  *(float4*)(out0 + row * DIM + 4 * lane) = a;
  *(float4*)(out0 + row * DIM + 256 + 4 * lane) = b;
  if (outb) {
    uint2 pa, pb;
    pa.x = pack2bf(a.x, a.y); pa.y = pack2bf(a.z, a.w);
    pb.x = pack2bf(b.x, b.y); pb.y = pack2bf(b.z, b.w);
    *(uint2*)(outb + row * DIM + 4 * lane) = pa;
    *(uint2*)(outb + row * DIM + 256 + 4 * lane) = pb;
  }
}

// SIM = V·V^T per episode via bf16 MFMA, 64x64 tile per 1-wave block.
__global__ __launch_bounds__(64) void sim_mfma_kernel(
    const u16* __restrict__ VB, float* __restrict__ SIM) {
  const int b = blockIdx.z, it = blockIdx.y, jt = blockIdx.x;
  const int lane = threadIdx.x;
  __shared__ __align__(16) u16 As[64][32];
  __shared__ __align__(16) u16 Bs[64][32];
  const u16* Vb = VB + (size_t)b * NT * DIM;
  f32x4 acc[4][4];
#pragma unroll
  for (int m = 0; m < 4; ++m)
#pragma unroll
    for (int n = 0; n < 4; ++n) acc[m][n] = (f32x4){0.f, 0.f, 0.f, 0.f};
  const int ra = it * 64 + lane, rb = jt * 64 + lane;
  for (int kk = 0; kk < DIM; kk += 32) {
    if (ra < NT) {
      const uint4* g = (const uint4*)(Vb + (size_t)ra * DIM + kk);
#pragma unroll
      for (int q = 0; q < 4; ++q) *(uint4*)&As[lane][8 * q] = g[q];
    } else {
      uint4 z = {0, 0, 0, 0};
#pragma unroll
      for (int q = 0; q < 4; ++q) *(uint4*)&As[lane][8 * q] = z;
    }
    if (rb < NT) {
      const uint4* g = (const uint4*)(Vb + (size_t)rb * DIM + kk);
#pragma unroll
      for (int q = 0; q < 4; ++q) *(uint4*)&Bs[lane][8 * q] = g[q];
    } else {
      uint4 z = {0, 0, 0, 0};
#pragma unroll
      for (int q = 0; q < 4; ++q) *(uint4*)&Bs[lane][8 * q] = z;
    }
    __syncthreads();
    s16x8 fa[4], fb[4];
#pragma unroll
    for (int m = 0; m < 4; ++m)
      fa[m] = ldfrag(&As[m * 16 + (lane & 15)][(lane >> 4) * 8]);
#pragma unroll
    for (int n = 0; n < 4; ++n)
      fb[n] = ldfrag(&Bs[n * 16 + (lane & 15)][(lane >> 4) * 8]);
#pragma unroll
    for (int m = 0; m < 4; ++m)
#pragma unroll
      for (int n = 0; n < 4; ++n)
        acc[m][n] = __builtin_amdgcn_mfma_f32_16x16x32_bf16(fa[m], fb[n],
                                                            acc[m][n], 0, 0, 0);
    __syncthreads();
  }
  const int r_ = (lane >> 4) * 4, c_ = lane & 15;
#pragma unroll
  for (int m = 0; m < 4; ++m)
#pragma unroll
    for (int n = 0; n < 4; ++n)
#pragma unroll
      for (int j = 0; j < 4; ++j) {
        int r = it * 64 + m * 16 + r_ + j, c = jt * 64 + n * 16 + c_;
        if (r < NT && c < NT) SIM[((size_t)b * NT + r) * NT + c] = acc[m][n][j];
      }
}

// Per (b,i): top-5 of SIM row, softmax/tau, MSGB[b,i,:] = sum w_k*V[idx_k] (bf16)
__global__ void topk_msg_kernel(const float* __restrict__ SIM,
                                const float* __restrict__ V,
                                u16* __restrict__ MSGB) {
  const int row = blockIdx.x;  // b*NT + i
  const int b = row / NT;
  const int lane = threadIdx.x;
  const float* srow = SIM + (size_t)row * NT;
  float sv[3];
  int si[3];
#pragma unroll
  for (int t = 0; t < 3; ++t) {
    int j = lane + 64 * t;
    sv[t] = (j < NT) ? srow[j] : -INFINITY;
    si[t] = j;
  }
  float topv[KNEI];
  int topi[KNEI];
#pragma unroll
  for (int t = 0; t < KNEI; ++t) {
    float bv = sv[0];
    int bi = si[0];
    if (sv[1] > bv) { bv = sv[1]; bi = si[1]; }
    if (sv[2] > bv) { bv = sv[2]; bi = si[2]; }
#pragma unroll
    for (int off = 32; off >= 1; off >>= 1) {
      float ov = __shfl_xor(bv, off);
      int oi = __shfl_xor(bi, off);
      if (ov > bv || (ov == bv && oi < bi)) { bv = ov; bi = oi; }
    }
    topv[t] = bv;
    topi[t] = bi;
#pragma unroll
    for (int u = 0; u < 3; ++u)
      if (si[u] == bi) sv[u] = -INFINITY;
  }
  float w[KNEI];
  float wsum = 0.f;
#pragma unroll
  for (int t = 0; t < KNEI; ++t) {
    w[t] = expf((topv[t] - topv[0]) * TAU_INV);
    wsum += w[t];
  }
  const float invs = 1.f / wsum;
  const float* Vb = V + (size_t)b * NT * DIM;
  float a8[8] = {0.f, 0.f, 0.f, 0.f, 0.f, 0.f, 0.f, 0.f};
#pragma unroll
  for (int t = 0; t < KNEI; ++t) {
    const float4* pp = (const float4*)(Vb + (size_t)topi[t] * DIM + 8 * lane);
    float4 x0 = pp[0], x1 = pp[1];
    a8[0] += w[t] * x0.x; a8[1] += w[t] * x0.y;
    a8[2] += w[t] * x0.z; a8[3] += w[t] * x0.w;
    a8[4] += w[t] * x1.x; a8[5] += w[t] * x1.y;
    a8[6] += w[t] * x1.z; a8[7] += w[t] * x1.w;
  }
  uint4 r;
  r.x = pack2bf(a8[0] * invs, a8[1] * invs);
  r.y = pack2bf(a8[2] * invs, a8[3] * invs);
  r.z = pack2bf(a8[4] * invs, a8[5] * invs);
  r.w = pack2bf(a8[6] * invs, a8[7] * invs);
  *(uint4*)(MSGB + (size_t)row * DIM + 8 * lane) = r;
}

// C = A·W^T fused tanh + scaled residual into Vio. M % 128 == 0, N = 512.
__global__ __launch_bounds__(256) void gemm_mfma_kernel(
    const u16* __restrict__ A, const u16* __restrict__ W,
    const float* __restrict__ bias, const float* __restrict__ scale_ptr,
    float* __restrict__ Vio) {
  const int mt = blockIdx.x, nt = blockIdx.y;
  const int tid = threadIdx.x;
  const int lane = tid & 63, wave = tid >> 6;
  const int wr = wave >> 1, wc = wave & 1;
  __shared__ __align__(16) u16 As[128][32];
  __shared__ __align__(16) u16 Bs[128][32];
  const int row0 = mt * 128, col0 = nt * 128;
  f32x4 acc[4][4];
#pragma unroll
  for (int m = 0; m < 4; ++m)
#pragma unroll
    for (int n = 0; n < 4; ++n) acc[m][n] = (f32x4){0.f, 0.f, 0.f, 0.f};
  for (int kk = 0; kk < DIM; kk += 32) {
#pragma unroll
    for (int s = 0; s < 2; ++s) {
      int c = tid + 256 * s;
      int r = c >> 2, ko = (c & 3) * 8;
      *(uint4*)&As[r][ko] = *(const uint4*)(A + (size_t)(row0 + r) * DIM + kk + ko);
      *(uint4*)&Bs[r][ko] = *(const uint4*)(W + (size_t)(col0 + r) * DIM + kk + ko);
    }
    __syncthreads();
    s16x8 fa[4], fb[4];
#pragma unroll
    for (int m = 0; m < 4; ++m)
      fa[m] = ldfrag(&As[wr * 64 + m * 16 + (lane & 15)][(lane >> 4) * 8]);
#pragma unroll
    for (int n = 0; n < 4; ++n)
      fb[n] = ldfrag(&Bs[wc * 64 + n * 16 + (lane & 15)][(lane >> 4) * 8]);
#pragma unroll
    for (int m = 0; m < 4; ++m)
#pragma unroll
      for (int n = 0; n < 4; ++n)
        acc[m][n] = __builtin_amdgcn_mfma_f32_16x16x32_bf16(fa[m], fb[n],
                                                            acc[m][n], 0, 0, 0);
    __syncthreads();
  }
  const float s = *scale_ptr;
  const int r_ = (lane >> 4) * 4, c_ = lane & 15;
#pragma unroll
  for (int m = 0; m < 4; ++m)
#pragma unroll
    for (int n = 0; n < 4; ++n) {
      const int c = col0 + wc * 64 + n * 16 + c_;
      const float bc = bias[c];
#pragma unroll
      for (int j = 0; j < 4; ++j) {
        const int r = row0 + wr * 64 + m * 16 + r_ + j;
        const size_t off = (size_t)r * DIM + c;
        Vio[off] = Vio[off] + s * tanh_fast(acc[m][n][j] + bc);
      }
    }
}

// Vio = l2n(0.8*Vio + 0.2*V0); optionally emit bf16 copy.
__global__ void resid_l2n_kernel(float* __restrict__ Vio,
                                 const float* __restrict__ V0,
                                 u16* __restrict__ outb) {
  const size_t row = blockIdx.x;
  const int lane = threadIdx.x;
  float* v = Vio + row * DIM;
  const float* v0 = V0 + row * DIM;
  float4 a = *(const float4*)(v + 4 * lane);
  float4 b = *(const float4*)(v + 256 + 4 * lane);
  float4 a0 = *(const float4*)(v0 + 4 * lane);
  float4 b0 = *(const float4*)(v0 + 256 + 4 * lane);
  a.x = 0.8f * a.x + 0.2f * a0.x; a.y = 0.8f * a.y + 0.2f * a0.y;
  a.z = 0.8f * a.z + 0.2f * a0.z; a.w = 0.8f * a.w + 0.2f * a0.w;
  b.x = 0.8f * b.x + 0.2f * b0.x; b.y = 0.8f * b.y + 0.2f * b0.y;
  b.z = 0.8f * b.z + 0.2f * b0.z; b.w = 0.8f * b.w + 0.2f * b0.w;
  float ss = a.x * a.x + a.y * a.y + a.z * a.z + a.w * a.w +
             b.x * b.x + b.y * b.y + b.z * b.z + b.w * b.w;
  ss = waveReduceSum(ss);
  const float inv = 1.f / fmaxf(sqrtf(ss), 1e-12f);
  a.x *= inv; a.y *= inv; a.z *= inv; a.w *= inv;
  b.x *= inv; b.y *= inv; b.z *= inv; b.w *= inv;
  *(float4*)(v + 4 * lane) = a;
  *(float4*)(v + 256 + 4 * lane) = b;
  if (outb) {
    uint2 pa, pb;
    pa.x = pack2bf(a.x, a.y); pa.y = pack2bf(a.z, a.w);
    pb.x = pack2bf(b.x, b.y); pb.y = pack2bf(b.z, b.w);
    *(uint2*)(outb + row * DIM + 4 * lane) = pa;
    *(uint2*)(outb + row * DIM + 256 + 4 * lane) = pb;
  }
}

// Prototype adjacency + message (20 nodes), writes bf16 PMSGB.
__global__ void p_adj_msg_kernel(const float* __restrict__ P,
                                 u16* __restrict__ PMSGB) {
  const int row = blockIdx.x;  // b*NWAYS + n
  const int b = row / NWAYS;
  const int lane = threadIdx.x;
  const float* Pb = P + (size_t)b * NWAYS * DIM;
  const float* q = P + (size_t)row * DIM;
  float qv[8];
#pragma unroll
  for (int t = 0; t < 8; ++t) qv[t] = q[lane + 64 * t];
  float sims[NWAYS];
#pragma unroll
  for (int m = 0; m < NWAYS; ++m) {
    const float* pm = Pb + (size_t)m * DIM;
    float p = 0.f;
#pragma unroll
    for (int t = 0; t < 8; ++t) p += qv[t] * pm[lane + 64 * t];
    sims[m] = waveReduceSum(p);
  }
  float topv[KNEI];
  int topi[KNEI];
  bool used[NWAYS];
#pragma unroll
  for (int m = 0; m < NWAYS; ++m) used[m] = false;
#pragma unroll
  for (int t = 0; t < KNEI; ++t) {
    float bv = -INFINITY;
    int bi = 0;
#pragma unroll
    for (int m = 0; m < NWAYS; ++m)
      if (!used[m] && sims[m] > bv) { bv = sims[m]; bi = m; }
    used[bi] = true;
    topv[t] = bv;
    topi[t] = bi;
  }
  float w[KNEI];
  float wsum = 0.f;
#pragma unroll
  for (int t = 0; t < KNEI; ++t) {
    w[t] = expf((topv[t] - topv[0]) * TAU_INV);
    wsum += w[t];
  }
  const float invs = 1.f / wsum;
  float a8[8] = {0.f, 0.f, 0.f, 0.f, 0.f, 0.f, 0.f, 0.f};
#pragma unroll
  for (int t = 0; t < KNEI; ++t) {
    const float4* pp = (const float4*)(Pb + (size_t)topi[t] * DIM + 8 * lane);
    float4 x0 = pp[0], x1 = pp[1];
    a8[0] += w[t] * x0.x; a8[1] += w[t] * x0.y;
    a8[2] += w[t] * x0.z; a8[3] += w[t] * x0.w;
    a8[4] += w[t] * x1.x; a8[5] += w[t] * x1.y;
    a8[6] += w[t] * x1.z; a8[7] += w[t] * x1.w;
  }
  uint4 r;
  r.x = pack2bf(a8[0] * invs, a8[1] * invs);
  r.y = pack2bf(a8[2] * invs, a8[3] * invs);
  r.z = pack2bf(a8[4] * invs, a8[5] * invs);
  r.w = pack2bf(a8[6] * invs, a8[7] * invs);
  *(uint4*)(PMSGB + (size_t)row * DIM + 8 * lane) = r;
}

// VC[b,n] = l2n(mean_k V[b, n*5+k])
__global__ void vc_kernel(const float* __restrict__ V, float* __restrict__ VC) {
  const int row = blockIdx.x;  // b*NWAYS + n
  const int b = row / NWAYS, n = row - b * NWAYS;
  const int lane = threadIdx.x;
  const float* base = V + ((size_t)b * NT + (size_t)n * KSHOT) * DIM;
  float x[8];
  float ss = 0.f;
#pragma unroll
  for (int t = 0; t < 8; ++t) {
    int d = lane + 64 * t;
    float a = 0.f;
#pragma unroll
    for (int k = 0; k < KSHOT; ++k) a += base[(size_t)k * DIM + d];
    a *= 0.2f;
    x[t] = a;
    ss += a * a;
  }
  ss = waveReduceSum(ss);
  const float inv = 1.f / fmaxf(sqrtf(ss), 1e-12f);
#pragma unroll
  for (int t = 0; t < 8; ++t) VC[(size_t)row * DIM + lane + 64 * t] = x[t] * inv;
}

// Pa = l2n(alpha*P + (1-alpha)*VC) -> bf16 PAB only
__global__ void pa_kernel(const float* __restrict__ P,
                          const float* __restrict__ VC,
                          const float* __restrict__ alpha_ptr,
                          u16* __restrict__ PAB) {
  const size_t row = blockIdx.x;
  const int lane = threadIdx.x;
  const float alpha = *alpha_ptr, oma = 1.f - alpha;
  float4 a, b;
  {
    float4 p0 = *(const float4*)(P + row * DIM + 4 * lane);
    float4 p1 = *(const float4*)(P + row * DIM + 256 + 4 * lane);
    float4 c0 = *(const float4*)(VC + row * DIM + 4 * lane);
    float4 c1 = *(const float4*)(VC + row * DIM + 256 + 4 * lane);
    a.x = alpha * p0.x + oma * c0.x; a.y = alpha * p0.y + oma * c0.y;
    a.z = alpha * p0.z + oma * c0.z; a.w = alpha * p0.w + oma * c0.w;
    b.x = alpha * p1.x + oma * c1.x; b.y = alpha * p1.y + oma * c1.y;
    b.z = alpha * p1.z + oma * c1.z; b.w = alpha * p1.w + oma * c1.w;
  }
  float ss = a.x * a.x + a.y * a.y + a.z * a.z + a.w * a.w +
             b.x * b.x + b.y * b.y + b.z * b.z + b.w * b.w;
  ss = waveReduceSum(ss);
  const float inv = 1.f / fmaxf(sqrtf(ss), 1e-12f);
  a.x *= inv; a.y *= inv; a.z *= inv; a.w *= inv;
  b.x *= inv; b.y *= inv; b.z *= inv; b.w *= inv;
  uint2 pa, pb;
  pa.x = pack2bf(a.x, a.y); pa.y = pack2bf(a.z, a.w);
  pb.x = pack2bf(b.x, b.y); pb.y = pack2bf(b.z, b.w);
  *(uint2*)(PAB + row * DIM + 4 * lane) = pa;
  *(uint2*)(PAB + row * DIM + 256 + 4 * lane) = pb;
}

// SIMS[b,r,n] = V[b,r]·Pa[b,n], MFMA, 64-row tile per 1-wave block.
__global__ __launch_bounds__(64) void sims_kernel(const u16* __restrict__ VB,
                                                  const u16* __restrict__ PAB,
                                                  float* __restrict__ SIMS) {
  const int it = blockIdx.x, b = blockIdx.y;
  const int lane = threadIdx.x;
  __shared__ __align__(16) u16 As[64][32];
  __shared__ __align__(16) u16 Bs[32][32];
  const u16* Vb = VB + (size_t)b * NT * DIM;
  const u16* Pb = PAB + (size_t)b * NWAYS * DIM;
  f32x4 acc[4][2];
#pragma unroll
  for (int m = 0; m < 4; ++m)
#pragma unroll
    for (int n = 0; n < 2; ++n) acc[m][n] = (f32x4){0.f, 0.f, 0.f, 0.f};
  const int ra = it * 64 + lane;
  const int rb = lane & 31, kb = (lane >> 5) * 16;
  for (int kk = 0; kk < DIM; kk += 32) {
    if (ra < NT) {
      const uint4* g = (const uint4*)(Vb + (size_t)ra * DIM + kk);
#pragma unroll
      for (int q = 0; q < 4; ++q) *(uint4*)&As[lane][8 * q] = g[q];
    } else {
      uint4 z = {0, 0, 0, 0};
#pragma unroll
      for (int q = 0; q < 4; ++q) *(uint4*)&As[lane][8 * q] = z;
    }
    if (rb < NWAYS) {
      const uint4* g = (const uint4*)(Pb + (size_t)rb * DIM + kk + kb);
      *(uint4*)&Bs[rb][kb] = g[0];
      *(uint4*)&Bs[rb][kb + 8] = g[1];
    } else {
      uint4 z = {0, 0, 0, 0};
      *(uint4*)&Bs[rb][kb] = z;
      *(uint4*)&Bs[rb][kb + 8] = z;
    }
    __syncthreads();
    s16x8 fa[4], fb[2];
#pragma unroll
    for (int m = 0; m < 4; ++m)
      fa[m] = ldfrag(&As[m * 16 + (lane & 15)][(lane >> 4) * 8]);
#pragma unroll
    for (int n = 0; n < 2; ++n)
      fb[n] = ldfrag(&Bs[n * 16 + (lane & 15)][(lane >> 4) * 8]);
#pragma unroll
    for (int m = 0; m < 4; ++m)
#pragma unroll
      for (int n = 0; n < 2; ++n)
        acc[m][n] = __builtin_amdgcn_mfma_f32_16x16x32_bf16(fa[m], fb[n],
                                                            acc[m][n], 0, 0, 0);
    __syncthreads();
  }
  const int r_ = (lane >> 4) * 4, c_ = lane & 15;
#pragma unroll
  for (int m = 0; m < 4; ++m)
#pragma unroll
    for (int n = 0; n < 2; ++n)
#pragma unroll
      for (int j = 0; j < 4; ++j) {
        int r = it * 64 + m * 16 + r_ + j, c = n * 16 + c_;
        if (r < NT && c < NWAYS)
          SIMS[((size_t)b * NT + r) * NWAYS + c] = acc[m][n][j];
      }
}

// G[b] = Pa·Pa^T (20x20), one wave per episode.
__global__ __launch_bounds__(64) void gram_kernel(const u16* __restrict__ PAB,
                                                  float* __restrict__ G) {
  const int b = blockIdx.x;
  const int lane = threadIdx.x;
  __shared__ __align__(16) u16 Ps[32][32];
  const u16* Pb = PAB + (size_t)b * NWAYS * DIM;
  f32x4 acc[2][2];
#pragma unroll
  for (int m = 0; m < 2; ++m)
#pragma unroll
    for (int n = 0; n < 2; ++n) acc[m][n] = (f32x4){0.f, 0.f, 0.f, 0.f};
  const int rb = lane & 31, kb = (lane >> 5) * 16;
  for (int kk = 0; kk < DIM; kk += 32) {
    if (rb < NWAYS) {
      const uint4* g = (const uint4*)(Pb + (size_t)rb * DIM + kk + kb);
      *(uint4*)&Ps[rb][kb] = g[0];
      *(uint4*)&Ps[rb][kb + 8] = g[1];
    } else {
      uint4 z = {0, 0, 0, 0};
      *(uint4*)&Ps[rb][kb] = z;
      *(uint4*)&Ps[rb][kb + 8] = z;
    }
    __syncthreads();
    s16x8 f[2];
#pragma unroll
    for (int m = 0; m < 2; ++m)
      f[m] = ldfrag(&Ps[m * 16 + (lane & 15)][(lane >> 4) * 8]);
#pragma unroll
    for (int m = 0; m < 2; ++m)
#pragma unroll
      for (int n = 0; n < 2; ++n)
        acc[m][n] = __builtin_amdgcn_mfma_f32_16x16x32_bf16(f[m], f[n],
                                                            acc[m][n], 0, 0, 0);
    __syncthreads();
  }
  const int r_ = (lane >> 4) * 4, c_ = lane & 15;
#pragma unroll
  for (int m = 0; m < 2; ++m)
#pragma unroll
    for (int n = 0; n < 2; ++n)
#pragma unroll
      for (int j = 0; j < 4; ++j) {
        int r = m * 16 + r_ + j, c = n * 16 + c_;
        if (r < NWAYS && c < NWAYS)
          G[(size_t)b * 400 + r * NWAYS + c] = acc[m][n][j];
      }
}

// Softmax + CE from scalars: per row computes soft weights S (bf16), invn,
// and for query rows the CE loss via logits = 5*invn*(beta*sims+(1-beta)*s·G).
__global__ __launch_bounds__(256) void softce_kernel(
    const float* __restrict__ SIMS, const float* __restrict__ G,
    const int* __restrict__ qy, const float* __restrict__ beta_ptr,
    u16* __restrict__ S, float* __restrict__ INVN, float* __restrict__ accum,
    int is_last) {
  const int b = blockIdx.x, yq = blockIdx.y;
  const int tid = threadIdx.x;
  const int wave = tid >> 6, lane = tid & 63;
  const int half = lane >> 5, n = lane & 31;
  __shared__ float gl[NWAYS][32];
  for (int c = tid; c < NWAYS * 32; c += 256) {
    int m = c >> 5, nn2 = c & 31;
    gl[m][nn2] = (nn2 < NWAYS) ? G[(size_t)b * 400 + m * NWAYS + nn2] : 0.f;
  }
  __syncthreads();
  const float beta = *beta_ptr, omb = 1.f - beta;
  const int r0 = 44 * yq;
  const int rend = min(44 * (yq + 1), NT);
  const int npairs = (rend - r0 + 1) >> 1;
  for (int pr = wave; pr < npairs; pr += 4) {
    const int r = r0 + 2 * pr + half;
    if (r < rend) {
      float s = (n < NWAYS) ? SIMS[((size_t)b * NT + r) * NWAYS + n] : -1e30f;
      float mx = s;
#pragma unroll
      for (int off = 16; off >= 1; off >>= 1)
        mx = fmaxf(mx, __shfl_xor(mx, off, 32));
      float e = __expf((s - mx) * TAU_INV);
      float wsum = e, dsum = e * s;
#pragma unroll
      for (int off = 16; off >= 1; off >>= 1) {
        wsum += __shfl_xor(wsum, off, 32);
        dsum += __shfl_xor(dsum, off, 32);
      }
      float sg = 0.f;
#pragma unroll
      for (int m = 0; m < NWAYS; ++m) sg += __shfl(e, m, 32) * gl[m][n];
      float qsum = e * sg;
#pragma unroll
      for (int off = 16; off >= 1; off >>= 1)
        qsum += __shfl_xor(qsum, off, 32);
      const float iw = 1.f / wsum;
      const float dN = dsum * iw;
      const float qN = qsum * iw * iw;
      const float nn2 = beta * beta + 2.f * beta * omb * dN + omb * omb * qN;
      const float invn = 1.f / fmaxf(sqrtf(nn2), 1e-12f);
      S[((size_t)b * NT + r) * 32 + n] = pack1bf(e * iw);
      if (n == 0) INVN[(size_t)b * NT + r] = invn;
      if (r >= NKS) {
        float l = (n < NWAYS)
                      ? LOGIT_SCALE * invn * (beta * s + omb * sg * iw)
                      : -1e30f;
        float bv = l;
        int bi = n;
#pragma unroll
        for (int off = 16; off >= 1; off >>= 1) {
          float ov = __shfl_xor(bv, off, 32);
          int oi = __shfl_xor(bi, off, 32);
          if (ov > bv || (ov == bv && oi < bi)) { bv = ov; bi = oi; }
        }
        float se = __expf(l - bv);
#pragma unroll
        for (int off = 16; off >= 1; off >>= 1) se += __shfl_xor(se, off, 32);
        const int y = qy[b * NQ + (r - NKS)];
        const float ly = __shfl(l, y, 32);
        if (n == 0) {
          atomicAdd(&accum[0], bv + __logf(se) - ly);
          if (is_last) atomicAdd(&accum[1], (bi == y) ? 1.f : 0.f);
        }
      }
    }
  }
}

// V = invn*(beta*V + (1-beta)*S·Pa), writes f32 V and bf16 VB.
__global__ __launch_bounds__(256) void vupdate_kernel(
    float* __restrict__ V, u16* __restrict__ VB, const u16* __restrict__ PAB,
    const u16* __restrict__ S, const float* __restrict__ INVN,
    const float* __restrict__ beta_ptr) {
  const int b = blockIdx.x, yc = blockIdx.y;  // 0..6
  const int tid = threadIdx.x, wave = tid >> 6, lane = tid & 63;
  __shared__ __align__(16) u16 palds[NWAYS][DIM];
  __shared__ __align__(16) u16 slds[25][32];
  __shared__ float ilds[25];
  const int r0 = 25 * yc;
  for (int c = tid; c < NWAYS * (DIM / 8); c += 256) {
    int m = c >> 6, ko = (c & 63) * 8;
    *(uint4*)&palds[m][ko] =
        *(const uint4*)(PAB + ((size_t)b * NWAYS + m) * DIM + ko);
  }
  for (int c = tid; c < 100; c += 256) {
    *(uint4*)&slds[0][c * 8] =
        *(const uint4*)(S + ((size_t)b * NT + r0) * 32 + c * 8);
  }
  if (tid < 25) ilds[tid] = INVN[(size_t)b * NT + r0 + tid];
  __syncthreads();
  const float beta = *beta_ptr, omb = 1.f - beta;
  for (int t = wave; t < 25; t += 4) {
    const int r = r0 + t;
    float* vrow = V + ((size_t)b * NT + r) * DIM;
    float4 vl = *(const float4*)(vrow + 4 * lane);
    float4 vh = *(const float4*)(vrow + 256 + 4 * lane);
    float4 gL = {0.f, 0.f, 0.f, 0.f}, gH = {0.f, 0.f, 0.f, 0.f};
#pragma unroll
    for (int m = 0; m < NWAYS; ++m) {
      const float w = bf1(slds[t][m]);
      uint2 p0 = *(const uint2*)&palds[m][4 * lane];
      uint2 p1 = *(const uint2*)&palds[m][256 + 4 * lane];
      gL.x += w * bflo(p0.x); gL.y += w * bfhi(p0.x);
      gL.z += w * bflo(p0.y); gL.w += w * bfhi(p0.y);
      gH.x += w * bflo(p1.x); gH.y += w * bfhi(p1.x);
      gH.z += w * bflo(p1.y); gH.w += w * bfhi(p1.y);
    }
    const float inv = ilds[t];
    float4 yl, yh;
    yl.x = inv * (beta * vl.x + omb * gL.x);
    yl.y = inv * (beta * vl.y + omb * gL.y);
    yl.z = inv * (beta * vl.z + omb * gL.z);
    yl.w = inv * (beta * vl.w + omb * gL.w);
    yh.x = inv * (beta * vh.x + omb * gH.x);
    yh.y = inv * (beta * vh.y + omb * gH.y);
    yh.z = inv * (beta * vh.z + omb * gH.z);
    yh.w = inv * (beta * vh.w + omb * gH.w);
    *(float4*)(vrow + 4 * lane) = yl;
    *(float4*)(vrow + 256 + 4 * lane) = yh;
    uint2 pa, pb;
    pa.x = pack2bf(yl.x, yl.y); pa.y = pack2bf(yl.z, yl.w);
    pb.x = pack2bf(yh.x, yh.y); pb.y = pack2bf(yh.z, yh.w);
    u16* vbrow = VB + ((size_t)b * NT + r) * DIM;
    *(uint2*)(vbrow + 4 * lane) = pa;
    *(uint2*)(vbrow + 256 + 4 * lane) = pb;
  }
}

__global__ void finalize_kernel(const float* __restrict__ acc,
                                float* __restrict__ out) {
  out[0] = acc[0] / (float)(NLAYERS * B_EP * NQ);
  out[1] = acc[1] / (float)(B_EP * NQ);
}

extern "C" void kernel_launch(void* const* d_in, const int* in_sizes, int n_in,
                              void* d_out, int out_size, void* d_ws,
                              size_t ws_size, hipStream_t stream) {
  const float* V_feat = (const float*)d_in[0];
  const float* P_feat = (const float*)d_in[1];
  const int* query_y = (const int*)d_in[2];
  const float* igb_W = (const float*)d_in[3];
  const float* igb_b = (const float*)d_in[4];
  const float* igb_s = (const float*)d_in[5];
  const float* pgb_W = (const float*)d_in[6];
  const float* pgb_b = (const float*)d_in[7];
  const float* pgb_s = (const float*)d_in[8];
  const float* alpha = (const float*)d_in[9];
  const float* beta = (const float*)d_in[10];
  float* out = (float*)d_out;

  float* ws = (float*)d_ws;
  const size_t vsz = (size_t)B_EP * NT * DIM;       // 22,937,600
  const size_t psz = (size_t)B_EP * NWAYS * DIM;    // 2,621,440
  const size_t ssz = (size_t)B_EP * NT * NT;        // 7,840,000
  const size_t wsz = (size_t)NLAYERS * DIM * DIM;   // 1,048,576
  float* ACC = ws;
  float* V = ws + 16;
  float* V0 = V + vsz;
  float* SIM = V0 + vsz;
  float* P = SIM + ssz;
  float* P0 = P + psz;
  float* VC = P0 + psz;
  float* SIMS = VC + psz;                     // B*NT*20
  float* G = SIMS + (size_t)B_EP * NT * NWAYS;  // B*400
  float* INVN = G + (size_t)B_EP * 400;       // B*NT
  u16* VB = (u16*)(INVN + (size_t)B_EP * NT);
  u16* MSGB = VB;  // alias: lifetimes disjoint (MSGB live steps 2-3 only)
  u16* PMSGB = VB + vsz;
  u16* WB = PMSGB + psz;
  u16* WPB = WB + wsz;
  u16* PAB = WPB + wsz;
  u16* S = PAB + psz;  // B*NT*32 u16

  init_accum_kernel<<<1, 64, 0, stream>>>(ACC);
  l2n_init_kernel<<<B_EP * NT, 64, 0, stream>>>(V_feat, V, V0, VB);
  l2n_init_kernel<<<B_EP * NWAYS, 64, 0, stream>>>(P_feat, P, P0, nullptr);
  cvt_bf16_kernel<<<(int)(wsz / 8 / 256), 256, 0, stream>>>(igb_W, WB,
                                                            (int)(wsz / 8));
  cvt_bf16_kernel<<<(int)(wsz / 8 / 256), 256, 0, stream>>>(pgb_W, WPB,
                                                            (int)(wsz / 8));

  for (int i = 0; i < NLAYERS; ++i) {
    sim_mfma_kernel<<<dim3(3, 3, B_EP), 64, 0, stream>>>(VB, SIM);
    topk_msg_kernel<<<B_EP * NT, 64, 0, stream>>>(SIM, V, MSGB);
    gemm_mfma_kernel<<<dim3(B_EP * NT / 128, 4), 256, 0, stream>>>(
        MSGB, WB + (size_t)i * DIM * DIM, igb_b + (size_t)i * DIM, igb_s + i, V);
    resid_l2n_kernel<<<B_EP * NT, 64, 0, stream>>>(V, V0, VB);

    p_adj_msg_kernel<<<B_EP * NWAYS, 64, 0, stream>>>(P, PMSGB);
    gemm_mfma_kernel<<<dim3(B_EP * NWAYS / 128, 4), 256, 0, stream>>>(
        PMSGB, WPB + (size_t)i * DIM * DIM, pgb_b + (size_t)i * DIM, pgb_s + i,
        P);
    resid_l2n_kernel<<<B_EP * NWAYS, 64, 0, stream>>>(P, P0, nullptr);

    vc_kernel<<<B_EP * NWAYS, 64, 0, stream>>>(V, VC);
    pa_kernel<<<B_EP * NWAYS, 64, 0, stream>>>(P, VC, alpha, PAB);

    sims_kernel<<<dim3(3, B_EP), 64, 0, stream>>>(VB, PAB, SIMS);
    gram_kernel<<<B_EP, 64, 0, stream>>>(PAB, G);
    softce_kernel<<<dim3(B_EP, 4), 256, 0, stream>>>(
        SIMS, G, query_y, beta, S, INVN, ACC, (i == NLAYERS - 1) ? 1 : 0);
    vupdate_kernel<<<dim3(B_EP, 7), 256, 0, stream>>>(V, VB, PAB, S, INVN,
                                                      beta);
  }
  finalize_kernel<<<1, 1, 0, stream>>>(ACC, out);
}

// Round 4
// 2021.628 us; speedup vs baseline: 3.9252x; 1.2676x over previous
//
#include <hip/hip_runtime.h>
#include <math.h>

#define B_EP 256
#define NT 175
#define NWAYS 20
#define KSHOT 5
#define NKS 100          // N_WAYS * N_SHOTS
#define NQ 75
#define DIM 512
#define NLAYERS 4
#define TAU_INV 10.0f
#define LOGIT_SCALE 5.0f
#define KNEI 5

typedef unsigned int u32;
typedef unsigned short u16;
typedef __attribute__((ext_vector_type(8))) short s16x8;   // 8 bf16 in 4 VGPRs
typedef __attribute__((ext_vector_type(4))) float f32x4;

__device__ __forceinline__ float waveReduceSum(float v) {
#pragma unroll
  for (int off = 32; off >= 1; off >>= 1) v += __shfl_xor(v, off);
  return v;
}

__device__ __forceinline__ u32 pack2bf(float a, float b) {
  u32 ua = __float_as_uint(a), ub = __float_as_uint(b);
  ua = (ua + 0x7FFFu + ((ua >> 16) & 1u)) >> 16;
  ub = (ub + 0x7FFFu + ((ub >> 16) & 1u)) >> 16;
  return ua | (ub << 16);
}

__device__ __forceinline__ u16 pack1bf(float a) {
  u32 ua = __float_as_uint(a);
  return (u16)((ua + 0x7FFFu + ((ua >> 16) & 1u)) >> 16);
}

__device__ __forceinline__ float bflo(u32 u) { return __uint_as_float(u << 16); }
__device__ __forceinline__ float bfhi(u32 u) { return __uint_as_float(u & 0xFFFF0000u); }
__device__ __forceinline__ float bf1(u16 h) { return __uint_as_float((u32)h << 16); }

__device__ __forceinline__ float tanh_fast(float x) {
  float e = __expf(2.f * x);
  return 1.f - 2.f * __builtin_amdgcn_rcpf(e + 1.f);
}

__device__ __forceinline__ s16x8 ldfrag(const u16* p) {
  return __builtin_bit_cast(s16x8, *(const uint4*)p);
}

__global__ void init_accum_kernel(float* acc) {
  if (threadIdx.x < 16) acc[threadIdx.x] = 0.f;
}

// f32 -> bf16 (RNE), 8 elems/thread (weights only now)
__global__ void cvt_bf16_kernel(const float* __restrict__ in,
                                u16* __restrict__ out, int n8) {
  int t = blockIdx.x * 256 + threadIdx.x;
  if (t >= n8) return;
  const float4* p = (const float4*)(in + (size_t)t * 8);
  float4 a = p[0], b = p[1];
  uint4 r;
  r.x = pack2bf(a.x, a.y);
  r.y = pack2bf(a.z, a.w);
  r.z = pack2bf(b.x, b.y);
  r.w = pack2bf(b.z, b.w);
  *(uint4*)(out + (size_t)t * 8) = r;
}

// l2-normalize rows (512 wide); optionally emit bf16 copy.
__global__ void l2n_init_kernel(const float* __restrict__ in,
                                float* __restrict__ out,
                                float* __restrict__ out0,
                                u16* __restrict__ outb) {
  const size_t row = blockIdx.x;
  const int lane = threadIdx.x;
  const float* src = in + row * DIM;
  float4 a = *(const float4*)(src + 4 * lane);
  float4 b = *(const float4*)(src + 256 + 4 * lane);
  float ss = a.x * a.x + a.y * a.y + a.z * a.z + a.w * a.w +
             b.x * b.x + b.y * b.y + b.z * b.z + b.w * b.w;
  ss = waveReduceSum(ss);
  const float inv = 1.f / fmaxf(sqrtf(ss), 1e-12f);
  a.x *= inv; a.y *= inv; a.z *= inv; a.w *= inv;
  b.x *= inv; b.y *= inv; b.z *= inv; b.w *= inv;
  *(float4*)(out + row * DIM + 4 * lane) = a;
  *(float4*)(out + row * DIM + 256 + 4 * lane) = b;
  *(float4*)(out0 + row * DIM + 4 * lane) = a;
  *(float4*)(out0 + row * DIM + 256 + 4 * lane) = b;
  if (outb) {
    uint2 pa, pb;
    pa.x = pack2bf(a.x, a.y); pa.y = pack2bf(a.z, a.w);
    pb.x = pack2bf(b.x, b.y); pb.y = pack2bf(b.z, b.w);
    *(uint2*)(outb + row * DIM + 4 * lane) = pa;
    *(uint2*)(outb + row * DIM + 256 + 4 * lane) = pb;
  }
}

// SIM = V·V^T per episode via bf16 MFMA, 64x64 tile per 1-wave block.
__global__ __launch_bounds__(64) void sim_mfma_kernel(
    const u16* __restrict__ VB, float* __restrict__ SIM) {
  const int b = blockIdx.z, it = blockIdx.y, jt = blockIdx.x;
  const int lane = threadIdx.x;
  __shared__ __align__(16) u16 As[64][32];
  __shared__ __align__(16) u16 Bs[64][32];
  const u16* Vb = VB + (size_t)b * NT * DIM;
  f32x4 acc[4][4];
#pragma unroll
  for (int m = 0; m < 4; ++m)
#pragma unroll
    for (int n = 0; n < 4; ++n) acc[m][n] = (f32x4){0.f, 0.f, 0.f, 0.f};
  const int ra = it * 64 + lane, rb = jt * 64 + lane;
  for (int kk = 0; kk < DIM; kk += 32) {
    if (ra < NT) {
      const uint4* g = (const uint4*)(Vb + (size_t)ra * DIM + kk);
#pragma unroll
      for (int q = 0; q < 4; ++q) *(uint4*)&As[lane][8 * q] = g[q];
    } else {
      uint4 z = {0, 0, 0, 0};
#pragma unroll
      for (int q = 0; q < 4; ++q) *(uint4*)&As[lane][8 * q] = z;
    }
    if (rb < NT) {
      const uint4* g = (const uint4*)(Vb + (size_t)rb * DIM + kk);
#pragma unroll
      for (int q = 0; q < 4; ++q) *(uint4*)&Bs[lane][8 * q] = g[q];
    } else {
      uint4 z = {0, 0, 0, 0};
#pragma unroll
      for (int q = 0; q < 4; ++q) *(uint4*)&Bs[lane][8 * q] = z;
    }
    __syncthreads();
    s16x8 fa[4], fb[4];
#pragma unroll
    for (int m = 0; m < 4; ++m)
      fa[m] = ldfrag(&As[m * 16 + (lane & 15)][(lane >> 4) * 8]);
#pragma unroll
    for (int n = 0; n < 4; ++n)
      fb[n] = ldfrag(&Bs[n * 16 + (lane & 15)][(lane >> 4) * 8]);
#pragma unroll
    for (int m = 0; m < 4; ++m)
#pragma unroll
      for (int n = 0; n < 4; ++n)
        acc[m][n] = __builtin_amdgcn_mfma_f32_16x16x32_bf16(fa[m], fb[n],
                                                            acc[m][n], 0, 0, 0);
    __syncthreads();
  }
  const int r_ = (lane >> 4) * 4, c_ = lane & 15;
#pragma unroll
  for (int m = 0; m < 4; ++m)
#pragma unroll
    for (int n = 0; n < 4; ++n)
#pragma unroll
      for (int j = 0; j < 4; ++j) {
        int r = it * 64 + m * 16 + r_ + j, c = jt * 64 + n * 16 + c_;
        if (r < NT && c < NT) SIM[((size_t)b * NT + r) * NT + c] = acc[m][n][j];
      }
}

// Per (b,i): top-5 of SIM row, softmax/tau, MSGB[b,i,:] = sum w_k*V[idx_k] (bf16)
__global__ void topk_msg_kernel(const float* __restrict__ SIM,
                                const float* __restrict__ V,
                                u16* __restrict__ MSGB) {
  const int row = blockIdx.x;  // b*NT + i
  const int b = row / NT;
  const int lane = threadIdx.x;
  const float* srow = SIM + (size_t)row * NT;
  float sv[3];
  int si[3];
#pragma unroll
  for (int t = 0; t < 3; ++t) {
    int j = lane + 64 * t;
    sv[t] = (j < NT) ? srow[j] : -INFINITY;
    si[t] = j;
  }
  float topv[KNEI];
  int topi[KNEI];
#pragma unroll
  for (int t = 0; t < KNEI; ++t) {
    float bv = sv[0];
    int bi = si[0];
    if (sv[1] > bv) { bv = sv[1]; bi = si[1]; }
    if (sv[2] > bv) { bv = sv[2]; bi = si[2]; }
#pragma unroll
    for (int off = 32; off >= 1; off >>= 1) {
      float ov = __shfl_xor(bv, off);
      int oi = __shfl_xor(bi, off);
      if (ov > bv || (ov == bv && oi < bi)) { bv = ov; bi = oi; }
    }
    topv[t] = bv;
    topi[t] = bi;
#pragma unroll
    for (int u = 0; u < 3; ++u)
      if (si[u] == bi) sv[u] = -INFINITY;
  }
  float w[KNEI];
  float wsum = 0.f;
#pragma unroll
  for (int t = 0; t < KNEI; ++t) {
    w[t] = expf((topv[t] - topv[0]) * TAU_INV);
    wsum += w[t];
  }
  const float invs = 1.f / wsum;
  const float* Vb = V + (size_t)b * NT * DIM;
  float a8[8] = {0.f, 0.f, 0.f, 0.f, 0.f, 0.f, 0.f, 0.f};
#pragma unroll
  for (int t = 0; t < KNEI; ++t) {
    const float4* pp = (const float4*)(Vb + (size_t)topi[t] * DIM + 8 * lane);
    float4 x0 = pp[0], x1 = pp[1];
    a8[0] += w[t] * x0.x; a8[1] += w[t] * x0.y;
    a8[2] += w[t] * x0.z; a8[3] += w[t] * x0.w;
    a8[4] += w[t] * x1.x; a8[5] += w[t] * x1.y;
    a8[6] += w[t] * x1.z; a8[7] += w[t] * x1.w;
  }
  uint4 r;
  r.x = pack2bf(a8[0] * invs, a8[1] * invs);
  r.y = pack2bf(a8[2] * invs, a8[3] * invs);
  r.z = pack2bf(a8[4] * invs, a8[5] * invs);
  r.w = pack2bf(a8[6] * invs, a8[7] * invs);
  *(uint4*)(MSGB + (size_t)row * DIM + 8 * lane) = r;
}

// C = A·W^T fused tanh + scaled residual into Vio. M % 128 == 0, N = 512.
__global__ __launch_bounds__(256) void gemm_mfma_kernel(
    const u16* __restrict__ A, const u16* __restrict__ W,
    const float* __restrict__ bias, const float* __restrict__ scale_ptr,
    float* __restrict__ Vio) {
  const int mt = blockIdx.x, nt = blockIdx.y;
  const int tid = threadIdx.x;
  const int lane = tid & 63, wave = tid >> 6;
  const int wr = wave >> 1, wc = wave & 1;
  __shared__ __align__(16) u16 As[128][32];
  __shared__ __align__(16) u16 Bs[128][32];
  const int row0 = mt * 128, col0 = nt * 128;
  f32x4 acc[4][4];
#pragma unroll
  for (int m = 0; m < 4; ++m)
#pragma unroll
    for (int n = 0; n < 4; ++n) acc[m][n] = (f32x4){0.f, 0.f, 0.f, 0.f};
  for (int kk = 0; kk < DIM; kk += 32) {
#pragma unroll
    for (int s = 0; s < 2; ++s) {
      int c = tid + 256 * s;
      int r = c >> 2, ko = (c & 3) * 8;
      *(uint4*)&As[r][ko] = *(const uint4*)(A + (size_t)(row0 + r) * DIM + kk + ko);
      *(uint4*)&Bs[r][ko] = *(const uint4*)(W + (size_t)(col0 + r) * DIM + kk + ko);
    }
    __syncthreads();
    s16x8 fa[4], fb[4];
#pragma unroll
    for (int m = 0; m < 4; ++m)
      fa[m] = ldfrag(&As[wr * 64 + m * 16 + (lane & 15)][(lane >> 4) * 8]);
#pragma unroll
    for (int n = 0; n < 4; ++n)
      fb[n] = ldfrag(&Bs[wc * 64 + n * 16 + (lane & 15)][(lane >> 4) * 8]);
#pragma unroll
    for (int m = 0; m < 4; ++m)
#pragma unroll
      for (int n = 0; n < 4; ++n)
        acc[m][n] = __builtin_amdgcn_mfma_f32_16x16x32_bf16(fa[m], fb[n],
                                                            acc[m][n], 0, 0, 0);
    __syncthreads();
  }
  const float s = *scale_ptr;
  const int r_ = (lane >> 4) * 4, c_ = lane & 15;
#pragma unroll
  for (int m = 0; m < 4; ++m)
#pragma unroll
    for (int n = 0; n < 4; ++n) {
      const int c = col0 + wc * 64 + n * 16 + c_;
      const float bc = bias[c];
#pragma unroll
      for (int j = 0; j < 4; ++j) {
        const int r = row0 + wr * 64 + m * 16 + r_ + j;
        const size_t off = (size_t)r * DIM + c;
        Vio[off] = Vio[off] + s * tanh_fast(acc[m][n][j] + bc);
      }
    }
}

// Vio = l2n(0.8*Vio + 0.2*V0); optionally emit bf16 copy.
__global__ void resid_l2n_kernel(float* __restrict__ Vio,
                                 const float* __restrict__ V0,
                                 u16* __restrict__ outb) {
  const size_t row = blockIdx.x;
  const int lane = threadIdx.x;
  float* v = Vio + row * DIM;
  const float* v0 = V0 + row * DIM;
  float4 a = *(const float4*)(v + 4 * lane);
  float4 b = *(const float4*)(v + 256 + 4 * lane);
  float4 a0 = *(const float4*)(v0 + 4 * lane);
  float4 b0 = *(const float4*)(v0 + 256 + 4 * lane);
  a.x = 0.8f * a.x + 0.2f * a0.x; a.y = 0.8f * a.y + 0.2f * a0.y;
  a.z = 0.8f * a.z + 0.2f * a0.z; a.w = 0.8f * a.w + 0.2f * a0.w;
  b.x = 0.8f * b.x + 0.2f * b0.x; b.y = 0.8f * b.y + 0.2f * b0.y;
  b.z = 0.8f * b.z + 0.2f * b0.z; b.w = 0.8f * b.w + 0.2f * b0.w;
  float ss = a.x * a.x + a.y * a.y + a.z * a.z + a.w * a.w +
             b.x * b.x + b.y * b.y + b.z * b.z + b.w * b.w;
  ss = waveReduceSum(ss);
  const float inv = 1.f / fmaxf(sqrtf(ss), 1e-12f);
  a.x *= inv; a.y *= inv; a.z *= inv; a.w *= inv;
  b.x *= inv; b.y *= inv; b.z *= inv; b.w *= inv;
  *(float4*)(v + 4 * lane) = a;
  *(float4*)(v + 256 + 4 * lane) = b;
  if (outb) {
    uint2 pa, pb;
    pa.x = pack2bf(a.x, a.y); pa.y = pack2bf(a.z, a.w);
    pb.x = pack2bf(b.x, b.y); pb.y = pack2bf(b.z, b.w);
    *(uint2*)(outb + row * DIM + 4 * lane) = pa;
    *(uint2*)(outb + row * DIM + 256 + 4 * lane) = pb;
  }
}

// Prototype adjacency + message (20 nodes), writes bf16 PMSGB.
__global__ void p_adj_msg_kernel(const float* __restrict__ P,
                                 u16* __restrict__ PMSGB) {
  const int row = blockIdx.x;  // b*NWAYS + n
  const int b = row / NWAYS;
  const int lane = threadIdx.x;
  const float* Pb = P + (size_t)b * NWAYS * DIM;
  const float* q = P + (size_t)row * DIM;
  float qv[8];
#pragma unroll
  for (int t = 0; t < 8; ++t) qv[t] = q[lane + 64 * t];
  float sims[NWAYS];
#pragma unroll
  for (int m = 0; m < NWAYS; ++m) {
    const float* pm = Pb + (size_t)m * DIM;
    float p = 0.f;
#pragma unroll
    for (int t = 0; t < 8; ++t) p += qv[t] * pm[lane + 64 * t];
    sims[m] = waveReduceSum(p);
  }
  float topv[KNEI];
  int topi[KNEI];
  bool used[NWAYS];
#pragma unroll
  for (int m = 0; m < NWAYS; ++m) used[m] = false;
#pragma unroll
  for (int t = 0; t < KNEI; ++t) {
    float bv = -INFINITY;
    int bi = 0;
#pragma unroll
    for (int m = 0; m < NWAYS; ++m)
      if (!used[m] && sims[m] > bv) { bv = sims[m]; bi = m; }
    used[bi] = true;
    topv[t] = bv;
    topi[t] = bi;
  }
  float w[KNEI];
  float wsum = 0.f;
#pragma unroll
  for (int t = 0; t < KNEI; ++t) {
    w[t] = expf((topv[t] - topv[0]) * TAU_INV);
    wsum += w[t];
  }
  const float invs = 1.f / wsum;
  float a8[8] = {0.f, 0.f, 0.f, 0.f, 0.f, 0.f, 0.f, 0.f};
#pragma unroll
  for (int t = 0; t < KNEI; ++t) {
    const float4* pp = (const float4*)(Pb + (size_t)topi[t] * DIM + 8 * lane);
    float4 x0 = pp[0], x1 = pp[1];
    a8[0] += w[t] * x0.x; a8[1] += w[t] * x0.y;
    a8[2] += w[t] * x0.z; a8[3] += w[t] * x0.w;
    a8[4] += w[t] * x1.x; a8[5] += w[t] * x1.y;
    a8[6] += w[t] * x1.z; a8[7] += w[t] * x1.w;
  }
  uint4 r;
  r.x = pack2bf(a8[0] * invs, a8[1] * invs);
  r.y = pack2bf(a8[2] * invs, a8[3] * invs);
  r.z = pack2bf(a8[4] * invs, a8[5] * invs);
  r.w = pack2bf(a8[6] * invs, a8[7] * invs);
  *(uint4*)(PMSGB + (size_t)row * DIM + 8 * lane) = r;
}

// VC[b,n] = l2n(mean_k V[b, n*5+k])
__global__ void vc_kernel(const float* __restrict__ V, float* __restrict__ VC) {
  const int row = blockIdx.x;  // b*NWAYS + n
  const int b = row / NWAYS, n = row - b * NWAYS;
  const int lane = threadIdx.x;
  const float* base = V + ((size_t)b * NT + (size_t)n * KSHOT) * DIM;
  float x[8];
  float ss = 0.f;
#pragma unroll
  for (int t = 0; t < 8; ++t) {
    int d = lane + 64 * t;
    float a = 0.f;
#pragma unroll
    for (int k = 0; k < KSHOT; ++k) a += base[(size_t)k * DIM + d];
    a *= 0.2f;
    x[t] = a;
    ss += a * a;
  }
  ss = waveReduceSum(ss);
  const float inv = 1.f / fmaxf(sqrtf(ss), 1e-12f);
#pragma unroll
  for (int t = 0; t < 8; ++t) VC[(size_t)row * DIM + lane + 64 * t] = x[t] * inv;
}

// Pa = l2n(alpha*P + (1-alpha)*VC) -> bf16 PAB only
__global__ void pa_kernel(const float* __restrict__ P,
                          const float* __restrict__ VC,
                          const float* __restrict__ alpha_ptr,
                          u16* __restrict__ PAB) {
  const size_t row = blockIdx.x;
  const int lane = threadIdx.x;
  const float alpha = *alpha_ptr, oma = 1.f - alpha;
  float4 a, b;
  {
    float4 p0 = *(const float4*)(P + row * DIM + 4 * lane);
    float4 p1 = *(const float4*)(P + row * DIM + 256 + 4 * lane);
    float4 c0 = *(const float4*)(VC + row * DIM + 4 * lane);
    float4 c1 = *(const float4*)(VC + row * DIM + 256 + 4 * lane);
    a.x = alpha * p0.x + oma * c0.x; a.y = alpha * p0.y + oma * c0.y;
    a.z = alpha * p0.z + oma * c0.z; a.w = alpha * p0.w + oma * c0.w;
    b.x = alpha * p1.x + oma * c1.x; b.y = alpha * p1.y + oma * c1.y;
    b.z = alpha * p1.z + oma * c1.z; b.w = alpha * p1.w + oma * c1.w;
  }
  float ss = a.x * a.x + a.y * a.y + a.z * a.z + a.w * a.w +
             b.x * b.x + b.y * b.y + b.z * b.z + b.w * b.w;
  ss = waveReduceSum(ss);
  const float inv = 1.f / fmaxf(sqrtf(ss), 1e-12f);
  a.x *= inv; a.y *= inv; a.z *= inv; a.w *= inv;
  b.x *= inv; b.y *= inv; b.z *= inv; b.w *= inv;
  uint2 pa, pb;
  pa.x = pack2bf(a.x, a.y); pa.y = pack2bf(a.z, a.w);
  pb.x = pack2bf(b.x, b.y); pb.y = pack2bf(b.z, b.w);
  *(uint2*)(PAB + row * DIM + 4 * lane) = pa;
  *(uint2*)(PAB + row * DIM + 256 + 4 * lane) = pb;
}

// SIMS[b,r,n] = V[b,r]·Pa[b,n], MFMA, 64-row tile per 1-wave block.
__global__ __launch_bounds__(64) void sims_kernel(const u16* __restrict__ VB,
                                                  const u16* __restrict__ PAB,
                                                  float* __restrict__ SIMS) {
  const int it = blockIdx.x, b = blockIdx.y;
  const int lane = threadIdx.x;
  __shared__ __align__(16) u16 As[64][32];
  __shared__ __align__(16) u16 Bs[32][32];
  const u16* Vb = VB + (size_t)b * NT * DIM;
  const u16* Pb = PAB + (size_t)b * NWAYS * DIM;
  f32x4 acc[4][2];
#pragma unroll
  for (int m = 0; m < 4; ++m)
#pragma unroll
    for (int n = 0; n < 2; ++n) acc[m][n] = (f32x4){0.f, 0.f, 0.f, 0.f};
  const int ra = it * 64 + lane;
  const int rb = lane & 31, kb = (lane >> 5) * 16;
  for (int kk = 0; kk < DIM; kk += 32) {
    if (ra < NT) {
      const uint4* g = (const uint4*)(Vb + (size_t)ra * DIM + kk);
#pragma unroll
      for (int q = 0; q < 4; ++q) *(uint4*)&As[lane][8 * q] = g[q];
    } else {
      uint4 z = {0, 0, 0, 0};
#pragma unroll
      for (int q = 0; q < 4; ++q) *(uint4*)&As[lane][8 * q] = z;
    }
    if (rb < NWAYS) {
      const uint4* g = (const uint4*)(Pb + (size_t)rb * DIM + kk + kb);
      *(uint4*)&Bs[rb][kb] = g[0];
      *(uint4*)&Bs[rb][kb + 8] = g[1];
    } else {
      uint4 z = {0, 0, 0, 0};
      *(uint4*)&Bs[rb][kb] = z;
      *(uint4*)&Bs[rb][kb + 8] = z;
    }
    __syncthreads();
    s16x8 fa[4], fb[2];
#pragma unroll
    for (int m = 0; m < 4; ++m)
      fa[m] = ldfrag(&As[m * 16 + (lane & 15)][(lane >> 4) * 8]);
#pragma unroll
    for (int n = 0; n < 2; ++n)
      fb[n] = ldfrag(&Bs[n * 16 + (lane & 15)][(lane >> 4) * 8]);
#pragma unroll
    for (int m = 0; m < 4; ++m)
#pragma unroll
      for (int n = 0; n < 2; ++n)
        acc[m][n] = __builtin_amdgcn_mfma_f32_16x16x32_bf16(fa[m], fb[n],
                                                            acc[m][n], 0, 0, 0);
    __syncthreads();
  }
  const int r_ = (lane >> 4) * 4, c_ = lane & 15;
#pragma unroll
  for (int m = 0; m < 4; ++m)
#pragma unroll
    for (int n = 0; n < 2; ++n)
#pragma unroll
      for (int j = 0; j < 4; ++j) {
        int r = it * 64 + m * 16 + r_ + j, c = n * 16 + c_;
        if (r < NT && c < NWAYS)
          SIMS[((size_t)b * NT + r) * NWAYS + c] = acc[m][n][j];
      }
}

// G[b] = Pa·Pa^T (20x20), one wave per episode.
__global__ __launch_bounds__(64) void gram_kernel(const u16* __restrict__ PAB,
                                                  float* __restrict__ G) {
  const int b = blockIdx.x;
  const int lane = threadIdx.x;
  __shared__ __align__(16) u16 Ps[32][32];
  const u16* Pb = PAB + (size_t)b * NWAYS * DIM;
  f32x4 acc[2][2];
#pragma unroll
  for (int m = 0; m < 2; ++m)
#pragma unroll
    for (int n = 0; n < 2; ++n) acc[m][n] = (f32x4){0.f, 0.f, 0.f, 0.f};
  const int rb = lane & 31, kb = (lane >> 5) * 16;
  for (int kk = 0; kk < DIM; kk += 32) {
    if (rb < NWAYS) {
      const uint4* g = (const uint4*)(Pb + (size_t)rb * DIM + kk + kb);
      *(uint4*)&Ps[rb][kb] = g[0];
      *(uint4*)&Ps[rb][kb + 8] = g[1];
    } else {
      uint4 z = {0, 0, 0, 0};
      *(uint4*)&Ps[rb][kb] = z;
      *(uint4*)&Ps[rb][kb + 8] = z;
    }
    __syncthreads();
    s16x8 f[2];
#pragma unroll
    for (int m = 0; m < 2; ++m)
      f[m] = ldfrag(&Ps[m * 16 + (lane & 15)][(lane >> 4) * 8]);
#pragma unroll
    for (int m = 0; m < 2; ++m)
#pragma unroll
      for (int n = 0; n < 2; ++n)
        acc[m][n] = __builtin_amdgcn_mfma_f32_16x16x32_bf16(f[m], f[n],
                                                            acc[m][n], 0, 0, 0);
    __syncthreads();
  }
  const int r_ = (lane >> 4) * 4, c_ = lane & 15;
#pragma unroll
  for (int m = 0; m < 2; ++m)
#pragma unroll
    for (int n = 0; n < 2; ++n)
#pragma unroll
      for (int j = 0; j < 4; ++j) {
        int r = m * 16 + r_ + j, c = n * 16 + c_;
        if (r < NWAYS && c < NWAYS)
          G[(size_t)b * 400 + r * NWAYS + c] = acc[m][n][j];
      }
}

// Softmax + CE from scalars: per row computes soft weights S (bf16), invn,
// and for query rows the CE loss via logits = 5*invn*(beta*sims+(1-beta)*s·G).
// CE/acc accumulated per-thread, block-reduced, ONE atomicAdd per block.
__global__ __launch_bounds__(256) void softce_kernel(
    const float* __restrict__ SIMS, const float* __restrict__ G,
    const int* __restrict__ qy, const float* __restrict__ beta_ptr,
    u16* __restrict__ S, float* __restrict__ INVN, float* __restrict__ accum,
    int is_last) {
  const int b = blockIdx.x, yq = blockIdx.y;
  const int tid = threadIdx.x;
  const int wave = tid >> 6, lane = tid & 63;
  const int half = lane >> 5, n = lane & 31;
  __shared__ float gl[NWAYS][32];
  __shared__ float red[8];
  for (int c = tid; c < NWAYS * 32; c += 256) {
    int m = c >> 5, nn2 = c & 31;
    gl[m][nn2] = (nn2 < NWAYS) ? G[(size_t)b * 400 + m * NWAYS + nn2] : 0.f;
  }
  __syncthreads();
  const float beta = *beta_ptr, omb = 1.f - beta;
  const int r0 = 44 * yq;
  const int rend = min(44 * (yq + 1), NT);
  const int npairs = (rend - r0 + 1) >> 1;
  float ce_acc = 0.f, ac_acc = 0.f;
  for (int pr = wave; pr < npairs; pr += 4) {
    const int r = r0 + 2 * pr + half;
    if (r < rend) {
      float s = (n < NWAYS) ? SIMS[((size_t)b * NT + r) * NWAYS + n] : -1e30f;
      float mx = s;
#pragma unroll
      for (int off = 16; off >= 1; off >>= 1)
        mx = fmaxf(mx, __shfl_xor(mx, off, 32));
      float e = __expf((s - mx) * TAU_INV);
      float wsum = e, dsum = e * s;
#pragma unroll
      for (int off = 16; off >= 1; off >>= 1) {
        wsum += __shfl_xor(wsum, off, 32);
        dsum += __shfl_xor(dsum, off, 32);
      }
      float sg = 0.f;
#pragma unroll
      for (int m = 0; m < NWAYS; ++m) sg += __shfl(e, m, 32) * gl[m][n];
      float qsum = e * sg;
#pragma unroll
      for (int off = 16; off >= 1; off >>= 1)
        qsum += __shfl_xor(qsum, off, 32);
      const float iw = 1.f / wsum;
      const float dN = dsum * iw;
      const float qN = qsum * iw * iw;
      const float nn2 = beta * beta + 2.f * beta * omb * dN + omb * omb * qN;
      const float invn = 1.f / fmaxf(sqrtf(nn2), 1e-12f);
      S[((size_t)b * NT + r) * 32 + n] = pack1bf(e * iw);
      if (n == 0) INVN[(size_t)b * NT + r] = invn;
      if (r >= NKS) {
        float l = (n < NWAYS)
                      ? LOGIT_SCALE * invn * (beta * s + omb * sg * iw)
                      : -1e30f;
        float bv = l;
        int bi = n;
#pragma unroll
        for (int off = 16; off >= 1; off >>= 1) {
          float ov = __shfl_xor(bv, off, 32);
          int oi = __shfl_xor(bi, off, 32);
          if (ov > bv || (ov == bv && oi < bi)) { bv = ov; bi = oi; }
        }
        float se = __expf(l - bv);
#pragma unroll
        for (int off = 16; off >= 1; off >>= 1) se += __shfl_xor(se, off, 32);
        const int y = qy[b * NQ + (r - NKS)];
        const float ly = __shfl(l, y, 32);
        if (n == 0) {
          ce_acc += bv + __logf(se) - ly;
          ac_acc += (bi == y) ? 1.f : 0.f;
        }
      }
    }
  }
  // block reduction: wave-reduce, then 4 partials through LDS, 1 atomic/block
  ce_acc = waveReduceSum(ce_acc);
  ac_acc = waveReduceSum(ac_acc);
  if (lane == 0) {
    red[wave] = ce_acc;
    red[4 + wave] = ac_acc;
  }
  __syncthreads();
  if (tid == 0) {
    float ce = red[0] + red[1] + red[2] + red[3];
    atomicAdd(&accum[0], ce);
    if (is_last) {
      float ac = red[4] + red[5] + red[6] + red[7];
      atomicAdd(&accum[1], ac);
    }
  }
}

// V = invn*(beta*V + (1-beta)*S·Pa), writes f32 V and bf16 VB.
__global__ __launch_bounds__(256) void vupdate_kernel(
    float* __restrict__ V, u16* __restrict__ VB, const u16* __restrict__ PAB,
    const u16* __restrict__ S, const float* __restrict__ INVN,
    const float* __restrict__ beta_ptr) {
  const int b = blockIdx.x, yc = blockIdx.y;  // 0..6
  const int tid = threadIdx.x, wave = tid >> 6, lane = tid & 63;
  __shared__ __align__(16) u16 palds[NWAYS][DIM];
  __shared__ __align__(16) u16 slds[25][32];
  __shared__ float ilds[25];
  const int r0 = 25 * yc;
  for (int c = tid; c < NWAYS * (DIM / 8); c += 256) {
    int m = c >> 6, ko = (c & 63) * 8;
    *(uint4*)&palds[m][ko] =
        *(const uint4*)(PAB + ((size_t)b * NWAYS + m) * DIM + ko);
  }
  for (int c = tid; c < 100; c += 256) {
    *(uint4*)&slds[0][c * 8] =
        *(const uint4*)(S + ((size_t)b * NT + r0) * 32 + c * 8);
  }
  if (tid < 25) ilds[tid] = INVN[(size_t)b * NT + r0 + tid];
  __syncthreads();
  const float beta = *beta_ptr, omb = 1.f - beta;
  for (int t = wave; t < 25; t += 4) {
    const int r = r0 + t;
    float* vrow = V + ((size_t)b * NT + r) * DIM;
    float4 vl = *(const float4*)(vrow + 4 * lane);
    float4 vh = *(const float4*)(vrow + 256 + 4 * lane);
    float4 gL = {0.f, 0.f, 0.f, 0.f}, gH = {0.f, 0.f, 0.f, 0.f};
#pragma unroll
    for (int m = 0; m < NWAYS; ++m) {
      const float w = bf1(slds[t][m]);
      uint2 p0 = *(const uint2*)&palds[m][4 * lane];
      uint2 p1 = *(const uint2*)&palds[m][256 + 4 * lane];
      gL.x += w * bflo(p0.x); gL.y += w * bfhi(p0.x);
      gL.z += w * bflo(p0.y); gL.w += w * bfhi(p0.y);
      gH.x += w * bflo(p1.x); gH.y += w * bfhi(p1.x);
      gH.z += w * bflo(p1.y); gH.w += w * bfhi(p1.y);
    }
    const float inv = ilds[t];
    float4 yl, yh;
    yl.x = inv * (beta * vl.x + omb * gL.x);
    yl.y = inv * (beta * vl.y + omb * gL.y);
    yl.z = inv * (beta * vl.z + omb * gL.z);
    yl.w = inv * (beta * vl.w + omb * gL.w);
    yh.x = inv * (beta * vh.x + omb * gH.x);
    yh.y = inv * (beta * vh.y + omb * gH.y);
    yh.z = inv * (beta * vh.z + omb * gH.z);
    yh.w = inv * (beta * vh.w + omb * gH.w);
    *(float4*)(vrow + 4 * lane) = yl;
    *(float4*)(vrow + 256 + 4 * lane) = yh;
    uint2 pa, pb;
    pa.x = pack2bf(yl.x, yl.y); pa.y = pack2bf(yl.z, yl.w);
    pb.x = pack2bf(yh.x, yh.y); pb.y = pack2bf(yh.z, yh.w);
    u16* vbrow = VB + ((size_t)b * NT + r) * DIM;
    *(uint2*)(vbrow + 4 * lane) = pa;
    *(uint2*)(vbrow + 256 + 4 * lane) = pb;
  }
}

__global__ void finalize_kernel(const float* __restrict__ acc,
                                float* __restrict__ out) {
  out[0] = acc[0] / (float)(NLAYERS * B_EP * NQ);
  out[1] = acc[1] / (float)(B_EP * NQ);
}

extern "C" void kernel_launch(void* const* d_in, const int* in_sizes, int n_in,
                              void* d_out, int out_size, void* d_ws,
                              size_t ws_size, hipStream_t stream) {
  const float* V_feat = (const float*)d_in[0];
  const float* P_feat = (const float*)d_in[1];
  const int* query_y = (const int*)d_in[2];
  const float* igb_W = (const float*)d_in[3];
  const float* igb_b = (const float*)d_in[4];
  const float* igb_s = (const float*)d_in[5];
  const float* pgb_W = (const float*)d_in[6];
  const float* pgb_b = (const float*)d_in[7];
  const float* pgb_s = (const float*)d_in[8];
  const float* alpha = (const float*)d_in[9];
  const float* beta = (const float*)d_in[10];
  float* out = (float*)d_out;

  float* ws = (float*)d_ws;
  const size_t vsz = (size_t)B_EP * NT * DIM;       // 22,937,600
  const size_t psz = (size_t)B_EP * NWAYS * DIM;    // 2,621,440
  const size_t ssz = (size_t)B_EP * NT * NT;        // 7,840,000
  const size_t wsz = (size_t)NLAYERS * DIM * DIM;   // 1,048,576
  float* ACC = ws;
  float* V = ws + 16;
  float* V0 = V + vsz;
  float* SIM = V0 + vsz;
  float* P = SIM + ssz;
  float* P0 = P + psz;
  float* VC = P0 + psz;
  float* SIMS = VC + psz;                     // B*NT*20
  float* G = SIMS + (size_t)B_EP * NT * NWAYS;  // B*400
  float* INVN = G + (size_t)B_EP * 400;       // B*NT
  u16* VB = (u16*)(INVN + (size_t)B_EP * NT);
  u16* MSGB = VB;  // alias: lifetimes disjoint (MSGB live steps 2-3 only)
  u16* PMSGB = VB + vsz;
  u16* WB = PMSGB + psz;
  u16* WPB = WB + wsz;
  u16* PAB = WPB + wsz;
  u16* S = PAB + psz;  // B*NT*32 u16

  init_accum_kernel<<<1, 64, 0, stream>>>(ACC);
  l2n_init_kernel<<<B_EP * NT, 64, 0, stream>>>(V_feat, V, V0, VB);
  l2n_init_kernel<<<B_EP * NWAYS, 64, 0, stream>>>(P_feat, P, P0, nullptr);
  cvt_bf16_kernel<<<(int)(wsz / 8 / 256), 256, 0, stream>>>(igb_W, WB,
                                                            (int)(wsz / 8));
  cvt_bf16_kernel<<<(int)(wsz / 8 / 256), 256, 0, stream>>>(pgb_W, WPB,
                                                            (int)(wsz / 8));

  for (int i = 0; i < NLAYERS; ++i) {
    sim_mfma_kernel<<<dim3(3, 3, B_EP), 64, 0, stream>>>(VB, SIM);
    topk_msg_kernel<<<B_EP * NT, 64, 0, stream>>>(SIM, V, MSGB);
    gemm_mfma_kernel<<<dim3(B_EP * NT / 128, 4), 256, 0, stream>>>(
        MSGB, WB + (size_t)i * DIM * DIM, igb_b + (size_t)i * DIM, igb_s + i, V);
    resid_l2n_kernel<<<B_EP * NT, 64, 0, stream>>>(V, V0, VB);

    p_adj_msg_kernel<<<B_EP * NWAYS, 64, 0, stream>>>(P, PMSGB);
    gemm_mfma_kernel<<<dim3(B_EP * NWAYS / 128, 4), 256, 0, stream>>>(
        PMSGB, WPB + (size_t)i * DIM * DIM, pgb_b + (size_t)i * DIM, pgb_s + i,
        P);
    resid_l2n_kernel<<<B_EP * NWAYS, 64, 0, stream>>>(P, P0, nullptr);

    vc_kernel<<<B_EP * NWAYS, 64, 0, stream>>>(V, VC);
    pa_kernel<<<B_EP * NWAYS, 64, 0, stream>>>(P, VC, alpha, PAB);

    sims_kernel<<<dim3(3, B_EP), 64, 0, stream>>>(VB, PAB, SIMS);
    gram_kernel<<<B_EP, 64, 0, stream>>>(PAB, G);
    softce_kernel<<<dim3(B_EP, 4), 256, 0, stream>>>(
        SIMS, G, query_y, beta, S, INVN, ACC, (i == NLAYERS - 1) ? 1 : 0);
    vupdate_kernel<<<dim3(B_EP, 7), 256, 0, stream>>>(V, VB, PAB, S, INVN,
                                                      beta);
  }
  finalize_kernel<<<1, 1, 0, stream>>>(ACC, out);
}

// Round 5
// 1927.339 us; speedup vs baseline: 4.1172x; 1.0489x over previous
//
#include <hip/hip_runtime.h>
#include <math.h>

#define B_EP 256
#define NT 175
#define NWAYS 20
#define KSHOT 5
#define NKS 100          // N_WAYS * N_SHOTS
#define NQ 75
#define DIM 512
#define NLAYERS 4
#define TAU_INV 10.0f
#define LOGIT_SCALE 5.0f
#define KNEI 5

typedef unsigned int u32;
typedef unsigned short u16;
typedef __attribute__((ext_vector_type(8))) short s16x8;   // 8 bf16 in 4 VGPRs
typedef __attribute__((ext_vector_type(4))) float f32x4;

__device__ __forceinline__ float waveReduceSum(float v) {
#pragma unroll
  for (int off = 32; off >= 1; off >>= 1) v += __shfl_xor(v, off);
  return v;
}

__device__ __forceinline__ u32 pack2bf(float a, float b) {
  u32 ua = __float_as_uint(a), ub = __float_as_uint(b);
  ua = (ua + 0x7FFFu + ((ua >> 16) & 1u)) >> 16;
  ub = (ub + 0x7FFFu + ((ub >> 16) & 1u)) >> 16;
  return ua | (ub << 16);
}

__device__ __forceinline__ u16 pack1bf(float a) {
  u32 ua = __float_as_uint(a);
  return (u16)((ua + 0x7FFFu + ((ua >> 16) & 1u)) >> 16);
}

__device__ __forceinline__ float bflo(u32 u) { return __uint_as_float(u << 16); }
__device__ __forceinline__ float bfhi(u32 u) { return __uint_as_float(u & 0xFFFF0000u); }
__device__ __forceinline__ float bf1(u16 h) { return __uint_as_float((u32)h << 16); }

__device__ __forceinline__ float tanh_fast(float x) {
  float e = __expf(2.f * x);
  return 1.f - 2.f * __builtin_amdgcn_rcpf(e + 1.f);
}

__device__ __forceinline__ s16x8 ldfrag(const u16* p) {
  return __builtin_bit_cast(s16x8, *(const uint4*)p);
}

// async global->LDS, 16B per lane. LDS dest = wave-uniform base + lane*16.
__device__ __forceinline__ void gload16(const u16* g, u16* l) {
  __builtin_amdgcn_global_load_lds(
      (const __attribute__((address_space(1))) void*)g,
      (__attribute__((address_space(3))) void*)l, 16, 0, 0);
}

__global__ void init_accum_kernel(float* acc) {
  if (threadIdx.x < 16) acc[threadIdx.x] = 0.f;
}

// f32 -> bf16 (RNE), 8 elems/thread (weights only)
__global__ void cvt_bf16_kernel(const float* __restrict__ in,
                                u16* __restrict__ out, int n8) {
  int t = blockIdx.x * 256 + threadIdx.x;
  if (t >= n8) return;
  const float4* p = (const float4*)(in + (size_t)t * 8);
  float4 a = p[0], b = p[1];
  uint4 r;
  r.x = pack2bf(a.x, a.y);
  r.y = pack2bf(a.z, a.w);
  r.z = pack2bf(b.x, b.y);
  r.w = pack2bf(b.z, b.w);
  *(uint4*)(out + (size_t)t * 8) = r;
}

// l2-normalize rows (512 wide); optionally emit bf16 copy.
__global__ void l2n_init_kernel(const float* __restrict__ in,
                                float* __restrict__ out,
                                float* __restrict__ out0,
                                u16* __restrict__ outb) {
  const size_t row = blockIdx.x;
  const int lane = threadIdx.x;
  const float* src = in + row * DIM;
  float4 a = *(const float4*)(src + 4 * lane);
  float4 b = *(const float4*)(src + 256 + 4 * lane);
  float ss = a.x * a.x + a.y * a.y + a.z * a.z + a.w * a.w +
             b.x * b.x + b.y * b.y + b.z * b.z + b.w * b.w;
  ss = waveReduceSum(ss);
  const float inv = 1.f / fmaxf(sqrtf(ss), 1e-12f);
  a.x *= inv; a.y *= inv; a.z *= inv; a.w *= inv;
  b.x *= inv; b.y *= inv; b.z *= inv; b.w *= inv;
  *(float4*)(out + row * DIM + 4 * lane) = a;
  *(float4*)(out + row * DIM + 256 + 4 * lane) = b;
  *(float4*)(out0 + row * DIM + 4 * lane) = a;
  *(float4*)(out0 + row * DIM + 256 + 4 * lane) = b;
  if (outb) {
    uint2 pa, pb;
    pa.x = pack2bf(a.x, a.y); pa.y = pack2bf(a.z, a.w);
    pb.x = pack2bf(b.x, b.y); pb.y = pack2bf(b.z, b.w);
    *(uint2*)(outb + row * DIM + 4 * lane) = pa;
    *(uint2*)(outb + row * DIM + 256 + 4 * lane) = pb;
  }
}

// SIM = V·V^T per episode via bf16 MFMA, 64x64 tile per 1-wave block.
// LDS layout [q][64][8]: q = K-chunk, so global_load_lds dest = base+lane*16.
__global__ __launch_bounds__(64) void sim_mfma_kernel(
    const u16* __restrict__ VB, float* __restrict__ SIM) {
  const int b = blockIdx.z, it = blockIdx.y, jt = blockIdx.x;
  const int lane = threadIdx.x;
  __shared__ __align__(16) u16 As2[4][64][8];
  __shared__ __align__(16) u16 Bs2[4][64][8];
  const u16* Vb = VB + (size_t)b * NT * DIM;
  f32x4 acc[4][4];
#pragma unroll
  for (int m = 0; m < 4; ++m)
#pragma unroll
    for (int n = 0; n < 4; ++n) acc[m][n] = (f32x4){0.f, 0.f, 0.f, 0.f};
  const int ra = it * 64 + lane, rb = jt * 64 + lane;
  for (int kk = 0; kk < DIM; kk += 32) {
    if (ra < NT) {
#pragma unroll
      for (int q = 0; q < 4; ++q)
        gload16(Vb + (size_t)ra * DIM + kk + q * 8, &As2[q][lane][0]);
    }
    if (rb < NT) {
#pragma unroll
      for (int q = 0; q < 4; ++q)
        gload16(Vb + (size_t)rb * DIM + kk + q * 8, &Bs2[q][lane][0]);
    }
    __syncthreads();
    s16x8 fa[4], fb[4];
#pragma unroll
    for (int m = 0; m < 4; ++m)
      fa[m] = ldfrag(&As2[lane >> 4][m * 16 + (lane & 15)][0]);
#pragma unroll
    for (int n = 0; n < 4; ++n)
      fb[n] = ldfrag(&Bs2[lane >> 4][n * 16 + (lane & 15)][0]);
#pragma unroll
    for (int m = 0; m < 4; ++m)
#pragma unroll
      for (int n = 0; n < 4; ++n)
        acc[m][n] = __builtin_amdgcn_mfma_f32_16x16x32_bf16(fa[m], fb[n],
                                                            acc[m][n], 0, 0, 0);
    __syncthreads();
  }
  const int r_ = (lane >> 4) * 4, c_ = lane & 15;
#pragma unroll
  for (int m = 0; m < 4; ++m)
#pragma unroll
    for (int n = 0; n < 4; ++n)
#pragma unroll
      for (int j = 0; j < 4; ++j) {
        int r = it * 64 + m * 16 + r_ + j, c = jt * 64 + n * 16 + c_;
        if (r < NT && c < NT) SIM[((size_t)b * NT + r) * NT + c] = acc[m][n][j];
      }
}

// Per (b,i): top-5 of SIM row, softmax/tau, MSGB[b,i,:] = sum w_k*V[idx_k].
// 4 blocks x 4 waves per episode; physical id p: b=p&255, yq=p>>8 so all 4
// blocks of an episode share p%8 -> same XCD -> episode V gathers hit L2.
__global__ __launch_bounds__(256) void topk_msg_kernel(
    const float* __restrict__ SIM, const float* __restrict__ V,
    u16* __restrict__ MSGB) {
  const int p = blockIdx.x;
  const int b = p & 255, yq = p >> 8;
  const int tid = threadIdx.x, wave = tid >> 6, lane = tid & 63;
  const int wq = yq * 4 + wave;  // 0..15
  const float* Vb = V + (size_t)b * NT * DIM;
  for (int row = wq; row < NT; row += 16) {
    const float* srow = SIM + ((size_t)b * NT + row) * NT;
    float sv[3];
    int si[3];
#pragma unroll
    for (int t = 0; t < 3; ++t) {
      int j = lane + 64 * t;
      sv[t] = (j < NT) ? srow[j] : -INFINITY;
      si[t] = j;
    }
    float topv[KNEI];
    int topi[KNEI];
#pragma unroll
    for (int t = 0; t < KNEI; ++t) {
      float bv = sv[0];
      int bi = si[0];
      if (sv[1] > bv) { bv = sv[1]; bi = si[1]; }
      if (sv[2] > bv) { bv = sv[2]; bi = si[2]; }
#pragma unroll
      for (int off = 32; off >= 1; off >>= 1) {
        float ov = __shfl_xor(bv, off);
        int oi = __shfl_xor(bi, off);
        if (ov > bv || (ov == bv && oi < bi)) { bv = ov; bi = oi; }
      }
      topv[t] = bv;
      topi[t] = bi;
#pragma unroll
      for (int u = 0; u < 3; ++u)
        if (si[u] == bi) sv[u] = -INFINITY;
    }
    float w[KNEI];
    float wsum = 0.f;
#pragma unroll
    for (int t = 0; t < KNEI; ++t) {
      w[t] = expf((topv[t] - topv[0]) * TAU_INV);
      wsum += w[t];
    }
    const float invs = 1.f / wsum;
    float a8[8] = {0.f, 0.f, 0.f, 0.f, 0.f, 0.f, 0.f, 0.f};
#pragma unroll
    for (int t = 0; t < KNEI; ++t) {
      const float4* pp = (const float4*)(Vb + (size_t)topi[t] * DIM + 8 * lane);
      float4 x0 = pp[0], x1 = pp[1];
      a8[0] += w[t] * x0.x; a8[1] += w[t] * x0.y;
      a8[2] += w[t] * x0.z; a8[3] += w[t] * x0.w;
      a8[4] += w[t] * x1.x; a8[5] += w[t] * x1.y;
      a8[6] += w[t] * x1.z; a8[7] += w[t] * x1.w;
    }
    uint4 r;
    r.x = pack2bf(a8[0] * invs, a8[1] * invs);
    r.y = pack2bf(a8[2] * invs, a8[3] * invs);
    r.z = pack2bf(a8[4] * invs, a8[5] * invs);
    r.w = pack2bf(a8[6] * invs, a8[7] * invs);
    *(uint4*)(MSGB + ((size_t)b * NT + row) * DIM + 8 * lane) = r;
  }
}

// C = A·W^T fused tanh + scaled residual into Vio. M % 128 == 0, N = 512.
// Staging via global_load_lds (LDS layout linear in lane order: byte = c*16).
__global__ __launch_bounds__(256) void gemm_mfma_kernel(
    const u16* __restrict__ A, const u16* __restrict__ W,
    const float* __restrict__ bias, const float* __restrict__ scale_ptr,
    float* __restrict__ Vio) {
  const int mt = blockIdx.x, nt = blockIdx.y;
  const int tid = threadIdx.x;
  const int lane = tid & 63, wave = tid >> 6;
  const int wr = wave >> 1, wc = wave & 1;
  __shared__ __align__(16) u16 As[128][32];
  __shared__ __align__(16) u16 Bs[128][32];
  const int row0 = mt * 128, col0 = nt * 128;
  f32x4 acc[4][4];
#pragma unroll
  for (int m = 0; m < 4; ++m)
#pragma unroll
    for (int n = 0; n < 4; ++n) acc[m][n] = (f32x4){0.f, 0.f, 0.f, 0.f};
  for (int kk = 0; kk < DIM; kk += 32) {
#pragma unroll
    for (int s = 0; s < 2; ++s) {
      int c = tid + 256 * s;
      int r = c >> 2, ko = (c & 3) * 8;
      gload16(A + (size_t)(row0 + r) * DIM + kk + ko, &As[0][0] + (size_t)c * 8);
      gload16(W + (size_t)(col0 + r) * DIM + kk + ko, &Bs[0][0] + (size_t)c * 8);
    }
    __syncthreads();
    s16x8 fa[4], fb[4];
#pragma unroll
    for (int m = 0; m < 4; ++m)
      fa[m] = ldfrag(&As[wr * 64 + m * 16 + (lane & 15)][(lane >> 4) * 8]);
#pragma unroll
    for (int n = 0; n < 4; ++n)
      fb[n] = ldfrag(&Bs[wc * 64 + n * 16 + (lane & 15)][(lane >> 4) * 8]);
#pragma unroll
    for (int m = 0; m < 4; ++m)
#pragma unroll
      for (int n = 0; n < 4; ++n)
        acc[m][n] = __builtin_amdgcn_mfma_f32_16x16x32_bf16(fa[m], fb[n],
                                                            acc[m][n], 0, 0, 0);
    __syncthreads();
  }
  const float s = *scale_ptr;
  const int r_ = (lane >> 4) * 4, c_ = lane & 15;
#pragma unroll
  for (int m = 0; m < 4; ++m)
#pragma unroll
    for (int n = 0; n < 4; ++n) {
      const int c = col0 + wc * 64 + n * 16 + c_;
      const float bc = bias[c];
#pragma unroll
      for (int j = 0; j < 4; ++j) {
        const int r = row0 + wr * 64 + m * 16 + r_ + j;
        const size_t off = (size_t)r * DIM + c;
        Vio[off] = Vio[off] + s * tanh_fast(acc[m][n][j] + bc);
      }
    }
}

// Vio = l2n(0.8*Vio + 0.2*V0); optionally emit bf16 copy.
__global__ void resid_l2n_kernel(float* __restrict__ Vio,
                                 const float* __restrict__ V0,
                                 u16* __restrict__ outb) {
  const size_t row = blockIdx.x;
  const int lane = threadIdx.x;
  float* v = Vio + row * DIM;
  const float* v0 = V0 + row * DIM;
  float4 a = *(const float4*)(v + 4 * lane);
  float4 b = *(const float4*)(v + 256 + 4 * lane);
  float4 a0 = *(const float4*)(v0 + 4 * lane);
  float4 b0 = *(const float4*)(v0 + 256 + 4 * lane);
  a.x = 0.8f * a.x + 0.2f * a0.x; a.y = 0.8f * a.y + 0.2f * a0.y;
  a.z = 0.8f * a.z + 0.2f * a0.z; a.w = 0.8f * a.w + 0.2f * a0.w;
  b.x = 0.8f * b.x + 0.2f * b0.x; b.y = 0.8f * b.y + 0.2f * b0.y;
  b.z = 0.8f * b.z + 0.2f * b0.z; b.w = 0.8f * b.w + 0.2f * b0.w;
  float ss = a.x * a.x + a.y * a.y + a.z * a.z + a.w * a.w +
             b.x * b.x + b.y * b.y + b.z * b.z + b.w * b.w;
  ss = waveReduceSum(ss);
  const float inv = 1.f / fmaxf(sqrtf(ss), 1e-12f);
  a.x *= inv; a.y *= inv; a.z *= inv; a.w *= inv;
  b.x *= inv; b.y *= inv; b.z *= inv; b.w *= inv;
  *(float4*)(v + 4 * lane) = a;
  *(float4*)(v + 256 + 4 * lane) = b;
  if (outb) {
    uint2 pa, pb;
    pa.x = pack2bf(a.x, a.y); pa.y = pack2bf(a.z, a.w);
    pb.x = pack2bf(b.x, b.y); pb.y = pack2bf(b.z, b.w);
    *(uint2*)(outb + row * DIM + 4 * lane) = pa;
    *(uint2*)(outb + row * DIM + 256 + 4 * lane) = pb;
  }
}

// Prototype adjacency + message (20 nodes), writes bf16 PMSGB.
__global__ void p_adj_msg_kernel(const float* __restrict__ P,
                                 u16* __restrict__ PMSGB) {
  const int row = blockIdx.x;  // b*NWAYS + n
  const int b = row / NWAYS;
  const int lane = threadIdx.x;
  const float* Pb = P + (size_t)b * NWAYS * DIM;
  const float* q = P + (size_t)row * DIM;
  float qv[8];
#pragma unroll
  for (int t = 0; t < 8; ++t) qv[t] = q[lane + 64 * t];
  float sims[NWAYS];
#pragma unroll
  for (int m = 0; m < NWAYS; ++m) {
    const float* pm = Pb + (size_t)m * DIM;
    float p = 0.f;
#pragma unroll
    for (int t = 0; t < 8; ++t) p += qv[t] * pm[lane + 64 * t];
    sims[m] = waveReduceSum(p);
  }
  float topv[KNEI];
  int topi[KNEI];
  bool used[NWAYS];
#pragma unroll
  for (int m = 0; m < NWAYS; ++m) used[m] = false;
#pragma unroll
  for (int t = 0; t < KNEI; ++t) {
    float bv = -INFINITY;
    int bi = 0;
#pragma unroll
    for (int m = 0; m < NWAYS; ++m)
      if (!used[m] && sims[m] > bv) { bv = sims[m]; bi = m; }
    used[bi] = true;
    topv[t] = bv;
    topi[t] = bi;
  }
  float w[KNEI];
  float wsum = 0.f;
#pragma unroll
  for (int t = 0; t < KNEI; ++t) {
    w[t] = expf((topv[t] - topv[0]) * TAU_INV);
    wsum += w[t];
  }
  const float invs = 1.f / wsum;
  float a8[8] = {0.f, 0.f, 0.f, 0.f, 0.f, 0.f, 0.f, 0.f};
#pragma unroll
  for (int t = 0; t < KNEI; ++t) {
    const float4* pp = (const float4*)(Pb + (size_t)topi[t] * DIM + 8 * lane);
    float4 x0 = pp[0], x1 = pp[1];
    a8[0] += w[t] * x0.x; a8[1] += w[t] * x0.y;
    a8[2] += w[t] * x0.z; a8[3] += w[t] * x0.w;
    a8[4] += w[t] * x1.x; a8[5] += w[t] * x1.y;
    a8[6] += w[t] * x1.z; a8[7] += w[t] * x1.w;
  }
  uint4 r;
  r.x = pack2bf(a8[0] * invs, a8[1] * invs);
  r.y = pack2bf(a8[2] * invs, a8[3] * invs);
  r.z = pack2bf(a8[4] * invs, a8[5] * invs);
  r.w = pack2bf(a8[6] * invs, a8[7] * invs);
  *(uint4*)(PMSGB + (size_t)row * DIM + 8 * lane) = r;
}

// Fused: VC = l2n(mean_k V[b,n*5+k]); Pa = l2n(alpha*P + (1-alpha)*VC) -> bf16
__global__ void vcpa_kernel(const float* __restrict__ V,
                            const float* __restrict__ P,
                            const float* __restrict__ alpha_ptr,
                            u16* __restrict__ PAB) {
  const int row = blockIdx.x;  // b*NWAYS + n
  const int bb = row / NWAYS, n = row - bb * NWAYS;
  const int lane = threadIdx.x;
  const float* base = V + ((size_t)bb * NT + (size_t)n * KSHOT) * DIM;
  float4 a = {0.f, 0.f, 0.f, 0.f}, b = {0.f, 0.f, 0.f, 0.f};
#pragma unroll
  for (int k = 0; k < KSHOT; ++k) {
    float4 x0 = *(const float4*)(base + (size_t)k * DIM + 4 * lane);
    float4 x1 = *(const float4*)(base + (size_t)k * DIM + 256 + 4 * lane);
    a.x += x0.x; a.y += x0.y; a.z += x0.z; a.w += x0.w;
    b.x += x1.x; b.y += x1.y; b.z += x1.z; b.w += x1.w;
  }
  float ss = a.x * a.x + a.y * a.y + a.z * a.z + a.w * a.w +
             b.x * b.x + b.y * b.y + b.z * b.z + b.w * b.w;
  ss = waveReduceSum(ss);
  const float inv = 1.f / fmaxf(sqrtf(ss), 1e-12f);  // mean scale cancels in l2n
  a.x *= inv; a.y *= inv; a.z *= inv; a.w *= inv;
  b.x *= inv; b.y *= inv; b.z *= inv; b.w *= inv;
  const float alpha = *alpha_ptr, oma = 1.f - alpha;
  {
    float4 p0 = *(const float4*)(P + (size_t)row * DIM + 4 * lane);
    float4 p1 = *(const float4*)(P + (size_t)row * DIM + 256 + 4 * lane);
    a.x = alpha * p0.x + oma * a.x; a.y = alpha * p0.y + oma * a.y;
    a.z = alpha * p0.z + oma * a.z; a.w = alpha * p0.w + oma * a.w;
    b.x = alpha * p1.x + oma * b.x; b.y = alpha * p1.y + oma * b.y;
    b.z = alpha * p1.z + oma * b.z; b.w = alpha * p1.w + oma * b.w;
  }
  float s2 = a.x * a.x + a.y * a.y + a.z * a.z + a.w * a.w +
             b.x * b.x + b.y * b.y + b.z * b.z + b.w * b.w;
  s2 = waveReduceSum(s2);
  const float inv2 = 1.f / fmaxf(sqrtf(s2), 1e-12f);
  a.x *= inv2; a.y *= inv2; a.z *= inv2; a.w *= inv2;
  b.x *= inv2; b.y *= inv2; b.z *= inv2; b.w *= inv2;
  uint2 pa, pb;
  pa.x = pack2bf(a.x, a.y); pa.y = pack2bf(a.z, a.w);
  pb.x = pack2bf(b.x, b.y); pb.y = pack2bf(b.z, b.w);
  *(uint2*)(PAB + (size_t)row * DIM + 4 * lane) = pa;
  *(uint2*)(PAB + (size_t)row * DIM + 256 + 4 * lane) = pb;
}

// SIMS[b,r,n] = V[b,r]·Pa[b,n], MFMA, 64-row tile per 1-wave block.
__global__ __launch_bounds__(64) void sims_kernel(const u16* __restrict__ VB,
                                                  const u16* __restrict__ PAB,
                                                  float* __restrict__ SIMS) {
  const int it = blockIdx.x, b = blockIdx.y;
  const int lane = threadIdx.x;
  __shared__ __align__(16) u16 As[64][32];
  __shared__ __align__(16) u16 Bs[32][32];
  const u16* Vb = VB + (size_t)b * NT * DIM;
  const u16* Pb = PAB + (size_t)b * NWAYS * DIM;
  f32x4 acc[4][2];
#pragma unroll
  for (int m = 0; m < 4; ++m)
#pragma unroll
    for (int n = 0; n < 2; ++n) acc[m][n] = (f32x4){0.f, 0.f, 0.f, 0.f};
  const int ra = it * 64 + lane;
  const int rb = lane & 31, kb = (lane >> 5) * 16;
  for (int kk = 0; kk < DIM; kk += 32) {
    if (ra < NT) {
      const uint4* g = (const uint4*)(Vb + (size_t)ra * DIM + kk);
#pragma unroll
      for (int q = 0; q < 4; ++q) *(uint4*)&As[lane][8 * q] = g[q];
    } else {
      uint4 z = {0, 0, 0, 0};
#pragma unroll
      for (int q = 0; q < 4; ++q) *(uint4*)&As[lane][8 * q] = z;
    }
    if (rb < NWAYS) {
      const uint4* g = (const uint4*)(Pb + (size_t)rb * DIM + kk + kb);
      *(uint4*)&Bs[rb][kb] = g[0];
      *(uint4*)&Bs[rb][kb + 8] = g[1];
    } else {
      uint4 z = {0, 0, 0, 0};
      *(uint4*)&Bs[rb][kb] = z;
      *(uint4*)&Bs[rb][kb + 8] = z;
    }
    __syncthreads();
    s16x8 fa[4], fb[2];
#pragma unroll
    for (int m = 0; m < 4; ++m)
      fa[m] = ldfrag(&As[m * 16 + (lane & 15)][(lane >> 4) * 8]);
#pragma unroll
    for (int n = 0; n < 2; ++n)
      fb[n] = ldfrag(&Bs[n * 16 + (lane & 15)][(lane >> 4) * 8]);
#pragma unroll
    for (int m = 0; m < 4; ++m)
#pragma unroll
      for (int n = 0; n < 2; ++n)
        acc[m][n] = __builtin_amdgcn_mfma_f32_16x16x32_bf16(fa[m], fb[n],
                                                            acc[m][n], 0, 0, 0);
    __syncthreads();
  }
  const int r_ = (lane >> 4) * 4, c_ = lane & 15;
#pragma unroll
  for (int m = 0; m < 4; ++m)
#pragma unroll
    for (int n = 0; n < 2; ++n)
#pragma unroll
      for (int j = 0; j < 4; ++j) {
        int r = it * 64 + m * 16 + r_ + j, c = n * 16 + c_;
        if (r < NT && c < NWAYS)
          SIMS[((size_t)b * NT + r) * NWAYS + c] = acc[m][n][j];
      }
}

// G[b] = Pa·Pa^T (20x20), one wave per episode.
__global__ __launch_bounds__(64) void gram_kernel(const u16* __restrict__ PAB,
                                                  float* __restrict__ G) {
  const int b = blockIdx.x;
  const int lane = threadIdx.x;
  __shared__ __align__(16) u16 Ps[32][32];
  const u16* Pb = PAB + (size_t)b * NWAYS * DIM;
  f32x4 acc[2][2];
#pragma unroll
  for (int m = 0; m < 2; ++m)
#pragma unroll
    for (int n = 0; n < 2; ++n) acc[m][n] = (f32x4){0.f, 0.f, 0.f, 0.f};
  const int rb = lane & 31, kb = (lane >> 5) * 16;
  for (int kk = 0; kk < DIM; kk += 32) {
    if (rb < NWAYS) {
      const uint4* g = (const uint4*)(Pb + (size_t)rb * DIM + kk + kb);
      *(uint4*)&Ps[rb][kb] = g[0];
      *(uint4*)&Ps[rb][kb + 8] = g[1];
    } else {
      uint4 z = {0, 0, 0, 0};
      *(uint4*)&Ps[rb][kb] = z;
      *(uint4*)&Ps[rb][kb + 8] = z;
    }
    __syncthreads();
    s16x8 f[2];
#pragma unroll
    for (int m = 0; m < 2; ++m)
      f[m] = ldfrag(&Ps[m * 16 + (lane & 15)][(lane >> 4) * 8]);
#pragma unroll
    for (int m = 0; m < 2; ++m)
#pragma unroll
      for (int n = 0; n < 2; ++n)
        acc[m][n] = __builtin_amdgcn_mfma_f32_16x16x32_bf16(f[m], f[n],
                                                            acc[m][n], 0, 0, 0);
    __syncthreads();
  }
  const int r_ = (lane >> 4) * 4, c_ = lane & 15;
#pragma unroll
  for (int m = 0; m < 2; ++m)
#pragma unroll
    for (int n = 0; n < 2; ++n)
#pragma unroll
      for (int j = 0; j < 4; ++j) {
        int r = m * 16 + r_ + j, c = n * 16 + c_;
        if (r < NWAYS && c < NWAYS)
          G[(size_t)b * 400 + r * NWAYS + c] = acc[m][n][j];
      }
}

// Softmax + CE from scalars; ONE atomicAdd per block.
__global__ __launch_bounds__(256) void softce_kernel(
    const float* __restrict__ SIMS, const float* __restrict__ G,
    const int* __restrict__ qy, const float* __restrict__ beta_ptr,
    u16* __restrict__ S, float* __restrict__ INVN, float* __restrict__ accum,
    int is_last) {
  const int b = blockIdx.x, yq = blockIdx.y;
  const int tid = threadIdx.x;
  const int wave = tid >> 6, lane = tid & 63;
  const int half = lane >> 5, n = lane & 31;
  __shared__ float gl[NWAYS][32];
  __shared__ float red[8];
  for (int c = tid; c < NWAYS * 32; c += 256) {
    int m = c >> 5, nn2 = c & 31;
    gl[m][nn2] = (nn2 < NWAYS) ? G[(size_t)b * 400 + m * NWAYS + nn2] : 0.f;
  }
  __syncthreads();
  const float beta = *beta_ptr, omb = 1.f - beta;
  const int r0 = 44 * yq;
  const int rend = min(44 * (yq + 1), NT);
  const int npairs = (rend - r0 + 1) >> 1;
  float ce_acc = 0.f, ac_acc = 0.f;
  for (int pr = wave; pr < npairs; pr += 4) {
    const int r = r0 + 2 * pr + half;
    if (r < rend) {
      float s = (n < NWAYS) ? SIMS[((size_t)b * NT + r) * NWAYS + n] : -1e30f;
      float mx = s;
#pragma unroll
      for (int off = 16; off >= 1; off >>= 1)
        mx = fmaxf(mx, __shfl_xor(mx, off, 32));
      float e = __expf((s - mx) * TAU_INV);
      float wsum = e, dsum = e * s;
#pragma unroll
      for (int off = 16; off >= 1; off >>= 1) {
        wsum += __shfl_xor(wsum, off, 32);
        dsum += __shfl_xor(dsum, off, 32);
      }
      float sg = 0.f;
#pragma unroll
      for (int m = 0; m < NWAYS; ++m) sg += __shfl(e, m, 32) * gl[m][n];
      float qsum = e * sg;
#pragma unroll
      for (int off = 16; off >= 1; off >>= 1)
        qsum += __shfl_xor(qsum, off, 32);
      const float iw = 1.f / wsum;
      const float dN = dsum * iw;
      const float qN = qsum * iw * iw;
      const float nn2 = beta * beta + 2.f * beta * omb * dN + omb * omb * qN;
      const float invn = 1.f / fmaxf(sqrtf(nn2), 1e-12f);
      S[((size_t)b * NT + r) * 32 + n] = pack1bf(e * iw);
      if (n == 0) INVN[(size_t)b * NT + r] = invn;
      if (r >= NKS) {
        float l = (n < NWAYS)
                      ? LOGIT_SCALE * invn * (beta * s + omb * sg * iw)
                      : -1e30f;
        float bv = l;
        int bi = n;
#pragma unroll
        for (int off = 16; off >= 1; off >>= 1) {
          float ov = __shfl_xor(bv, off, 32);
          int oi = __shfl_xor(bi, off, 32);
          if (ov > bv || (ov == bv && oi < bi)) { bv = ov; bi = oi; }
        }
        float se = __expf(l - bv);
#pragma unroll
        for (int off = 16; off >= 1; off >>= 1) se += __shfl_xor(se, off, 32);
        const int y = qy[b * NQ + (r - NKS)];
        const float ly = __shfl(l, y, 32);
        if (n == 0) {
          ce_acc += bv + __logf(se) - ly;
          ac_acc += (bi == y) ? 1.f : 0.f;
        }
      }
    }
  }
  ce_acc = waveReduceSum(ce_acc);
  ac_acc = waveReduceSum(ac_acc);
  if (lane == 0) {
    red[wave] = ce_acc;
    red[4 + wave] = ac_acc;
  }
  __syncthreads();
  if (tid == 0) {
    float ce = red[0] + red[1] + red[2] + red[3];
    atomicAdd(&accum[0], ce);
    if (is_last) {
      float ac = red[4] + red[5] + red[6] + red[7];
      atomicAdd(&accum[1], ac);
    }
  }
}

// V = invn*(beta*V + (1-beta)*S·Pa), writes f32 V and bf16 VB.
__global__ __launch_bounds__(256) void vupdate_kernel(
    float* __restrict__ V, u16* __restrict__ VB, const u16* __restrict__ PAB,
    const u16* __restrict__ S, const float* __restrict__ INVN,
    const float* __restrict__ beta_ptr) {
  const int b = blockIdx.x, yc = blockIdx.y;  // 0..6
  const int tid = threadIdx.x, wave = tid >> 6, lane = tid & 63;
  __shared__ __align__(16) u16 palds[NWAYS][DIM];
  __shared__ __align__(16) u16 slds[25][32];
  __shared__ float ilds[25];
  const int r0 = 25 * yc;
  for (int c = tid; c < NWAYS * (DIM / 8); c += 256) {
    int m = c >> 6, ko = (c & 63) * 8;
    *(uint4*)&palds[m][ko] =
        *(const uint4*)(PAB + ((size_t)b * NWAYS + m) * DIM + ko);
  }
  for (int c = tid; c < 100; c += 256) {
    *(uint4*)&slds[0][c * 8] =
        *(const uint4*)(S + ((size_t)b * NT + r0) * 32 + c * 8);
  }
  if (tid < 25) ilds[tid] = INVN[(size_t)b * NT + r0 + tid];
  __syncthreads();
  const float beta = *beta_ptr, omb = 1.f - beta;
  for (int t = wave; t < 25; t += 4) {
    const int r = r0 + t;
    float* vrow = V + ((size_t)b * NT + r) * DIM;
    float4 vl = *(const float4*)(vrow + 4 * lane);
    float4 vh = *(const float4*)(vrow + 256 + 4 * lane);
    float4 gL = {0.f, 0.f, 0.f, 0.f}, gH = {0.f, 0.f, 0.f, 0.f};
#pragma unroll
    for (int m = 0; m < NWAYS; ++m) {
      const float w = bf1(slds[t][m]);
      uint2 p0 = *(const uint2*)&palds[m][4 * lane];
      uint2 p1 = *(const uint2*)&palds[m][256 + 4 * lane];
      gL.x += w * bflo(p0.x); gL.y += w * bfhi(p0.x);
      gL.z += w * bflo(p0.y); gL.w += w * bfhi(p0.y);
      gH.x += w * bflo(p1.x); gH.y += w * bfhi(p1.x);
      gH.z += w * bflo(p1.y); gH.w += w * bfhi(p1.y);
    }
    const float inv = ilds[t];
    float4 yl, yh;
    yl.x = inv * (beta * vl.x + omb * gL.x);
    yl.y = inv * (beta * vl.y + omb * gL.y);
    yl.z = inv * (beta * vl.z + omb * gL.z);
    yl.w = inv * (beta * vl.w + omb * gL.w);
    yh.x = inv * (beta * vh.x + omb * gH.x);
    yh.y = inv * (beta * vh.y + omb * gH.y);
    yh.z = inv * (beta * vh.z + omb * gH.z);
    yh.w = inv * (beta * vh.w + omb * gH.w);
    *(float4*)(vrow + 4 * lane) = yl;
    *(float4*)(vrow + 256 + 4 * lane) = yh;
    uint2 pa, pb;
    pa.x = pack2bf(yl.x, yl.y); pa.y = pack2bf(yl.z, yl.w);
    pb.x = pack2bf(yh.x, yh.y); pb.y = pack2bf(yh.z, yh.w);
    u16* vbrow = VB + ((size_t)b * NT + r) * DIM;
    *(uint2*)(vbrow + 4 * lane) = pa;
    *(uint2*)(vbrow + 256 + 4 * lane) = pb;
  }
}

__global__ void finalize_kernel(const float* __restrict__ acc,
                                float* __restrict__ out) {
  out[0] = acc[0] / (float)(NLAYERS * B_EP * NQ);
  out[1] = acc[1] / (float)(B_EP * NQ);
}

extern "C" void kernel_launch(void* const* d_in, const int* in_sizes, int n_in,
                              void* d_out, int out_size, void* d_ws,
                              size_t ws_size, hipStream_t stream) {
  const float* V_feat = (const float*)d_in[0];
  const float* P_feat = (const float*)d_in[1];
  const int* query_y = (const int*)d_in[2];
  const float* igb_W = (const float*)d_in[3];
  const float* igb_b = (const float*)d_in[4];
  const float* igb_s = (const float*)d_in[5];
  const float* pgb_W = (const float*)d_in[6];
  const float* pgb_b = (const float*)d_in[7];
  const float* pgb_s = (const float*)d_in[8];
  const float* alpha = (const float*)d_in[9];
  const float* beta = (const float*)d_in[10];
  float* out = (float*)d_out;

  float* ws = (float*)d_ws;
  const size_t vsz = (size_t)B_EP * NT * DIM;       // 22,937,600
  const size_t psz = (size_t)B_EP * NWAYS * DIM;    // 2,621,440
  const size_t ssz = (size_t)B_EP * NT * NT;        // 7,840,000
  const size_t wsz = (size_t)NLAYERS * DIM * DIM;   // 1,048,576
  float* ACC = ws;
  float* V = ws + 16;
  float* V0 = V + vsz;
  float* SIM = V0 + vsz;
  float* P = SIM + ssz;
  float* P0 = P + psz;
  float* VC = P0 + psz;  // unused (kept for layout stability)
  float* SIMS = VC + psz;                       // B*NT*20
  float* G = SIMS + (size_t)B_EP * NT * NWAYS;  // B*400
  float* INVN = G + (size_t)B_EP * 400;         // B*NT
  u16* VB = (u16*)(INVN + (size_t)B_EP * NT);
  u16* MSGB = VB;  // alias: lifetimes disjoint (MSGB live steps 2-3 only)
  u16* PMSGB = VB + vsz;
  u16* WB = PMSGB + psz;
  u16* WPB = WB + wsz;
  u16* PAB = WPB + wsz;
  u16* S = PAB + psz;  // B*NT*32 u16

  init_accum_kernel<<<1, 64, 0, stream>>>(ACC);
  l2n_init_kernel<<<B_EP * NT, 64, 0, stream>>>(V_feat, V, V0, VB);
  l2n_init_kernel<<<B_EP * NWAYS, 64, 0, stream>>>(P_feat, P, P0, nullptr);
  cvt_bf16_kernel<<<(int)(wsz / 8 / 256), 256, 0, stream>>>(igb_W, WB,
                                                            (int)(wsz / 8));
  cvt_bf16_kernel<<<(int)(wsz / 8 / 256), 256, 0, stream>>>(pgb_W, WPB,
                                                            (int)(wsz / 8));

  for (int i = 0; i < NLAYERS; ++i) {
    sim_mfma_kernel<<<dim3(3, 3, B_EP), 64, 0, stream>>>(VB, SIM);
    topk_msg_kernel<<<4 * B_EP, 256, 0, stream>>>(SIM, V, MSGB);
    gemm_mfma_kernel<<<dim3(B_EP * NT / 128, 4), 256, 0, stream>>>(
        MSGB, WB + (size_t)i * DIM * DIM, igb_b + (size_t)i * DIM, igb_s + i, V);
    resid_l2n_kernel<<<B_EP * NT, 64, 0, stream>>>(V, V0, VB);

    p_adj_msg_kernel<<<B_EP * NWAYS, 64, 0, stream>>>(P, PMSGB);
    gemm_mfma_kernel<<<dim3(B_EP * NWAYS / 128, 4), 256, 0, stream>>>(
        PMSGB, WPB + (size_t)i * DIM * DIM, pgb_b + (size_t)i * DIM, pgb_s + i,
        P);
    resid_l2n_kernel<<<B_EP * NWAYS, 64, 0, stream>>>(P, P0, nullptr);

    vcpa_kernel<<<B_EP * NWAYS, 64, 0, stream>>>(V, P, alpha, PAB);

    sims_kernel<<<dim3(3, B_EP), 64, 0, stream>>>(VB, PAB, SIMS);
    gram_kernel<<<B_EP, 64, 0, stream>>>(PAB, G);
    softce_kernel<<<dim3(B_EP, 4), 256, 0, stream>>>(
        SIMS, G, query_y, beta, S, INVN, ACC, (i == NLAYERS - 1) ? 1 : 0);
    vupdate_kernel<<<dim3(B_EP, 7), 256, 0, stream>>>(V, VB, PAB, S, INVN,
                                                      beta);
  }
  finalize_kernel<<<1, 1, 0, stream>>>(ACC, out);
}

// Round 6
// 1711.343 us; speedup vs baseline: 4.6369x; 1.1262x over previous
//
#include <hip/hip_runtime.h>
#include <math.h>

#define B_EP 256
#define NT 175
#define NWAYS 20
#define KSHOT 5
#define NKS 100          // N_WAYS * N_SHOTS
#define NQ 75
#define DIM 512
#define NLAYERS 4
#define TAU_INV 10.0f
#define LOGIT_SCALE 5.0f
#define KNEI 5

typedef unsigned int u32;
typedef unsigned short u16;
typedef __attribute__((ext_vector_type(8))) short s16x8;   // 8 bf16 in 4 VGPRs
typedef __attribute__((ext_vector_type(4))) float f32x4;

__device__ __forceinline__ float waveReduceSum(float v) {
#pragma unroll
  for (int off = 32; off >= 1; off >>= 1) v += __shfl_xor(v, off);
  return v;
}

__device__ __forceinline__ u32 pack2bf(float a, float b) {
  u32 ua = __float_as_uint(a), ub = __float_as_uint(b);
  ua = (ua + 0x7FFFu + ((ua >> 16) & 1u)) >> 16;
  ub = (ub + 0x7FFFu + ((ub >> 16) & 1u)) >> 16;
  return ua | (ub << 16);
}

__device__ __forceinline__ u16 pack1bf(float a) {
  u32 ua = __float_as_uint(a);
  return (u16)((ua + 0x7FFFu + ((ua >> 16) & 1u)) >> 16);
}

__device__ __forceinline__ float bflo(u32 u) { return __uint_as_float(u << 16); }
__device__ __forceinline__ float bfhi(u32 u) { return __uint_as_float(u & 0xFFFF0000u); }
__device__ __forceinline__ float bf1(u16 h) { return __uint_as_float((u32)h << 16); }

__device__ __forceinline__ float tanh_fast(float x) {
  float e = __expf(2.f * x);
  return 1.f - 2.f * __builtin_amdgcn_rcpf(e + 1.f);
}

__device__ __forceinline__ s16x8 ldfrag(const u16* p) {
  return __builtin_bit_cast(s16x8, *(const uint4*)p);
}

// async global->LDS, 16B per lane. LDS dest = wave-uniform base + lane*16.
__device__ __forceinline__ void gload16(const u16* g, u16* l) {
  __builtin_amdgcn_global_load_lds(
      (const __attribute__((address_space(1))) void*)g,
      (__attribute__((address_space(3))) void*)l, 16, 0, 0);
}

__global__ void init_accum_kernel(float* acc) {
  if (threadIdx.x < 16) acc[threadIdx.x] = 0.f;
}

// f32 -> bf16 (RNE), 8 elems/thread (weights only)
__global__ void cvt_bf16_kernel(const float* __restrict__ in,
                                u16* __restrict__ out, int n8) {
  int t = blockIdx.x * 256 + threadIdx.x;
  if (t >= n8) return;
  const float4* p = (const float4*)(in + (size_t)t * 8);
  float4 a = p[0], b = p[1];
  uint4 r;
  r.x = pack2bf(a.x, a.y);
  r.y = pack2bf(a.z, a.w);
  r.z = pack2bf(b.x, b.y);
  r.w = pack2bf(b.z, b.w);
  *(uint4*)(out + (size_t)t * 8) = r;
}

// l2-normalize rows (512 wide); optionally emit bf16 copy.
__global__ void l2n_init_kernel(const float* __restrict__ in,
                                float* __restrict__ out,
                                float* __restrict__ out0,
                                u16* __restrict__ outb) {
  const size_t row = blockIdx.x;
  const int lane = threadIdx.x;
  const float* src = in + row * DIM;
  float4 a = *(const float4*)(src + 4 * lane);
  float4 b = *(const float4*)(src + 256 + 4 * lane);
  float ss = a.x * a.x + a.y * a.y + a.z * a.z + a.w * a.w +
             b.x * b.x + b.y * b.y + b.z * b.z + b.w * b.w;
  ss = waveReduceSum(ss);
  const float inv = 1.f / fmaxf(sqrtf(ss), 1e-12f);
  a.x *= inv; a.y *= inv; a.z *= inv; a.w *= inv;
  b.x *= inv; b.y *= inv; b.z *= inv; b.w *= inv;
  *(float4*)(out + row * DIM + 4 * lane) = a;
  *(float4*)(out + row * DIM + 256 + 4 * lane) = b;
  *(float4*)(out0 + row * DIM + 4 * lane) = a;
  *(float4*)(out0 + row * DIM + 256 + 4 * lane) = b;
  if (outb) {
    uint2 pa, pb;
    pa.x = pack2bf(a.x, a.y); pa.y = pack2bf(a.z, a.w);
    pb.x = pack2bf(b.x, b.y); pb.y = pack2bf(b.z, b.w);
    *(uint2*)(outb + row * DIM + 4 * lane) = pa;
    *(uint2*)(outb + row * DIM + 256 + 4 * lane) = pb;
  }
}

// SIM = V·V^T per episode via bf16 MFMA, 64x64 tile per 1-wave block.
// LDS layout [q][64][8]: q = K-chunk, so global_load_lds dest = base+lane*16.
__global__ __launch_bounds__(64) void sim_mfma_kernel(
    const u16* __restrict__ VB, float* __restrict__ SIM) {
  const int b = blockIdx.z, it = blockIdx.y, jt = blockIdx.x;
  const int lane = threadIdx.x;
  __shared__ __align__(16) u16 As2[4][64][8];
  __shared__ __align__(16) u16 Bs2[4][64][8];
  const u16* Vb = VB + (size_t)b * NT * DIM;
  f32x4 acc[4][4];
#pragma unroll
  for (int m = 0; m < 4; ++m)
#pragma unroll
    for (int n = 0; n < 4; ++n) acc[m][n] = (f32x4){0.f, 0.f, 0.f, 0.f};
  const int ra = it * 64 + lane, rb = jt * 64 + lane;
  for (int kk = 0; kk < DIM; kk += 32) {
    if (ra < NT) {
#pragma unroll
      for (int q = 0; q < 4; ++q)
        gload16(Vb + (size_t)ra * DIM + kk + q * 8, &As2[q][lane][0]);
    }
    if (rb < NT) {
#pragma unroll
      for (int q = 0; q < 4; ++q)
        gload16(Vb + (size_t)rb * DIM + kk + q * 8, &Bs2[q][lane][0]);
    }
    __syncthreads();
    s16x8 fa[4], fb[4];
#pragma unroll
    for (int m = 0; m < 4; ++m)
      fa[m] = ldfrag(&As2[lane >> 4][m * 16 + (lane & 15)][0]);
#pragma unroll
    for (int n = 0; n < 4; ++n)
      fb[n] = ldfrag(&Bs2[lane >> 4][n * 16 + (lane & 15)][0]);
#pragma unroll
    for (int m = 0; m < 4; ++m)
#pragma unroll
      for (int n = 0; n < 4; ++n)
        acc[m][n] = __builtin_amdgcn_mfma_f32_16x16x32_bf16(fa[m], fb[n],
                                                            acc[m][n], 0, 0, 0);
    __syncthreads();
  }
  const int r_ = (lane >> 4) * 4, c_ = lane & 15;
#pragma unroll
  for (int m = 0; m < 4; ++m)
#pragma unroll
    for (int n = 0; n < 4; ++n)
#pragma unroll
      for (int j = 0; j < 4; ++j) {
        int r = it * 64 + m * 16 + r_ + j, c = jt * 64 + n * 16 + c_;
        if (r < NT && c < NT) SIM[((size_t)b * NT + r) * NT + c] = acc[m][n][j];
      }
}

// Per (b,i): top-5 of SIM row, softmax/tau, MSGB[b,i,:] = sum w_k*VB[idx_k].
// 4 blocks x 4 waves per episode; physical id p: b=p&255, yq=p>>8 so all 4
// blocks of an episode share p%8 -> same XCD -> episode V gathers hit L2.
__global__ __launch_bounds__(256) void topk_msg_kernel(
    const float* __restrict__ SIM, const u16* __restrict__ VB,
    u16* __restrict__ MSGB) {
  const int p = blockIdx.x;
  const int b = p & 255, yq = p >> 8;
  const int tid = threadIdx.x, wave = tid >> 6, lane = tid & 63;
  const int wq = yq * 4 + wave;  // 0..15
  const u16* Vb = VB + (size_t)b * NT * DIM;
  for (int row = wq; row < NT; row += 16) {
    const float* srow = SIM + ((size_t)b * NT + row) * NT;
    float sv[3];
    int si[3];
#pragma unroll
    for (int t = 0; t < 3; ++t) {
      int j = lane + 64 * t;
      sv[t] = (j < NT) ? srow[j] : -INFINITY;
      si[t] = j;
    }
    float topv[KNEI];
    int topi[KNEI];
#pragma unroll
    for (int t = 0; t < KNEI; ++t) {
      float bv = sv[0];
      int bi = si[0];
      if (sv[1] > bv) { bv = sv[1]; bi = si[1]; }
      if (sv[2] > bv) { bv = sv[2]; bi = si[2]; }
#pragma unroll
      for (int off = 32; off >= 1; off >>= 1) {
        float ov = __shfl_xor(bv, off);
        int oi = __shfl_xor(bi, off);
        if (ov > bv || (ov == bv && oi < bi)) { bv = ov; bi = oi; }
      }
      topv[t] = bv;
      topi[t] = bi;
#pragma unroll
      for (int u = 0; u < 3; ++u)
        if (si[u] == bi) sv[u] = -INFINITY;
    }
    float w[KNEI];
    float wsum = 0.f;
#pragma unroll
    for (int t = 0; t < KNEI; ++t) {
      w[t] = expf((topv[t] - topv[0]) * TAU_INV);
      wsum += w[t];
    }
    const float invs = 1.f / wsum;
    float a8[8] = {0.f, 0.f, 0.f, 0.f, 0.f, 0.f, 0.f, 0.f};
#pragma unroll
    for (int t = 0; t < KNEI; ++t) {
      uint4 v = *(const uint4*)(Vb + (size_t)topi[t] * DIM + 8 * lane);
      a8[0] += w[t] * bflo(v.x); a8[1] += w[t] * bfhi(v.x);
      a8[2] += w[t] * bflo(v.y); a8[3] += w[t] * bfhi(v.y);
      a8[4] += w[t] * bflo(v.z); a8[5] += w[t] * bfhi(v.z);
      a8[6] += w[t] * bflo(v.w); a8[7] += w[t] * bfhi(v.w);
    }
    uint4 r;
    r.x = pack2bf(a8[0] * invs, a8[1] * invs);
    r.y = pack2bf(a8[2] * invs, a8[3] * invs);
    r.z = pack2bf(a8[4] * invs, a8[5] * invs);
    r.w = pack2bf(a8[6] * invs, a8[7] * invs);
    *(uint4*)(MSGB + ((size_t)b * NT + row) * DIM + 8 * lane) = r;
  }
}

// C = A·W^T fused tanh + scaled residual into Vio. M % 128 == 0, N = 512.
__global__ __launch_bounds__(256) void gemm_mfma_kernel(
    const u16* __restrict__ A, const u16* __restrict__ W,
    const float* __restrict__ bias, const float* __restrict__ scale_ptr,
    float* __restrict__ Vio) {
  const int mt = blockIdx.x, nt = blockIdx.y;
  const int tid = threadIdx.x;
  const int lane = tid & 63, wave = tid >> 6;
  const int wr = wave >> 1, wc = wave & 1;
  __shared__ __align__(16) u16 As[128][32];
  __shared__ __align__(16) u16 Bs[128][32];
  const int row0 = mt * 128, col0 = nt * 128;
  f32x4 acc[4][4];
#pragma unroll
  for (int m = 0; m < 4; ++m)
#pragma unroll
    for (int n = 0; n < 4; ++n) acc[m][n] = (f32x4){0.f, 0.f, 0.f, 0.f};
  for (int kk = 0; kk < DIM; kk += 32) {
#pragma unroll
    for (int s = 0; s < 2; ++s) {
      int c = tid + 256 * s;
      int r = c >> 2, ko = (c & 3) * 8;
      gload16(A + (size_t)(row0 + r) * DIM + kk + ko, &As[0][0] + (size_t)c * 8);
      gload16(W + (size_t)(col0 + r) * DIM + kk + ko, &Bs[0][0] + (size_t)c * 8);
    }
    __syncthreads();
    s16x8 fa[4], fb[4];
#pragma unroll
    for (int m = 0; m < 4; ++m)
      fa[m] = ldfrag(&As[wr * 64 + m * 16 + (lane & 15)][(lane >> 4) * 8]);
#pragma unroll
    for (int n = 0; n < 4; ++n)
      fb[n] = ldfrag(&Bs[wc * 64 + n * 16 + (lane & 15)][(lane >> 4) * 8]);
#pragma unroll
    for (int m = 0; m < 4; ++m)
#pragma unroll
      for (int n = 0; n < 4; ++n)
        acc[m][n] = __builtin_amdgcn_mfma_f32_16x16x32_bf16(fa[m], fb[n],
                                                            acc[m][n], 0, 0, 0);
    __syncthreads();
  }
  const float s = *scale_ptr;
  const int r_ = (lane >> 4) * 4, c_ = lane & 15;
#pragma unroll
  for (int m = 0; m < 4; ++m)
#pragma unroll
    for (int n = 0; n < 4; ++n) {
      const int c = col0 + wc * 64 + n * 16 + c_;
      const float bc = bias[c];
#pragma unroll
      for (int j = 0; j < 4; ++j) {
        const int r = row0 + wr * 64 + m * 16 + r_ + j;
        const size_t off = (size_t)r * DIM + c;
        Vio[off] = Vio[off] + s * tanh_fast(acc[m][n][j] + bc);
      }
    }
}

// Vio = l2n(0.8*Vio + 0.2*V0); optionally emit bf16 copy.
__global__ void resid_l2n_kernel(float* __restrict__ Vio,
                                 const float* __restrict__ V0,
                                 u16* __restrict__ outb) {
  const size_t row = blockIdx.x;
  const int lane = threadIdx.x;
  float* v = Vio + row * DIM;
  const float* v0 = V0 + row * DIM;
  float4 a = *(const float4*)(v + 4 * lane);
  float4 b = *(const float4*)(v + 256 + 4 * lane);
  float4 a0 = *(const float4*)(v0 + 4 * lane);
  float4 b0 = *(const float4*)(v0 + 256 + 4 * lane);
  a.x = 0.8f * a.x + 0.2f * a0.x; a.y = 0.8f * a.y + 0.2f * a0.y;
  a.z = 0.8f * a.z + 0.2f * a0.z; a.w = 0.8f * a.w + 0.2f * a0.w;
  b.x = 0.8f * b.x + 0.2f * b0.x; b.y = 0.8f * b.y + 0.2f * b0.y;
  b.z = 0.8f * b.z + 0.2f * b0.z; b.w = 0.8f * b.w + 0.2f * b0.w;
  float ss = a.x * a.x + a.y * a.y + a.z * a.z + a.w * a.w +
             b.x * b.x + b.y * b.y + b.z * b.z + b.w * b.w;
  ss = waveReduceSum(ss);
  const float inv = 1.f / fmaxf(sqrtf(ss), 1e-12f);
  a.x *= inv; a.y *= inv; a.z *= inv; a.w *= inv;
  b.x *= inv; b.y *= inv; b.z *= inv; b.w *= inv;
  *(float4*)(v + 4 * lane) = a;
  *(float4*)(v + 256 + 4 * lane) = b;
  if (outb) {
    uint2 pa, pb;
    pa.x = pack2bf(a.x, a.y); pa.y = pack2bf(a.z, a.w);
    pb.x = pack2bf(b.x, b.y); pb.y = pack2bf(b.z, b.w);
    *(uint2*)(outb + row * DIM + 4 * lane) = pa;
    *(uint2*)(outb + row * DIM + 256 + 4 * lane) = pb;
  }
}

// Fused prototype branch: per-episode block (64 thr). LDS-stage bf16 P,
// 20x20 gram via MFMA, per-row serial top-5 + softmax, LDS-gather message.
__global__ __launch_bounds__(64) void p_branch_kernel(
    const u16* __restrict__ PB, u16* __restrict__ PMSGB) {
  const int b = blockIdx.x;
  const int lane = threadIdx.x;
  __shared__ __align__(16) u16 Pl[32][520];  // pad 520: break b128 bank conflict
  __shared__ float Gl[NWAYS][NWAYS];
  __shared__ float Wl[NWAYS][KNEI];
  __shared__ int Il[NWAYS][KNEI];
  const u16* Pb = PB + (size_t)b * NWAYS * DIM;
  for (int c = lane; c < 32 * 64; c += 64) {
    int m = c >> 6, ko = (c & 63) * 8;
    uint4 v = {0, 0, 0, 0};
    if (m < NWAYS) v = *(const uint4*)(Pb + (size_t)m * DIM + ko);
    *(uint4*)&Pl[m][ko] = v;
  }
  __syncthreads();
  f32x4 acc[2][2];
#pragma unroll
  for (int m = 0; m < 2; ++m)
#pragma unroll
    for (int n = 0; n < 2; ++n) acc[m][n] = (f32x4){0.f, 0.f, 0.f, 0.f};
  for (int kk = 0; kk < DIM; kk += 32) {
    s16x8 f[2];
#pragma unroll
    for (int m = 0; m < 2; ++m)
      f[m] = ldfrag(&Pl[m * 16 + (lane & 15)][kk + (lane >> 4) * 8]);
#pragma unroll
    for (int m = 0; m < 2; ++m)
#pragma unroll
      for (int n = 0; n < 2; ++n)
        acc[m][n] = __builtin_amdgcn_mfma_f32_16x16x32_bf16(f[m], f[n],
                                                            acc[m][n], 0, 0, 0);
  }
  const int r_ = (lane >> 4) * 4, c_ = lane & 15;
#pragma unroll
  for (int m = 0; m < 2; ++m)
#pragma unroll
    for (int n = 0; n < 2; ++n)
#pragma unroll
      for (int j = 0; j < 4; ++j) {
        int r = m * 16 + r_ + j, c = n * 16 + c_;
        if (r < NWAYS && c < NWAYS) Gl[r][c] = acc[m][n][j];
      }
  __syncthreads();
  if (lane < NWAYS) {
    float sims[NWAYS];
#pragma unroll
    for (int m = 0; m < NWAYS; ++m) sims[m] = Gl[lane][m];
    float topv[KNEI];
    int topi[KNEI];
#pragma unroll
    for (int t = 0; t < KNEI; ++t) {
      float bv = -INFINITY;
      int bi = 0;
#pragma unroll
      for (int m = 0; m < NWAYS; ++m)
        if (sims[m] > bv) { bv = sims[m]; bi = m; }
      sims[bi] = -INFINITY;
      topv[t] = bv;
      topi[t] = bi;
    }
    float w[KNEI], wsum = 0.f;
#pragma unroll
    for (int t = 0; t < KNEI; ++t) {
      w[t] = __expf((topv[t] - topv[0]) * TAU_INV);
      wsum += w[t];
    }
    const float invs = 1.f / wsum;
#pragma unroll
    for (int t = 0; t < KNEI; ++t) {
      Wl[lane][t] = w[t] * invs;
      Il[lane][t] = topi[t];
    }
  }
  __syncthreads();
  u16* outp = PMSGB + (size_t)b * NWAYS * DIM;
#pragma unroll 4
  for (int n = 0; n < NWAYS; ++n) {
    float a8[8] = {0.f, 0.f, 0.f, 0.f, 0.f, 0.f, 0.f, 0.f};
#pragma unroll
    for (int t = 0; t < KNEI; ++t) {
      const float w = Wl[n][t];
      uint4 v = *(const uint4*)&Pl[Il[n][t]][8 * lane];
      a8[0] += w * bflo(v.x); a8[1] += w * bfhi(v.x);
      a8[2] += w * bflo(v.y); a8[3] += w * bfhi(v.y);
      a8[4] += w * bflo(v.z); a8[5] += w * bfhi(v.z);
      a8[6] += w * bflo(v.w); a8[7] += w * bfhi(v.w);
    }
    uint4 r;
    r.x = pack2bf(a8[0], a8[1]);
    r.y = pack2bf(a8[2], a8[3]);
    r.z = pack2bf(a8[4], a8[5]);
    r.w = pack2bf(a8[6], a8[7]);
    *(uint4*)(outp + (size_t)n * DIM + 8 * lane) = r;
  }
}

// Fused: VC = l2n(mean_k V[b,n*5+k]); Pa = l2n(alpha*P + (1-alpha)*VC) -> bf16
__global__ void vcpa_kernel(const float* __restrict__ V,
                            const float* __restrict__ P,
                            const float* __restrict__ alpha_ptr,
                            u16* __restrict__ PAB) {
  const int row = blockIdx.x;  // b*NWAYS + n
  const int bb = row / NWAYS, n = row - bb * NWAYS;
  const int lane = threadIdx.x;
  const float* base = V + ((size_t)bb * NT + (size_t)n * KSHOT) * DIM;
  float4 a = {0.f, 0.f, 0.f, 0.f}, b = {0.f, 0.f, 0.f, 0.f};
#pragma unroll
  for (int k = 0; k < KSHOT; ++k) {
    float4 x0 = *(const float4*)(base + (size_t)k * DIM + 4 * lane);
    float4 x1 = *(const float4*)(base + (size_t)k * DIM + 256 + 4 * lane);
    a.x += x0.x; a.y += x0.y; a.z += x0.z; a.w += x0.w;
    b.x += x1.x; b.y += x1.y; b.z += x1.z; b.w += x1.w;
  }
  float ss = a.x * a.x + a.y * a.y + a.z * a.z + a.w * a.w +
             b.x * b.x + b.y * b.y + b.z * b.z + b.w * b.w;
  ss = waveReduceSum(ss);
  const float inv = 1.f / fmaxf(sqrtf(ss), 1e-12f);  // mean scale cancels in l2n
  a.x *= inv; a.y *= inv; a.z *= inv; a.w *= inv;
  b.x *= inv; b.y *= inv; b.z *= inv; b.w *= inv;
  const float alpha = *alpha_ptr, oma = 1.f - alpha;
  {
    float4 p0 = *(const float4*)(P + (size_t)row * DIM + 4 * lane);
    float4 p1 = *(const float4*)(P + (size_t)row * DIM + 256 + 4 * lane);
    a.x = alpha * p0.x + oma * a.x; a.y = alpha * p0.y + oma * a.y;
    a.z = alpha * p0.z + oma * a.z; a.w = alpha * p0.w + oma * a.w;
    b.x = alpha * p1.x + oma * b.x; b.y = alpha * p1.y + oma * b.y;
    b.z = alpha * p1.z + oma * b.z; b.w = alpha * p1.w + oma * b.w;
  }
  float s2 = a.x * a.x + a.y * a.y + a.z * a.z + a.w * a.w +
             b.x * b.x + b.y * b.y + b.z * b.z + b.w * b.w;
  s2 = waveReduceSum(s2);
  const float inv2 = 1.f / fmaxf(sqrtf(s2), 1e-12f);
  a.x *= inv2; a.y *= inv2; a.z *= inv2; a.w *= inv2;
  b.x *= inv2; b.y *= inv2; b.z *= inv2; b.w *= inv2;
  uint2 pa, pb;
  pa.x = pack2bf(a.x, a.y); pa.y = pack2bf(a.z, a.w);
  pb.x = pack2bf(b.x, b.y); pb.y = pack2bf(b.z, b.w);
  *(uint2*)(PAB + (size_t)row * DIM + 4 * lane) = pa;
  *(uint2*)(PAB + (size_t)row * DIM + 256 + 4 * lane) = pb;
}

// SIMS[b,r,n] = V[b,r]·Pa[b,n], MFMA, 64-row tile per 1-wave block.
__global__ __launch_bounds__(64) void sims_kernel(const u16* __restrict__ VB,
                                                  const u16* __restrict__ PAB,
                                                  float* __restrict__ SIMS) {
  const int it = blockIdx.x, b = blockIdx.y;
  const int lane = threadIdx.x;
  __shared__ __align__(16) u16 As[64][32];
  __shared__ __align__(16) u16 Bs[32][32];
  const u16* Vb = VB + (size_t)b * NT * DIM;
  const u16* Pb = PAB + (size_t)b * NWAYS * DIM;
  f32x4 acc[4][2];
#pragma unroll
  for (int m = 0; m < 4; ++m)
#pragma unroll
    for (int n = 0; n < 2; ++n) acc[m][n] = (f32x4){0.f, 0.f, 0.f, 0.f};
  const int ra = it * 64 + lane;
  const int rb = lane & 31, kb = (lane >> 5) * 16;
  for (int kk = 0; kk < DIM; kk += 32) {
    if (ra < NT) {
      const uint4* g = (const uint4*)(Vb + (size_t)ra * DIM + kk);
#pragma unroll
      for (int q = 0; q < 4; ++q) *(uint4*)&As[lane][8 * q] = g[q];
    } else {
      uint4 z = {0, 0, 0, 0};
#pragma unroll
      for (int q = 0; q < 4; ++q) *(uint4*)&As[lane][8 * q] = z;
    }
    if (rb < NWAYS) {
      const uint4* g = (const uint4*)(Pb + (size_t)rb * DIM + kk + kb);
      *(uint4*)&Bs[rb][kb] = g[0];
      *(uint4*)&Bs[rb][kb + 8] = g[1];
    } else {
      uint4 z = {0, 0, 0, 0};
      *(uint4*)&Bs[rb][kb] = z;
      *(uint4*)&Bs[rb][kb + 8] = z;
    }
    __syncthreads();
    s16x8 fa[4], fb[2];
#pragma unroll
    for (int m = 0; m < 4; ++m)
      fa[m] = ldfrag(&As[m * 16 + (lane & 15)][(lane >> 4) * 8]);
#pragma unroll
    for (int n = 0; n < 2; ++n)
      fb[n] = ldfrag(&Bs[n * 16 + (lane & 15)][(lane >> 4) * 8]);
#pragma unroll
    for (int m = 0; m < 4; ++m)
#pragma unroll
      for (int n = 0; n < 2; ++n)
        acc[m][n] = __builtin_amdgcn_mfma_f32_16x16x32_bf16(fa[m], fb[n],
                                                            acc[m][n], 0, 0, 0);
    __syncthreads();
  }
  const int r_ = (lane >> 4) * 4, c_ = lane & 15;
#pragma unroll
  for (int m = 0; m < 4; ++m)
#pragma unroll
    for (int n = 0; n < 2; ++n)
#pragma unroll
      for (int j = 0; j < 4; ++j) {
        int r = it * 64 + m * 16 + r_ + j, c = n * 16 + c_;
        if (r < NT && c < NWAYS)
          SIMS[((size_t)b * NT + r) * NWAYS + c] = acc[m][n][j];
      }
}

// G[b] = Pa·Pa^T (20x20), one wave per episode.
__global__ __launch_bounds__(64) void gram_kernel(const u16* __restrict__ PAB,
                                                  float* __restrict__ G) {
  const int b = blockIdx.x;
  const int lane = threadIdx.x;
  __shared__ __align__(16) u16 Ps[32][32];
  const u16* Pb = PAB + (size_t)b * NWAYS * DIM;
  f32x4 acc[2][2];
#pragma unroll
  for (int m = 0; m < 2; ++m)
#pragma unroll
    for (int n = 0; n < 2; ++n) acc[m][n] = (f32x4){0.f, 0.f, 0.f, 0.f};
  const int rb = lane & 31, kb = (lane >> 5) * 16;
  for (int kk = 0; kk < DIM; kk += 32) {
    if (rb < NWAYS) {
      const uint4* g = (const uint4*)(Pb + (size_t)rb * DIM + kk + kb);
      *(uint4*)&Ps[rb][kb] = g[0];
      *(uint4*)&Ps[rb][kb + 8] = g[1];
    } else {
      uint4 z = {0, 0, 0, 0};
      *(uint4*)&Ps[rb][kb] = z;
      *(uint4*)&Ps[rb][kb + 8] = z;
    }
    __syncthreads();
    s16x8 f[2];
#pragma unroll
    for (int m = 0; m < 2; ++m)
      f[m] = ldfrag(&Ps[m * 16 + (lane & 15)][(lane >> 4) * 8]);
#pragma unroll
    for (int m = 0; m < 2; ++m)
#pragma unroll
      for (int n = 0; n < 2; ++n)
        acc[m][n] = __builtin_amdgcn_mfma_f32_16x16x32_bf16(f[m], f[n],
                                                            acc[m][n], 0, 0, 0);
    __syncthreads();
  }
  const int r_ = (lane >> 4) * 4, c_ = lane & 15;
#pragma unroll
  for (int m = 0; m < 2; ++m)
#pragma unroll
    for (int n = 0; n < 2; ++n)
#pragma unroll
      for (int j = 0; j < 4; ++j) {
        int r = m * 16 + r_ + j, c = n * 16 + c_;
        if (r < NWAYS && c < NWAYS)
          G[(size_t)b * 400 + r * NWAYS + c] = acc[m][n][j];
      }
}

// Softmax + CE from scalars; ONE atomicAdd per block.
__global__ __launch_bounds__(256) void softce_kernel(
    const float* __restrict__ SIMS, const float* __restrict__ G,
    const int* __restrict__ qy, const float* __restrict__ beta_ptr,
    u16* __restrict__ S, float* __restrict__ INVN, float* __restrict__ accum,
    int is_last) {
  const int b = blockIdx.x, yq = blockIdx.y;
  const int tid = threadIdx.x;
  const int wave = tid >> 6, lane = tid & 63;
  const int half = lane >> 5, n = lane & 31;
  __shared__ float gl[NWAYS][32];
  __shared__ float red[8];
  for (int c = tid; c < NWAYS * 32; c += 256) {
    int m = c >> 5, nn2 = c & 31;
    gl[m][nn2] = (nn2 < NWAYS) ? G[(size_t)b * 400 + m * NWAYS + nn2] : 0.f;
  }
  __syncthreads();
  const float beta = *beta_ptr, omb = 1.f - beta;
  const int r0 = 44 * yq;
  const int rend = min(44 * (yq + 1), NT);
  const int npairs = (rend - r0 + 1) >> 1;
  float ce_acc = 0.f, ac_acc = 0.f;
  for (int pr = wave; pr < npairs; pr += 4) {
    const int r = r0 + 2 * pr + half;
    if (r < rend) {
      float s = (n < NWAYS) ? SIMS[((size_t)b * NT + r) * NWAYS + n] : -1e30f;
      float mx = s;
#pragma unroll
      for (int off = 16; off >= 1; off >>= 1)
        mx = fmaxf(mx, __shfl_xor(mx, off, 32));
      float e = __expf((s - mx) * TAU_INV);
      float wsum = e, dsum = e * s;
#pragma unroll
      for (int off = 16; off >= 1; off >>= 1) {
        wsum += __shfl_xor(wsum, off, 32);
        dsum += __shfl_xor(dsum, off, 32);
      }
      float sg = 0.f;
#pragma unroll
      for (int m = 0; m < NWAYS; ++m) sg += __shfl(e, m, 32) * gl[m][n];
      float qsum = e * sg;
#pragma unroll
      for (int off = 16; off >= 1; off >>= 1)
        qsum += __shfl_xor(qsum, off, 32);
      const float iw = 1.f / wsum;
      const float dN = dsum * iw;
      const float qN = qsum * iw * iw;
      const float nn2 = beta * beta + 2.f * beta * omb * dN + omb * omb * qN;
      const float invn = 1.f / fmaxf(sqrtf(nn2), 1e-12f);
      S[((size_t)b * NT + r) * 32 + n] = pack1bf(e * iw);
      if (n == 0) INVN[(size_t)b * NT + r] = invn;
      if (r >= NKS) {
        float l = (n < NWAYS)
                      ? LOGIT_SCALE * invn * (beta * s + omb * sg * iw)
                      : -1e30f;
        float bv = l;
        int bi = n;
#pragma unroll
        for (int off = 16; off >= 1; off >>= 1) {
          float ov = __shfl_xor(bv, off, 32);
          int oi = __shfl_xor(bi, off, 32);
          if (ov > bv || (ov == bv && oi < bi)) { bv = ov; bi = oi; }
        }
        float se = __expf(l - bv);
#pragma unroll
        for (int off = 16; off >= 1; off >>= 1) se += __shfl_xor(se, off, 32);
        const int y = qy[b * NQ + (r - NKS)];
        const float ly = __shfl(l, y, 32);
        if (n == 0) {
          ce_acc += bv + __logf(se) - ly;
          ac_acc += (bi == y) ? 1.f : 0.f;
        }
      }
    }
  }
  ce_acc = waveReduceSum(ce_acc);
  ac_acc = waveReduceSum(ac_acc);
  if (lane == 0) {
    red[wave] = ce_acc;
    red[4 + wave] = ac_acc;
  }
  __syncthreads();
  if (tid == 0) {
    float ce = red[0] + red[1] + red[2] + red[3];
    atomicAdd(&accum[0], ce);
    if (is_last) {
      float ac = red[4] + red[5] + red[6] + red[7];
      atomicAdd(&accum[1], ac);
    }
  }
}

// V = invn*(beta*V + (1-beta)*S·Pa), writes f32 V and bf16 VB.
__global__ __launch_bounds__(256) void vupdate_kernel(
    float* __restrict__ V, u16* __restrict__ VB, const u16* __restrict__ PAB,
    const u16* __restrict__ S, const float* __restrict__ INVN,
    const float* __restrict__ beta_ptr) {
  const int b = blockIdx.x, yc = blockIdx.y;  // 0..6
  const int tid = threadIdx.x, wave = tid >> 6, lane = tid & 63;
  __shared__ __align__(16) u16 palds[NWAYS][DIM];
  __shared__ __align__(16) u16 slds[25][32];
  __shared__ float ilds[25];
  const int r0 = 25 * yc;
  for (int c = tid; c < NWAYS * (DIM / 8); c += 256) {
    int m = c >> 6, ko = (c & 63) * 8;
    *(uint4*)&palds[m][ko] =
        *(const uint4*)(PAB + ((size_t)b * NWAYS + m) * DIM + ko);
  }
  for (int c = tid; c < 100; c += 256) {
    *(uint4*)&slds[0][c * 8] =
        *(const uint4*)(S + ((size_t)b * NT + r0) * 32 + c * 8);
  }
  if (tid < 25) ilds[tid] = INVN[(size_t)b * NT + r0 + tid];
  __syncthreads();
  const float beta = *beta_ptr, omb = 1.f - beta;
  for (int t = wave; t < 25; t += 4) {
    const int r = r0 + t;
    float* vrow = V + ((size_t)b * NT + r) * DIM;
    float4 vl = *(const float4*)(vrow + 4 * lane);
    float4 vh = *(const float4*)(vrow + 256 + 4 * lane);
    float4 gL = {0.f, 0.f, 0.f, 0.f}, gH = {0.f, 0.f, 0.f, 0.f};
#pragma unroll
    for (int m = 0; m < NWAYS; ++m) {
      const float w = bf1(slds[t][m]);
      uint2 p0 = *(const uint2*)&palds[m][4 * lane];
      uint2 p1 = *(const uint2*)&palds[m][256 + 4 * lane];
      gL.x += w * bflo(p0.x); gL.y += w * bfhi(p0.x);
      gL.z += w * bflo(p0.y); gL.w += w * bfhi(p0.y);
      gH.x += w * bflo(p1.x); gH.y += w * bfhi(p1.x);
      gH.z += w * bflo(p1.y); gH.w += w * bfhi(p1.y);
    }
    const float inv = ilds[t];
    float4 yl, yh;
    yl.x = inv * (beta * vl.x + omb * gL.x);
    yl.y = inv * (beta * vl.y + omb * gL.y);
    yl.z = inv * (beta * vl.z + omb * gL.z);
    yl.w = inv * (beta * vl.w + omb * gL.w);
    yh.x = inv * (beta * vh.x + omb * gH.x);
    yh.y = inv * (beta * vh.y + omb * gH.y);
    yh.z = inv * (beta * vh.z + omb * gH.z);
    yh.w = inv * (beta * vh.w + omb * gH.w);
    *(float4*)(vrow + 4 * lane) = yl;
    *(float4*)(vrow + 256 + 4 * lane) = yh;
    uint2 pa, pb;
    pa.x = pack2bf(yl.x, yl.y); pa.y = pack2bf(yl.z, yl.w);
    pb.x = pack2bf(yh.x, yh.y); pb.y = pack2bf(yh.z, yh.w);
    u16* vbrow = VB + ((size_t)b * NT + r) * DIM;
    *(uint2*)(vbrow + 4 * lane) = pa;
    *(uint2*)(vbrow + 256 + 4 * lane) = pb;
  }
}

__global__ void finalize_kernel(const float* __restrict__ acc,
                                float* __restrict__ out) {
  out[0] = acc[0] / (float)(NLAYERS * B_EP * NQ);
  out[1] = acc[1] / (float)(B_EP * NQ);
}

extern "C" void kernel_launch(void* const* d_in, const int* in_sizes, int n_in,
                              void* d_out, int out_size, void* d_ws,
                              size_t ws_size, hipStream_t stream) {
  const float* V_feat = (const float*)d_in[0];
  const float* P_feat = (const float*)d_in[1];
  const int* query_y = (const int*)d_in[2];
  const float* igb_W = (const float*)d_in[3];
  const float* igb_b = (const float*)d_in[4];
  const float* igb_s = (const float*)d_in[5];
  const float* pgb_W = (const float*)d_in[6];
  const float* pgb_b = (const float*)d_in[7];
  const float* pgb_s = (const float*)d_in[8];
  const float* alpha = (const float*)d_in[9];
  const float* beta = (const float*)d_in[10];
  float* out = (float*)d_out;

  float* ws = (float*)d_ws;
  const size_t vsz = (size_t)B_EP * NT * DIM;       // 22,937,600
  const size_t psz = (size_t)B_EP * NWAYS * DIM;    // 2,621,440
  const size_t ssz = (size_t)B_EP * NT * NT;        // 7,840,000
  const size_t wsz = (size_t)NLAYERS * DIM * DIM;   // 1,048,576
  float* ACC = ws;
  float* V = ws + 16;
  float* V0 = V + vsz;
  float* SIM = V0 + vsz;
  float* P = SIM + ssz;
  float* P0 = P + psz;
  float* SIMS = P0 + psz;                       // B*NT*20
  float* G = SIMS + (size_t)B_EP * NT * NWAYS;  // B*400
  float* INVN = G + (size_t)B_EP * 400;         // B*NT
  u16* VB = (u16*)(INVN + (size_t)B_EP * NT);
  u16* MSGB = VB + vsz;     // own buffer now (topk reads VB!)
  u16* PMSGB = MSGB + vsz;
  u16* WB = PMSGB + psz;
  u16* WPB = WB + wsz;
  u16* PAB = WPB + wsz;
  u16* PB = PAB + psz;
  u16* S = PB + psz;  // B*NT*32 u16

  init_accum_kernel<<<1, 64, 0, stream>>>(ACC);
  l2n_init_kernel<<<B_EP * NT, 64, 0, stream>>>(V_feat, V, V0, VB);
  l2n_init_kernel<<<B_EP * NWAYS, 64, 0, stream>>>(P_feat, P, P0, PB);
  cvt_bf16_kernel<<<(int)(wsz / 8 / 256), 256, 0, stream>>>(igb_W, WB,
                                                            (int)(wsz / 8));
  cvt_bf16_kernel<<<(int)(wsz / 8 / 256), 256, 0, stream>>>(pgb_W, WPB,
                                                            (int)(wsz / 8));

  for (int i = 0; i < NLAYERS; ++i) {
    sim_mfma_kernel<<<dim3(3, 3, B_EP), 64, 0, stream>>>(VB, SIM);
    topk_msg_kernel<<<4 * B_EP, 256, 0, stream>>>(SIM, VB, MSGB);
    gemm_mfma_kernel<<<dim3(B_EP * NT / 128, 4), 256, 0, stream>>>(
        MSGB, WB + (size_t)i * DIM * DIM, igb_b + (size_t)i * DIM, igb_s + i, V);
    resid_l2n_kernel<<<B_EP * NT, 64, 0, stream>>>(V, V0, VB);

    p_branch_kernel<<<B_EP, 64, 0, stream>>>(PB, PMSGB);
    gemm_mfma_kernel<<<dim3(B_EP * NWAYS / 128, 4), 256, 0, stream>>>(
        PMSGB, WPB + (size_t)i * DIM * DIM, pgb_b + (size_t)i * DIM, pgb_s + i,
        P);
    resid_l2n_kernel<<<B_EP * NWAYS, 64, 0, stream>>>(P, P0, PB);

    vcpa_kernel<<<B_EP * NWAYS, 64, 0, stream>>>(V, P, alpha, PAB);

    sims_kernel<<<dim3(3, B_EP), 64, 0, stream>>>(VB, PAB, SIMS);
    gram_kernel<<<B_EP, 64, 0, stream>>>(PAB, G);
    softce_kernel<<<dim3(B_EP, 4), 256, 0, stream>>>(
        SIMS, G, query_y, beta, S, INVN, ACC, (i == NLAYERS - 1) ? 1 : 0);
    vupdate_kernel<<<dim3(B_EP, 7), 256, 0, stream>>>(V, VB, PAB, S, INVN,
                                                      beta);
  }
  finalize_kernel<<<1, 1, 0, stream>>>(ACC, out);
}

// Round 7
// 1587.170 us; speedup vs baseline: 4.9997x; 1.0782x over previous
//
#include <hip/hip_runtime.h>
#include <math.h>

#define B_EP 256
#define NT 175
#define NWAYS 20
#define KSHOT 5
#define NKS 100          // N_WAYS * N_SHOTS
#define NQ 75
#define DIM 512
#define NLAYERS 4
#define TAU_INV 10.0f
#define LOGIT_SCALE 5.0f
#define KNEI 5

typedef unsigned int u32;
typedef unsigned short u16;
typedef __attribute__((ext_vector_type(8))) short s16x8;   // 8 bf16 in 4 VGPRs
typedef __attribute__((ext_vector_type(4))) float f32x4;

__device__ __forceinline__ float waveReduceSum(float v) {
#pragma unroll
  for (int off = 32; off >= 1; off >>= 1) v += __shfl_xor(v, off);
  return v;
}

__device__ __forceinline__ u32 pack2bf(float a, float b) {
  u32 ua = __float_as_uint(a), ub = __float_as_uint(b);
  ua = (ua + 0x7FFFu + ((ua >> 16) & 1u)) >> 16;
  ub = (ub + 0x7FFFu + ((ub >> 16) & 1u)) >> 16;
  return ua | (ub << 16);
}

__device__ __forceinline__ u16 pack1bf(float a) {
  u32 ua = __float_as_uint(a);
  return (u16)((ua + 0x7FFFu + ((ua >> 16) & 1u)) >> 16);
}

__device__ __forceinline__ float bflo(u32 u) { return __uint_as_float(u << 16); }
__device__ __forceinline__ float bfhi(u32 u) { return __uint_as_float(u & 0xFFFF0000u); }
__device__ __forceinline__ float bf1(u16 h) { return __uint_as_float((u32)h << 16); }

__device__ __forceinline__ float tanh_fast(float x) {
  float e = __expf(2.f * x);
  return 1.f - 2.f * __builtin_amdgcn_rcpf(e + 1.f);
}

__device__ __forceinline__ s16x8 ldfrag(const u16* p) {
  return __builtin_bit_cast(s16x8, *(const uint4*)p);
}

// async global->LDS, 16B per lane. LDS dest = wave-uniform base + lane*16.
__device__ __forceinline__ void gload16(const u16* g, u16* l) {
  __builtin_amdgcn_global_load_lds(
      (const __attribute__((address_space(1))) void*)g,
      (__attribute__((address_space(3))) void*)l, 16, 0, 0);
}

__global__ void init_accum_kernel(float* acc) {
  if (threadIdx.x < 16) acc[threadIdx.x] = 0.f;
}

// f32 -> bf16 (RNE), 8 elems/thread (weights only)
__global__ void cvt_bf16_kernel(const float* __restrict__ in,
                                u16* __restrict__ out, int n8) {
  int t = blockIdx.x * 256 + threadIdx.x;
  if (t >= n8) return;
  const float4* p = (const float4*)(in + (size_t)t * 8);
  float4 a = p[0], b = p[1];
  uint4 r;
  r.x = pack2bf(a.x, a.y);
  r.y = pack2bf(a.z, a.w);
  r.z = pack2bf(b.x, b.y);
  r.w = pack2bf(b.z, b.w);
  *(uint4*)(out + (size_t)t * 8) = r;
}

// l2-normalize rows (512 wide); optionally emit bf16 copy.
__global__ void l2n_init_kernel(const float* __restrict__ in,
                                float* __restrict__ out,
                                float* __restrict__ out0,
                                u16* __restrict__ outb) {
  const size_t row = blockIdx.x;
  const int lane = threadIdx.x;
  const float* src = in + row * DIM;
  float4 a = *(const float4*)(src + 4 * lane);
  float4 b = *(const float4*)(src + 256 + 4 * lane);
  float ss = a.x * a.x + a.y * a.y + a.z * a.z + a.w * a.w +
             b.x * b.x + b.y * b.y + b.z * b.z + b.w * b.w;
  ss = waveReduceSum(ss);
  const float inv = 1.f / fmaxf(sqrtf(ss), 1e-12f);
  a.x *= inv; a.y *= inv; a.z *= inv; a.w *= inv;
  b.x *= inv; b.y *= inv; b.z *= inv; b.w *= inv;
  *(float4*)(out + row * DIM + 4 * lane) = a;
  *(float4*)(out + row * DIM + 256 + 4 * lane) = b;
  *(float4*)(out0 + row * DIM + 4 * lane) = a;
  *(float4*)(out0 + row * DIM + 256 + 4 * lane) = b;
  if (outb) {
    uint2 pa, pb;
    pa.x = pack2bf(a.x, a.y); pa.y = pack2bf(a.z, a.w);
    pb.x = pack2bf(b.x, b.y); pb.y = pack2bf(b.z, b.w);
    *(uint2*)(outb + row * DIM + 4 * lane) = pa;
    *(uint2*)(outb + row * DIM + 256 + 4 * lane) = pb;
  }
}

// SIM = V·V^T per episode via bf16 MFMA, 64x64 tile per 1-wave block.
__global__ __launch_bounds__(64) void sim_mfma_kernel(
    const u16* __restrict__ VB, float* __restrict__ SIM) {
  const int b = blockIdx.z, it = blockIdx.y, jt = blockIdx.x;
  const int lane = threadIdx.x;
  __shared__ __align__(16) u16 As2[4][64][8];
  __shared__ __align__(16) u16 Bs2[4][64][8];
  const u16* Vb = VB + (size_t)b * NT * DIM;
  f32x4 acc[4][4];
#pragma unroll
  for (int m = 0; m < 4; ++m)
#pragma unroll
    for (int n = 0; n < 4; ++n) acc[m][n] = (f32x4){0.f, 0.f, 0.f, 0.f};
  const int ra = it * 64 + lane, rb = jt * 64 + lane;
  for (int kk = 0; kk < DIM; kk += 32) {
    if (ra < NT) {
#pragma unroll
      for (int q = 0; q < 4; ++q)
        gload16(Vb + (size_t)ra * DIM + kk + q * 8, &As2[q][lane][0]);
    }
    if (rb < NT) {
#pragma unroll
      for (int q = 0; q < 4; ++q)
        gload16(Vb + (size_t)rb * DIM + kk + q * 8, &Bs2[q][lane][0]);
    }
    __syncthreads();
    s16x8 fa[4], fb[4];
#pragma unroll
    for (int m = 0; m < 4; ++m)
      fa[m] = ldfrag(&As2[lane >> 4][m * 16 + (lane & 15)][0]);
#pragma unroll
    for (int n = 0; n < 4; ++n)
      fb[n] = ldfrag(&Bs2[lane >> 4][n * 16 + (lane & 15)][0]);
#pragma unroll
    for (int m = 0; m < 4; ++m)
#pragma unroll
      for (int n = 0; n < 4; ++n)
        acc[m][n] = __builtin_amdgcn_mfma_f32_16x16x32_bf16(fa[m], fb[n],
                                                            acc[m][n], 0, 0, 0);
    __syncthreads();
  }
  const int r_ = (lane >> 4) * 4, c_ = lane & 15;
#pragma unroll
  for (int m = 0; m < 4; ++m)
#pragma unroll
    for (int n = 0; n < 4; ++n)
#pragma unroll
      for (int j = 0; j < 4; ++j) {
        int r = it * 64 + m * 16 + r_ + j, c = jt * 64 + n * 16 + c_;
        if (r < NT && c < NT) SIM[((size_t)b * NT + r) * NT + c] = acc[m][n][j];
      }
}

// Per (b,i): top-5 via packed sortable keys (value<<8 | 255-idx), softmax/tau,
// MSGB[b,i,:] = sum w_k*VB[idx_k]. 8 blocks x 4 waves per episode; b=p&255
// keeps all blocks of an episode on one XCD for L2 gather locality.
__global__ __launch_bounds__(256) void topk_msg_kernel(
    const float* __restrict__ SIM, const u16* __restrict__ VB,
    u16* __restrict__ MSGB) {
  const int p = blockIdx.x;
  const int b = p & 255, yq = p >> 8;  // yq 0..7
  const int tid = threadIdx.x, wave = tid >> 6, lane = tid & 63;
  const int wq = yq * 4 + wave;  // 0..31
  const u16* Vb = VB + (size_t)b * NT * DIM;
  for (int row = wq; row < NT; row += 32) {
    const float* srow = SIM + ((size_t)b * NT + row) * NT;
    u32 pk[3];
#pragma unroll
    for (int t = 0; t < 3; ++t) {
      int j = lane + 64 * t;
      if (j < NT) {
        u32 bits = __float_as_uint(srow[j]);
        u32 key = bits ^ ((bits >> 31) ? 0xFFFFFFFFu : 0x80000000u);
        pk[t] = (key & 0xFFFFFF00u) | (u32)(255 - j);
      } else {
        pk[t] = 0u;
      }
    }
    float topv[KNEI];
    int topi[KNEI];
#pragma unroll
    for (int t = 0; t < KNEI; ++t) {
      u32 c = max(pk[0], max(pk[1], pk[2]));
#pragma unroll
      for (int off = 32; off >= 1; off >>= 1)
        c = max(c, (u32)__shfl_xor((int)c, off));
#pragma unroll
      for (int u = 0; u < 3; ++u)
        if (pk[u] == c) pk[u] = 0u;
      const u32 vk = c & 0xFFFFFF00u;
      const u32 bits = (vk & 0x80000000u) ? (vk ^ 0x80000000u) : ~vk;
      topv[t] = __uint_as_float(bits);
      topi[t] = 255 - (int)(c & 0xFFu);
    }
    float w[KNEI];
    float wsum = 0.f;
#pragma unroll
    for (int t = 0; t < KNEI; ++t) {
      w[t] = __expf((topv[t] - topv[0]) * TAU_INV);
      wsum += w[t];
    }
    const float invs = 1.f / wsum;
    float a8[8] = {0.f, 0.f, 0.f, 0.f, 0.f, 0.f, 0.f, 0.f};
#pragma unroll
    for (int t = 0; t < KNEI; ++t) {
      uint4 v = *(const uint4*)(Vb + (size_t)topi[t] * DIM + 8 * lane);
      a8[0] += w[t] * bflo(v.x); a8[1] += w[t] * bfhi(v.x);
      a8[2] += w[t] * bflo(v.y); a8[3] += w[t] * bfhi(v.y);
      a8[4] += w[t] * bflo(v.z); a8[5] += w[t] * bfhi(v.z);
      a8[6] += w[t] * bflo(v.w); a8[7] += w[t] * bfhi(v.w);
    }
    uint4 r;
    r.x = pack2bf(a8[0] * invs, a8[1] * invs);
    r.y = pack2bf(a8[2] * invs, a8[3] * invs);
    r.z = pack2bf(a8[4] * invs, a8[5] * invs);
    r.w = pack2bf(a8[6] * invs, a8[7] * invs);
    *(uint4*)(MSGB + ((size_t)b * NT + row) * DIM + 8 * lane) = r;
  }
}

// Fused GNN layer tail: X = l2n(0.8*(X + s*tanh(A·W^T + bias)) + 0.2*X0),
// writes f32 X and bf16 XB. Block = 64 rows x full 512 cols, 512 threads
// (8 waves, wave w owns cols [w*64, w*64+64)). W streamed via LDS per k-chunk.
__global__ __launch_bounds__(512) void gemm_fused_kernel(
    const u16* __restrict__ A, const u16* __restrict__ W,
    const float* __restrict__ bias, const float* __restrict__ scale_ptr,
    float* __restrict__ X, const float* __restrict__ X0,
    u16* __restrict__ XB) {
  const int row0 = blockIdx.x * 64;
  const int tid = threadIdx.x, wave = tid >> 6, lane = tid & 63;
  __shared__ __align__(16) u16 As[64 * 32];   // [r][k], stride 32
  __shared__ __align__(16) u16 Bs[512 * 32];  // [c][k], stride 32
  __shared__ float redL[8][64];
  __shared__ float invL[64];
  f32x4 acc[4][4];
#pragma unroll
  for (int m = 0; m < 4; ++m)
#pragma unroll
    for (int n = 0; n < 4; ++n) acc[m][n] = (f32x4){0.f, 0.f, 0.f, 0.f};
  const int rsrc = lane >> 2;        // 0..15
  const int ksrc = (lane & 3) * 8;   // 0,8,16,24
  for (int kk = 0; kk < DIM; kk += 32) {
#pragma unroll
    for (int q = 0; q < 4; ++q) {
      const int t = wave * 4 + q;  // 0..31 covers all 512 W rows
      gload16(W + (size_t)(t * 16 + rsrc) * DIM + kk + ksrc, Bs + t * 512);
    }
    if (wave < 4)
      gload16(A + (size_t)(row0 + wave * 16 + rsrc) * DIM + kk + ksrc,
              As + wave * 512);
    __syncthreads();
    s16x8 fa[4], fb[4];
#pragma unroll
    for (int m = 0; m < 4; ++m)
      fa[m] = ldfrag(&As[(m * 16 + (lane & 15)) * 32 + (lane >> 4) * 8]);
#pragma unroll
    for (int n = 0; n < 4; ++n)
      fb[n] = ldfrag(
          &Bs[(wave * 64 + n * 16 + (lane & 15)) * 32 + (lane >> 4) * 8]);
#pragma unroll
    for (int m = 0; m < 4; ++m)
#pragma unroll
      for (int n = 0; n < 4; ++n)
        acc[m][n] = __builtin_amdgcn_mfma_f32_16x16x32_bf16(fa[m], fb[n],
                                                            acc[m][n], 0, 0, 0);
    __syncthreads();
  }
  const float s = *scale_ptr;
  const int rq = lane >> 4, c_ = lane & 15;
  // t = 0.8*(x + s*tanh(acc+bias)) + 0.2*x0, overwritten into acc
#pragma unroll
  for (int n = 0; n < 4; ++n) {
    const int col = wave * 64 + n * 16 + c_;
    const float bc = bias[col];
#pragma unroll
    for (int m = 0; m < 4; ++m)
#pragma unroll
      for (int j = 0; j < 4; ++j) {
        const int row = m * 16 + rq * 4 + j;
        const size_t off = (size_t)(row0 + row) * DIM + col;
        const float t =
            0.8f * (X[off] + s * tanh_fast(acc[m][n][j] + bc)) + 0.2f * X0[off];
        acc[m][n][j] = t;
      }
  }
  // row-wise sum of squares: per-thread over n, then 16-lane shuffle, then LDS
  float pr[4][4];
#pragma unroll
  for (int m = 0; m < 4; ++m)
#pragma unroll
    for (int j = 0; j < 4; ++j) {
      float v = acc[m][0][j] * acc[m][0][j] + acc[m][1][j] * acc[m][1][j] +
                acc[m][2][j] * acc[m][2][j] + acc[m][3][j] * acc[m][3][j];
      pr[m][j] = v;
    }
#pragma unroll
  for (int off = 8; off >= 1; off >>= 1)
#pragma unroll
    for (int m = 0; m < 4; ++m)
#pragma unroll
      for (int j = 0; j < 4; ++j) pr[m][j] += __shfl_xor(pr[m][j], off);
  if (c_ == 0) {
#pragma unroll
    for (int m = 0; m < 4; ++m)
#pragma unroll
      for (int j = 0; j < 4; ++j) redL[wave][m * 16 + rq * 4 + j] = pr[m][j];
  }
  __syncthreads();
  if (tid < 64) {
    float ssum = 0.f;
#pragma unroll
    for (int w8 = 0; w8 < 8; ++w8) ssum += redL[w8][tid];
    invL[tid] = 1.f / fmaxf(sqrtf(ssum), 1e-12f);
  }
  __syncthreads();
#pragma unroll
  for (int n = 0; n < 4; ++n) {
    const int col = wave * 64 + n * 16 + c_;
#pragma unroll
    for (int m = 0; m < 4; ++m)
#pragma unroll
      for (int j = 0; j < 4; ++j) {
        const int row = m * 16 + rq * 4 + j;
        const size_t off = (size_t)(row0 + row) * DIM + col;
        const float y = acc[m][n][j] * invL[row];
        X[off] = y;
        XB[off] = pack1bf(y);
      }
  }
}

// Fused prototype branch: per-episode block (64 thr). LDS-stage bf16 P,
// 20x20 gram via MFMA, per-row serial top-5 + softmax, LDS-gather message.
__global__ __launch_bounds__(64) void p_branch_kernel(
    const u16* __restrict__ PB, u16* __restrict__ PMSGB) {
  const int b = blockIdx.x;
  const int lane = threadIdx.x;
  __shared__ __align__(16) u16 Pl[32][520];  // pad 520: break b128 bank conflict
  __shared__ float Gl[NWAYS][NWAYS];
  __shared__ float Wl[NWAYS][KNEI];
  __shared__ int Il[NWAYS][KNEI];
  const u16* Pb = PB + (size_t)b * NWAYS * DIM;
  for (int c = lane; c < 32 * 64; c += 64) {
    int m = c >> 6, ko = (c & 63) * 8;
    uint4 v = {0, 0, 0, 0};
    if (m < NWAYS) v = *(const uint4*)(Pb + (size_t)m * DIM + ko);
    *(uint4*)&Pl[m][ko] = v;
  }
  __syncthreads();
  f32x4 acc[2][2];
#pragma unroll
  for (int m = 0; m < 2; ++m)
#pragma unroll
    for (int n = 0; n < 2; ++n) acc[m][n] = (f32x4){0.f, 0.f, 0.f, 0.f};
  for (int kk = 0; kk < DIM; kk += 32) {
    s16x8 f[2];
#pragma unroll
    for (int m = 0; m < 2; ++m)
      f[m] = ldfrag(&Pl[m * 16 + (lane & 15)][kk + (lane >> 4) * 8]);
#pragma unroll
    for (int m = 0; m < 2; ++m)
#pragma unroll
      for (int n = 0; n < 2; ++n)
        acc[m][n] = __builtin_amdgcn_mfma_f32_16x16x32_bf16(f[m], f[n],
                                                            acc[m][n], 0, 0, 0);
  }
  const int r_ = (lane >> 4) * 4, c_ = lane & 15;
#pragma unroll
  for (int m = 0; m < 2; ++m)
#pragma unroll
    for (int n = 0; n < 2; ++n)
#pragma unroll
      for (int j = 0; j < 4; ++j) {
        int r = m * 16 + r_ + j, c = n * 16 + c_;
        if (r < NWAYS && c < NWAYS) Gl[r][c] = acc[m][n][j];
      }
  __syncthreads();
  if (lane < NWAYS) {
    float sims[NWAYS];
#pragma unroll
    for (int m = 0; m < NWAYS; ++m) sims[m] = Gl[lane][m];
    float topv[KNEI];
    int topi[KNEI];
#pragma unroll
    for (int t = 0; t < KNEI; ++t) {
      float bv = -INFINITY;
      int bi = 0;
#pragma unroll
      for (int m = 0; m < NWAYS; ++m)
        if (sims[m] > bv) { bv = sims[m]; bi = m; }
      sims[bi] = -INFINITY;
      topv[t] = bv;
      topi[t] = bi;
    }
    float w[KNEI], wsum = 0.f;
#pragma unroll
    for (int t = 0; t < KNEI; ++t) {
      w[t] = __expf((topv[t] - topv[0]) * TAU_INV);
      wsum += w[t];
    }
    const float invs = 1.f / wsum;
#pragma unroll
    for (int t = 0; t < KNEI; ++t) {
      Wl[lane][t] = w[t] * invs;
      Il[lane][t] = topi[t];
    }
  }
  __syncthreads();
  u16* outp = PMSGB + (size_t)b * NWAYS * DIM;
#pragma unroll 4
  for (int n = 0; n < NWAYS; ++n) {
    float a8[8] = {0.f, 0.f, 0.f, 0.f, 0.f, 0.f, 0.f, 0.f};
#pragma unroll
    for (int t = 0; t < KNEI; ++t) {
      const float w = Wl[n][t];
      uint4 v = *(const uint4*)&Pl[Il[n][t]][8 * lane];
      a8[0] += w * bflo(v.x); a8[1] += w * bfhi(v.x);
      a8[2] += w * bflo(v.y); a8[3] += w * bfhi(v.y);
      a8[4] += w * bflo(v.z); a8[5] += w * bfhi(v.z);
      a8[6] += w * bflo(v.w); a8[7] += w * bfhi(v.w);
    }
    uint4 r;
    r.x = pack2bf(a8[0], a8[1]);
    r.y = pack2bf(a8[2], a8[3]);
    r.z = pack2bf(a8[4], a8[5]);
    r.w = pack2bf(a8[6], a8[7]);
    *(uint4*)(outp + (size_t)n * DIM + 8 * lane) = r;
  }
}

// Fused: VC = l2n(mean_k V[b,n*5+k]); Pa = l2n(alpha*P + (1-alpha)*VC) -> bf16
__global__ void vcpa_kernel(const float* __restrict__ V,
                            const float* __restrict__ P,
                            const float* __restrict__ alpha_ptr,
                            u16* __restrict__ PAB) {
  const int row = blockIdx.x;  // b*NWAYS + n
  const int bb = row / NWAYS, n = row - bb * NWAYS;
  const int lane = threadIdx.x;
  const float* base = V + ((size_t)bb * NT + (size_t)n * KSHOT) * DIM;
  float4 a = {0.f, 0.f, 0.f, 0.f}, b = {0.f, 0.f, 0.f, 0.f};
#pragma unroll
  for (int k = 0; k < KSHOT; ++k) {
    float4 x0 = *(const float4*)(base + (size_t)k * DIM + 4 * lane);
    float4 x1 = *(const float4*)(base + (size_t)k * DIM + 256 + 4 * lane);
    a.x += x0.x; a.y += x0.y; a.z += x0.z; a.w += x0.w;
    b.x += x1.x; b.y += x1.y; b.z += x1.z; b.w += x1.w;
  }
  float ss = a.x * a.x + a.y * a.y + a.z * a.z + a.w * a.w +
             b.x * b.x + b.y * b.y + b.z * b.z + b.w * b.w;
  ss = waveReduceSum(ss);
  const float inv = 1.f / fmaxf(sqrtf(ss), 1e-12f);  // mean scale cancels in l2n
  a.x *= inv; a.y *= inv; a.z *= inv; a.w *= inv;
  b.x *= inv; b.y *= inv; b.z *= inv; b.w *= inv;
  const float alpha = *alpha_ptr, oma = 1.f - alpha;
  {
    float4 p0 = *(const float4*)(P + (size_t)row * DIM + 4 * lane);
    float4 p1 = *(const float4*)(P + (size_t)row * DIM + 256 + 4 * lane);
    a.x = alpha * p0.x + oma * a.x; a.y = alpha * p0.y + oma * a.y;
    a.z = alpha * p0.z + oma * a.z; a.w = alpha * p0.w + oma * a.w;
    b.x = alpha * p1.x + oma * b.x; b.y = alpha * p1.y + oma * b.y;
    b.z = alpha * p1.z + oma * b.z; b.w = alpha * p1.w + oma * b.w;
  }
  float s2 = a.x * a.x + a.y * a.y + a.z * a.z + a.w * a.w +
             b.x * b.x + b.y * b.y + b.z * b.z + b.w * b.w;
  s2 = waveReduceSum(s2);
  const float inv2 = 1.f / fmaxf(sqrtf(s2), 1e-12f);
  a.x *= inv2; a.y *= inv2; a.z *= inv2; a.w *= inv2;
  b.x *= inv2; b.y *= inv2; b.z *= inv2; b.w *= inv2;
  uint2 pa, pb;
  pa.x = pack2bf(a.x, a.y); pa.y = pack2bf(a.z, a.w);
  pb.x = pack2bf(b.x, b.y); pb.y = pack2bf(b.z, b.w);
  *(uint2*)(PAB + (size_t)row * DIM + 4 * lane) = pa;
  *(uint2*)(PAB + (size_t)row * DIM + 256 + 4 * lane) = pb;
}

// SIMS[b,r,n] = V[b,r]·Pa[b,n], MFMA, 64-row tile per 1-wave block.
__global__ __launch_bounds__(64) void sims_kernel(const u16* __restrict__ VB,
                                                  const u16* __restrict__ PAB,
                                                  float* __restrict__ SIMS) {
  const int it = blockIdx.x, b = blockIdx.y;
  const int lane = threadIdx.x;
  __shared__ __align__(16) u16 As[64][32];
  __shared__ __align__(16) u16 Bs[32][32];
  const u16* Vb = VB + (size_t)b * NT * DIM;
  const u16* Pb = PAB + (size_t)b * NWAYS * DIM;
  f32x4 acc[4][2];
#pragma unroll
  for (int m = 0; m < 4; ++m)
#pragma unroll
    for (int n = 0; n < 2; ++n) acc[m][n] = (f32x4){0.f, 0.f, 0.f, 0.f};
  const int ra = it * 64 + lane;
  const int rb = lane & 31, kb = (lane >> 5) * 16;
  for (int kk = 0; kk < DIM; kk += 32) {
    if (ra < NT) {
      const uint4* g = (const uint4*)(Vb + (size_t)ra * DIM + kk);
#pragma unroll
      for (int q = 0; q < 4; ++q) *(uint4*)&As[lane][8 * q] = g[q];
    } else {
      uint4 z = {0, 0, 0, 0};
#pragma unroll
      for (int q = 0; q < 4; ++q) *(uint4*)&As[lane][8 * q] = z;
    }
    if (rb < NWAYS) {
      const uint4* g = (const uint4*)(Pb + (size_t)rb * DIM + kk + kb);
      *(uint4*)&Bs[rb][kb] = g[0];
      *(uint4*)&Bs[rb][kb + 8] = g[1];
    } else {
      uint4 z = {0, 0, 0, 0};
      *(uint4*)&Bs[rb][kb] = z;
      *(uint4*)&Bs[rb][kb + 8] = z;
    }
    __syncthreads();
    s16x8 fa[4], fb[2];
#pragma unroll
    for (int m = 0; m < 4; ++m)
      fa[m] = ldfrag(&As[m * 16 + (lane & 15)][(lane >> 4) * 8]);
#pragma unroll
    for (int n = 0; n < 2; ++n)
      fb[n] = ldfrag(&Bs[n * 16 + (lane & 15)][(lane >> 4) * 8]);
#pragma unroll
    for (int m = 0; m < 4; ++m)
#pragma unroll
      for (int n = 0; n < 2; ++n)
        acc[m][n] = __builtin_amdgcn_mfma_f32_16x16x32_bf16(fa[m], fb[n],
                                                            acc[m][n], 0, 0, 0);
    __syncthreads();
  }
  const int r_ = (lane >> 4) * 4, c_ = lane & 15;
#pragma unroll
  for (int m = 0; m < 4; ++m)
#pragma unroll
    for (int n = 0; n < 2; ++n)
#pragma unroll
      for (int j = 0; j < 4; ++j) {
        int r = it * 64 + m * 16 + r_ + j, c = n * 16 + c_;
        if (r < NT && c < NWAYS)
          SIMS[((size_t)b * NT + r) * NWAYS + c] = acc[m][n][j];
      }
}

// G[b] = Pa·Pa^T (20x20), one wave per episode.
__global__ __launch_bounds__(64) void gram_kernel(const u16* __restrict__ PAB,
                                                  float* __restrict__ G) {
  const int b = blockIdx.x;
  const int lane = threadIdx.x;
  __shared__ __align__(16) u16 Ps[32][32];
  const u16* Pb = PAB + (size_t)b * NWAYS * DIM;
  f32x4 acc[2][2];
#pragma unroll
  for (int m = 0; m < 2; ++m)
#pragma unroll
    for (int n = 0; n < 2; ++n) acc[m][n] = (f32x4){0.f, 0.f, 0.f, 0.f};
  const int rb = lane & 31, kb = (lane >> 5) * 16;
  for (int kk = 0; kk < DIM; kk += 32) {
    if (rb < NWAYS) {
      const uint4* g = (const uint4*)(Pb + (size_t)rb * DIM + kk + kb);
      *(uint4*)&Ps[rb][kb] = g[0];
      *(uint4*)&Ps[rb][kb + 8] = g[1];
    } else {
      uint4 z = {0, 0, 0, 0};
      *(uint4*)&Ps[rb][kb] = z;
      *(uint4*)&Ps[rb][kb + 8] = z;
    }
    __syncthreads();
    s16x8 f[2];
#pragma unroll
    for (int m = 0; m < 2; ++m)
      f[m] = ldfrag(&Ps[m * 16 + (lane & 15)][(lane >> 4) * 8]);
#pragma unroll
    for (int m = 0; m < 2; ++m)
#pragma unroll
      for (int n = 0; n < 2; ++n)
        acc[m][n] = __builtin_amdgcn_mfma_f32_16x16x32_bf16(f[m], f[n],
                                                            acc[m][n], 0, 0, 0);
    __syncthreads();
  }
  const int r_ = (lane >> 4) * 4, c_ = lane & 15;
#pragma unroll
  for (int m = 0; m < 2; ++m)
#pragma unroll
    for (int n = 0; n < 2; ++n)
#pragma unroll
      for (int j = 0; j < 4; ++j) {
        int r = m * 16 + r_ + j, c = n * 16 + c_;
        if (r < NWAYS && c < NWAYS)
          G[(size_t)b * 400 + r * NWAYS + c] = acc[m][n][j];
      }
}

// Softmax + CE from scalars; ONE atomicAdd per block.
__global__ __launch_bounds__(256) void softce_kernel(
    const float* __restrict__ SIMS, const float* __restrict__ G,
    const int* __restrict__ qy, const float* __restrict__ beta_ptr,
    u16* __restrict__ S, float* __restrict__ INVN, float* __restrict__ accum,
    int is_last) {
  const int b = blockIdx.x, yq = blockIdx.y;
  const int tid = threadIdx.x;
  const int wave = tid >> 6, lane = tid & 63;
  const int half = lane >> 5, n = lane & 31;
  __shared__ float gl[NWAYS][32];
  __shared__ float red[8];
  for (int c = tid; c < NWAYS * 32; c += 256) {
    int m = c >> 5, nn2 = c & 31;
    gl[m][nn2] = (nn2 < NWAYS) ? G[(size_t)b * 400 + m * NWAYS + nn2] : 0.f;
  }
  __syncthreads();
  const float beta = *beta_ptr, omb = 1.f - beta;
  const int r0 = 44 * yq;
  const int rend = min(44 * (yq + 1), NT);
  const int npairs = (rend - r0 + 1) >> 1;
  float ce_acc = 0.f, ac_acc = 0.f;
  for (int pr = wave; pr < npairs; pr += 4) {
    const int r = r0 + 2 * pr + half;
    if (r < rend) {
      float s = (n < NWAYS) ? SIMS[((size_t)b * NT + r) * NWAYS + n] : -1e30f;
      float mx = s;
#pragma unroll
      for (int off = 16; off >= 1; off >>= 1)
        mx = fmaxf(mx, __shfl_xor(mx, off, 32));
      float e = __expf((s - mx) * TAU_INV);
      float wsum = e, dsum = e * s;
#pragma unroll
      for (int off = 16; off >= 1; off >>= 1) {
        wsum += __shfl_xor(wsum, off, 32);
        dsum += __shfl_xor(dsum, off, 32);
      }
      float sg = 0.f;
#pragma unroll
      for (int m = 0; m < NWAYS; ++m) sg += __shfl(e, m, 32) * gl[m][n];
      float qsum = e * sg;
#pragma unroll
      for (int off = 16; off >= 1; off >>= 1)
        qsum += __shfl_xor(qsum, off, 32);
      const float iw = 1.f / wsum;
      const float dN = dsum * iw;
      const float qN = qsum * iw * iw;
      const float nn2 = beta * beta + 2.f * beta * omb * dN + omb * omb * qN;
      const float invn = 1.f / fmaxf(sqrtf(nn2), 1e-12f);
      S[((size_t)b * NT + r) * 32 + n] = pack1bf(e * iw);
      if (n == 0) INVN[(size_t)b * NT + r] = invn;
      if (r >= NKS) {
        float l = (n < NWAYS)
                      ? LOGIT_SCALE * invn * (beta * s + omb * sg * iw)
                      : -1e30f;
        float bv = l;
        int bi = n;
#pragma unroll
        for (int off = 16; off >= 1; off >>= 1) {
          float ov = __shfl_xor(bv, off, 32);
          int oi = __shfl_xor(bi, off, 32);
          if (ov > bv || (ov == bv && oi < bi)) { bv = ov; bi = oi; }
        }
        float se = __expf(l - bv);
#pragma unroll
        for (int off = 16; off >= 1; off >>= 1) se += __shfl_xor(se, off, 32);
        const int y = qy[b * NQ + (r - NKS)];
        const float ly = __shfl(l, y, 32);
        if (n == 0) {
          ce_acc += bv + __logf(se) - ly;
          ac_acc += (bi == y) ? 1.f : 0.f;
        }
      }
    }
  }
  ce_acc = waveReduceSum(ce_acc);
  ac_acc = waveReduceSum(ac_acc);
  if (lane == 0) {
    red[wave] = ce_acc;
    red[4 + wave] = ac_acc;
  }
  __syncthreads();
  if (tid == 0) {
    float ce = red[0] + red[1] + red[2] + red[3];
    atomicAdd(&accum[0], ce);
    if (is_last) {
      float ac = red[4] + red[5] + red[6] + red[7];
      atomicAdd(&accum[1], ac);
    }
  }
}

// V = invn*(beta*V + (1-beta)*S·Pa), writes f32 V and bf16 VB.
__global__ __launch_bounds__(256) void vupdate_kernel(
    float* __restrict__ V, u16* __restrict__ VB, const u16* __restrict__ PAB,
    const u16* __restrict__ S, const float* __restrict__ INVN,
    const float* __restrict__ beta_ptr) {
  const int b = blockIdx.x, yc = blockIdx.y;  // 0..6
  const int tid = threadIdx.x, wave = tid >> 6, lane = tid & 63;
  __shared__ __align__(16) u16 palds[NWAYS][DIM];
  __shared__ __align__(16) u16 slds[25][32];
  __shared__ float ilds[25];
  const int r0 = 25 * yc;
  for (int c = tid; c < NWAYS * (DIM / 8); c += 256) {
    int m = c >> 6, ko = (c & 63) * 8;
    *(uint4*)&palds[m][ko] =
        *(const uint4*)(PAB + ((size_t)b * NWAYS + m) * DIM + ko);
  }
  for (int c = tid; c < 100; c += 256) {
    *(uint4*)&slds[0][c * 8] =
        *(const uint4*)(S + ((size_t)b * NT + r0) * 32 + c * 8);
  }
  if (tid < 25) ilds[tid] = INVN[(size_t)b * NT + r0 + tid];
  __syncthreads();
  const float beta = *beta_ptr, omb = 1.f - beta;
  for (int t = wave; t < 25; t += 4) {
    const int r = r0 + t;
    float* vrow = V + ((size_t)b * NT + r) * DIM;
    float4 vl = *(const float4*)(vrow + 4 * lane);
    float4 vh = *(const float4*)(vrow + 256 + 4 * lane);
    float4 gL = {0.f, 0.f, 0.f, 0.f}, gH = {0.f, 0.f, 0.f, 0.f};
#pragma unroll
    for (int m = 0; m < NWAYS; ++m) {
      const float w = bf1(slds[t][m]);
      uint2 p0 = *(const uint2*)&palds[m][4 * lane];
      uint2 p1 = *(const uint2*)&palds[m][256 + 4 * lane];
      gL.x += w * bflo(p0.x); gL.y += w * bfhi(p0.x);
      gL.z += w * bflo(p0.y); gL.w += w * bfhi(p0.y);
      gH.x += w * bflo(p1.x); gH.y += w * bfhi(p1.x);
      gH.z += w * bflo(p1.y); gH.w += w * bfhi(p1.y);
    }
    const float inv = ilds[t];
    float4 yl, yh;
    yl.x = inv * (beta * vl.x + omb * gL.x);
    yl.y = inv * (beta * vl.y + omb * gL.y);
    yl.z = inv * (beta * vl.z + omb * gL.z);
    yl.w = inv * (beta * vl.w + omb * gL.w);
    yh.x = inv * (beta * vh.x + omb * gH.x);
    yh.y = inv * (beta * vh.y + omb * gH.y);
    yh.z = inv * (beta * vh.z + omb * gH.z);
    yh.w = inv * (beta * vh.w + omb * gH.w);
    *(float4*)(vrow + 4 * lane) = yl;
    *(float4*)(vrow + 256 + 4 * lane) = yh;
    uint2 pa, pb;
    pa.x = pack2bf(yl.x, yl.y); pa.y = pack2bf(yl.z, yl.w);
    pb.x = pack2bf(yh.x, yh.y); pb.y = pack2bf(yh.z, yh.w);
    u16* vbrow = VB + ((size_t)b * NT + r) * DIM;
    *(uint2*)(vbrow + 4 * lane) = pa;
    *(uint2*)(vbrow + 256 + 4 * lane) = pb;
  }
}

__global__ void finalize_kernel(const float* __restrict__ acc,
                                float* __restrict__ out) {
  out[0] = acc[0] / (float)(NLAYERS * B_EP * NQ);
  out[1] = acc[1] / (float)(B_EP * NQ);
}

extern "C" void kernel_launch(void* const* d_in, const int* in_sizes, int n_in,
                              void* d_out, int out_size, void* d_ws,
                              size_t ws_size, hipStream_t stream) {
  const float* V_feat = (const float*)d_in[0];
  const float* P_feat = (const float*)d_in[1];
  const int* query_y = (const int*)d_in[2];
  const float* igb_W = (const float*)d_in[3];
  const float* igb_b = (const float*)d_in[4];
  const float* igb_s = (const float*)d_in[5];
  const float* pgb_W = (const float*)d_in[6];
  const float* pgb_b = (const float*)d_in[7];
  const float* pgb_s = (const float*)d_in[8];
  const float* alpha = (const float*)d_in[9];
  const float* beta = (const float*)d_in[10];
  float* out = (float*)d_out;

  float* ws = (float*)d_ws;
  const size_t vsz = (size_t)B_EP * NT * DIM;       // 22,937,600
  const size_t psz = (size_t)B_EP * NWAYS * DIM;    // 2,621,440
  const size_t ssz = (size_t)B_EP * NT * NT;        // 7,840,000
  const size_t wsz = (size_t)NLAYERS * DIM * DIM;   // 1,048,576
  float* ACC = ws;
  float* V = ws + 16;
  float* V0 = V + vsz;
  float* SIM = V0 + vsz;
  float* P = SIM + ssz;
  float* P0 = P + psz;
  float* SIMS = P0 + psz;                       // B*NT*20
  float* G = SIMS + (size_t)B_EP * NT * NWAYS;  // B*400
  float* INVN = G + (size_t)B_EP * 400;         // B*NT
  u16* VB = (u16*)(INVN + (size_t)B_EP * NT);
  u16* MSGB = VB + vsz;
  u16* PMSGB = MSGB + vsz;
  u16* WB = PMSGB + psz;
  u16* WPB = WB + wsz;
  u16* PAB = WPB + wsz;
  u16* PB = PAB + psz;
  u16* S = PB + psz;  // B*NT*32 u16

  init_accum_kernel<<<1, 64, 0, stream>>>(ACC);
  l2n_init_kernel<<<B_EP * NT, 64, 0, stream>>>(V_feat, V, V0, VB);
  l2n_init_kernel<<<B_EP * NWAYS, 64, 0, stream>>>(P_feat, P, P0, PB);
  cvt_bf16_kernel<<<(int)(wsz / 8 / 256), 256, 0, stream>>>(igb_W, WB,
                                                            (int)(wsz / 8));
  cvt_bf16_kernel<<<(int)(wsz / 8 / 256), 256, 0, stream>>>(pgb_W, WPB,
                                                            (int)(wsz / 8));

  for (int i = 0; i < NLAYERS; ++i) {
    sim_mfma_kernel<<<dim3(3, 3, B_EP), 64, 0, stream>>>(VB, SIM);
    topk_msg_kernel<<<8 * B_EP, 256, 0, stream>>>(SIM, VB, MSGB);
    gemm_fused_kernel<<<B_EP * NT / 64, 512, 0, stream>>>(
        MSGB, WB + (size_t)i * DIM * DIM, igb_b + (size_t)i * DIM, igb_s + i,
        V, V0, VB);

    p_branch_kernel<<<B_EP, 64, 0, stream>>>(PB, PMSGB);
    gemm_fused_kernel<<<B_EP * NWAYS / 64, 512, 0, stream>>>(
        PMSGB, WPB + (size_t)i * DIM * DIM, pgb_b + (size_t)i * DIM, pgb_s + i,
        P, P0, PB);

    vcpa_kernel<<<B_EP * NWAYS, 64, 0, stream>>>(V, P, alpha, PAB);

    sims_kernel<<<dim3(3, B_EP), 64, 0, stream>>>(VB, PAB, SIMS);
    gram_kernel<<<B_EP, 64, 0, stream>>>(PAB, G);
    softce_kernel<<<dim3(B_EP, 4), 256, 0, stream>>>(
        SIMS, G, query_y, beta, S, INVN, ACC, (i == NLAYERS - 1) ? 1 : 0);
    vupdate_kernel<<<dim3(B_EP, 7), 256, 0, stream>>>(V, VB, PAB, S, INVN,
                                                      beta);
  }
  finalize_kernel<<<1, 1, 0, stream>>>(ACC, out);
}

// Round 8
// 1248.721 us; speedup vs baseline: 6.3547x; 1.2710x over previous
//
#include <hip/hip_runtime.h>
#include <math.h>

#define B_EP 256
#define NT 175
#define NWAYS 20
#define KSHOT 5
#define NKS 100          // N_WAYS * N_SHOTS
#define NQ 75
#define DIM 512
#define NLAYERS 4
#define TAU_INV 10.0f
#define LOGIT_SCALE 5.0f
#define KNEI 5

typedef unsigned int u32;
typedef unsigned short u16;
typedef __attribute__((ext_vector_type(8))) short s16x8;   // 8 bf16 in 4 VGPRs
typedef __attribute__((ext_vector_type(4))) float f32x4;

__device__ __forceinline__ float waveReduceSum(float v) {
#pragma unroll
  for (int off = 32; off >= 1; off >>= 1) v += __shfl_xor(v, off);
  return v;
}

__device__ __forceinline__ u32 pack2bf(float a, float b) {
  u32 ua = __float_as_uint(a), ub = __float_as_uint(b);
  ua = (ua + 0x7FFFu + ((ua >> 16) & 1u)) >> 16;
  ub = (ub + 0x7FFFu + ((ub >> 16) & 1u)) >> 16;
  return ua | (ub << 16);
}

__device__ __forceinline__ u16 pack1bf(float a) {
  u32 ua = __float_as_uint(a);
  return (u16)((ua + 0x7FFFu + ((ua >> 16) & 1u)) >> 16);
}

__device__ __forceinline__ float bflo(u32 u) { return __uint_as_float(u << 16); }
__device__ __forceinline__ float bfhi(u32 u) { return __uint_as_float(u & 0xFFFF0000u); }
__device__ __forceinline__ float bf1(u16 h) { return __uint_as_float((u32)h << 16); }

__device__ __forceinline__ float tanh_fast(float x) {
  float e = __expf(2.f * x);
  return 1.f - 2.f * __builtin_amdgcn_rcpf(e + 1.f);
}

__device__ __forceinline__ s16x8 ldfrag(const u16* p) {
  return __builtin_bit_cast(s16x8, *(const uint4*)p);
}

// async global->LDS, 16B per lane. LDS dest = wave-uniform base + lane*16.
__device__ __forceinline__ void gload16(const u16* g, u16* l) {
  __builtin_amdgcn_global_load_lds(
      (const __attribute__((address_space(1))) void*)g,
      (__attribute__((address_space(3))) void*)l, 16, 0, 0);
}

__global__ void init_accum_kernel(float* acc) {
  if (threadIdx.x < 16) acc[threadIdx.x] = 0.f;
}

// f32 -> bf16 (RNE), 8 elems/thread (weights only)
__global__ void cvt_bf16_kernel(const float* __restrict__ in,
                                u16* __restrict__ out, int n8) {
  int t = blockIdx.x * 256 + threadIdx.x;
  if (t >= n8) return;
  const float4* p = (const float4*)(in + (size_t)t * 8);
  float4 a = p[0], b = p[1];
  uint4 r;
  r.x = pack2bf(a.x, a.y);
  r.y = pack2bf(a.z, a.w);
  r.z = pack2bf(b.x, b.y);
  r.w = pack2bf(b.z, b.w);
  *(uint4*)(out + (size_t)t * 8) = r;
}

// l2-normalize rows (512 wide) from f32 input -> bf16 master + bf16 residual.
__global__ void l2n_init_kernel(const float* __restrict__ in,
                                u16* __restrict__ outb,
                                u16* __restrict__ out0b) {
  const size_t row = blockIdx.x;
  const int lane = threadIdx.x;
  const float* src = in + row * DIM;
  float4 a = *(const float4*)(src + 4 * lane);
  float4 b = *(const float4*)(src + 256 + 4 * lane);
  float ss = a.x * a.x + a.y * a.y + a.z * a.z + a.w * a.w +
             b.x * b.x + b.y * b.y + b.z * b.z + b.w * b.w;
  ss = waveReduceSum(ss);
  const float inv = 1.f / fmaxf(sqrtf(ss), 1e-12f);
  a.x *= inv; a.y *= inv; a.z *= inv; a.w *= inv;
  b.x *= inv; b.y *= inv; b.z *= inv; b.w *= inv;
  uint2 pa, pb;
  pa.x = pack2bf(a.x, a.y); pa.y = pack2bf(a.z, a.w);
  pb.x = pack2bf(b.x, b.y); pb.y = pack2bf(b.z, b.w);
  *(uint2*)(outb + row * DIM + 4 * lane) = pa;
  *(uint2*)(outb + row * DIM + 256 + 4 * lane) = pb;
  *(uint2*)(out0b + row * DIM + 4 * lane) = pa;
  *(uint2*)(out0b + row * DIM + 256 + 4 * lane) = pb;
}

// SIM = V·V^T per episode via bf16 MFMA, 64x64 tile per 1-wave block.
__global__ __launch_bounds__(64) void sim_mfma_kernel(
    const u16* __restrict__ VB, float* __restrict__ SIM) {
  const int b = blockIdx.z, it = blockIdx.y, jt = blockIdx.x;
  const int lane = threadIdx.x;
  __shared__ __align__(16) u16 As2[4][64][8];
  __shared__ __align__(16) u16 Bs2[4][64][8];
  const u16* Vb = VB + (size_t)b * NT * DIM;
  f32x4 acc[4][4];
#pragma unroll
  for (int m = 0; m < 4; ++m)
#pragma unroll
    for (int n = 0; n < 4; ++n) acc[m][n] = (f32x4){0.f, 0.f, 0.f, 0.f};
  const int ra = it * 64 + lane, rb = jt * 64 + lane;
  for (int kk = 0; kk < DIM; kk += 32) {
    if (ra < NT) {
#pragma unroll
      for (int q = 0; q < 4; ++q)
        gload16(Vb + (size_t)ra * DIM + kk + q * 8, &As2[q][lane][0]);
    }
    if (rb < NT) {
#pragma unroll
      for (int q = 0; q < 4; ++q)
        gload16(Vb + (size_t)rb * DIM + kk + q * 8, &Bs2[q][lane][0]);
    }
    __syncthreads();
    s16x8 fa[4], fb[4];
#pragma unroll
    for (int m = 0; m < 4; ++m)
      fa[m] = ldfrag(&As2[lane >> 4][m * 16 + (lane & 15)][0]);
#pragma unroll
    for (int n = 0; n < 4; ++n)
      fb[n] = ldfrag(&Bs2[lane >> 4][n * 16 + (lane & 15)][0]);
#pragma unroll
    for (int m = 0; m < 4; ++m)
#pragma unroll
      for (int n = 0; n < 4; ++n)
        acc[m][n] = __builtin_amdgcn_mfma_f32_16x16x32_bf16(fa[m], fb[n],
                                                            acc[m][n], 0, 0, 0);
    __syncthreads();
  }
  const int r_ = (lane >> 4) * 4, c_ = lane & 15;
#pragma unroll
  for (int m = 0; m < 4; ++m)
#pragma unroll
    for (int n = 0; n < 4; ++n)
#pragma unroll
      for (int j = 0; j < 4; ++j) {
        int r = it * 64 + m * 16 + r_ + j, c = jt * 64 + n * 16 + c_;
        if (r < NT && c < NT) SIM[((size_t)b * NT + r) * NT + c] = acc[m][n][j];
      }
}

// Per (b,i): top-5 via packed sortable keys (value<<8 | 255-idx), softmax/tau,
// MSGB[b,i,:] = sum w_k*VB[idx_k]. 8 blocks x 4 waves per episode; b=p&255
// keeps all blocks of an episode on one XCD for L2 gather locality.
__global__ __launch_bounds__(256) void topk_msg_kernel(
    const float* __restrict__ SIM, const u16* __restrict__ VB,
    u16* __restrict__ MSGB) {
  const int p = blockIdx.x;
  const int b = p & 255, yq = p >> 8;  // yq 0..7
  const int tid = threadIdx.x, wave = tid >> 6, lane = tid & 63;
  const int wq = yq * 4 + wave;  // 0..31
  const u16* Vb = VB + (size_t)b * NT * DIM;
  for (int row = wq; row < NT; row += 32) {
    const float* srow = SIM + ((size_t)b * NT + row) * NT;
    u32 pk[3];
#pragma unroll
    for (int t = 0; t < 3; ++t) {
      int j = lane + 64 * t;
      if (j < NT) {
        u32 bits = __float_as_uint(srow[j]);
        u32 key = bits ^ ((bits >> 31) ? 0xFFFFFFFFu : 0x80000000u);
        pk[t] = (key & 0xFFFFFF00u) | (u32)(255 - j);
      } else {
        pk[t] = 0u;
      }
    }
    float topv[KNEI];
    int topi[KNEI];
#pragma unroll
    for (int t = 0; t < KNEI; ++t) {
      u32 c = max(pk[0], max(pk[1], pk[2]));
#pragma unroll
      for (int off = 32; off >= 1; off >>= 1)
        c = max(c, (u32)__shfl_xor((int)c, off));
#pragma unroll
      for (int u = 0; u < 3; ++u)
        if (pk[u] == c) pk[u] = 0u;
      const u32 vk = c & 0xFFFFFF00u;
      const u32 bits = (vk & 0x80000000u) ? (vk ^ 0x80000000u) : ~vk;
      topv[t] = __uint_as_float(bits);
      topi[t] = 255 - (int)(c & 0xFFu);
    }
    float w[KNEI];
    float wsum = 0.f;
#pragma unroll
    for (int t = 0; t < KNEI; ++t) {
      w[t] = __expf((topv[t] - topv[0]) * TAU_INV);
      wsum += w[t];
    }
    const float invs = 1.f / wsum;
    float a8[8] = {0.f, 0.f, 0.f, 0.f, 0.f, 0.f, 0.f, 0.f};
#pragma unroll
    for (int t = 0; t < KNEI; ++t) {
      uint4 v = *(const uint4*)(Vb + (size_t)topi[t] * DIM + 8 * lane);
      a8[0] += w[t] * bflo(v.x); a8[1] += w[t] * bfhi(v.x);
      a8[2] += w[t] * bflo(v.y); a8[3] += w[t] * bfhi(v.y);
      a8[4] += w[t] * bflo(v.z); a8[5] += w[t] * bfhi(v.z);
      a8[6] += w[t] * bflo(v.w); a8[7] += w[t] * bfhi(v.w);
    }
    uint4 r;
    r.x = pack2bf(a8[0] * invs, a8[1] * invs);
    r.y = pack2bf(a8[2] * invs, a8[3] * invs);
    r.z = pack2bf(a8[4] * invs, a8[5] * invs);
    r.w = pack2bf(a8[6] * invs, a8[7] * invs);
    *(uint4*)(MSGB + ((size_t)b * NT + row) * DIM + 8 * lane) = r;
  }
}

// Fused GNN layer tail, bf16 master:
// XB = bf16(l2n(0.8*(XB + s*tanh(A·W^T + bias)) + 0.2*X0B)).
// Block = 64 rows x full 512 cols, 512 threads (8 waves, wave w owns cols
// [w*64, w*64+64)). W streamed via LDS per k-chunk (L2-resident).
__global__ __launch_bounds__(512) void gemm_fused_kernel(
    const u16* __restrict__ A, const u16* __restrict__ W,
    const float* __restrict__ bias, const float* __restrict__ scale_ptr,
    u16* __restrict__ XB, const u16* __restrict__ X0B) {
  const int row0 = blockIdx.x * 64;
  const int tid = threadIdx.x, wave = tid >> 6, lane = tid & 63;
  __shared__ __align__(16) u16 As[64 * 32];   // [r][k], stride 32
  __shared__ __align__(16) u16 Bs[512 * 32];  // [c][k], stride 32
  __shared__ float redL[8][64];
  __shared__ float invL[64];
  f32x4 acc[4][4];
#pragma unroll
  for (int m = 0; m < 4; ++m)
#pragma unroll
    for (int n = 0; n < 4; ++n) acc[m][n] = (f32x4){0.f, 0.f, 0.f, 0.f};
  const int rsrc = lane >> 2;        // 0..15
  const int ksrc = (lane & 3) * 8;   // 0,8,16,24
  for (int kk = 0; kk < DIM; kk += 32) {
#pragma unroll
    for (int q = 0; q < 4; ++q) {
      const int t = wave * 4 + q;  // 0..31 covers all 512 W rows
      gload16(W + (size_t)(t * 16 + rsrc) * DIM + kk + ksrc, Bs + t * 512);
    }
    if (wave < 4)
      gload16(A + (size_t)(row0 + wave * 16 + rsrc) * DIM + kk + ksrc,
              As + wave * 512);
    __syncthreads();
    s16x8 fa[4], fb[4];
#pragma unroll
    for (int m = 0; m < 4; ++m)
      fa[m] = ldfrag(&As[(m * 16 + (lane & 15)) * 32 + (lane >> 4) * 8]);
#pragma unroll
    for (int n = 0; n < 4; ++n)
      fb[n] = ldfrag(
          &Bs[(wave * 64 + n * 16 + (lane & 15)) * 32 + (lane >> 4) * 8]);
#pragma unroll
    for (int m = 0; m < 4; ++m)
#pragma unroll
      for (int n = 0; n < 4; ++n)
        acc[m][n] = __builtin_amdgcn_mfma_f32_16x16x32_bf16(fa[m], fb[n],
                                                            acc[m][n], 0, 0, 0);
    __syncthreads();
  }
  const float s = *scale_ptr;
  const int rq = lane >> 4, c_ = lane & 15;
  // t = 0.8*(x + s*tanh(acc+bias)) + 0.2*x0, overwritten into acc
#pragma unroll
  for (int n = 0; n < 4; ++n) {
    const int col = wave * 64 + n * 16 + c_;
    const float bc = bias[col];
#pragma unroll
    for (int m = 0; m < 4; ++m)
#pragma unroll
      for (int j = 0; j < 4; ++j) {
        const int row = m * 16 + rq * 4 + j;
        const size_t off = (size_t)(row0 + row) * DIM + col;
        const float t = 0.8f * (bf1(XB[off]) + s * tanh_fast(acc[m][n][j] + bc)) +
                        0.2f * bf1(X0B[off]);
        acc[m][n][j] = t;
      }
  }
  // row-wise sum of squares: per-thread over n, then 16-lane shuffle, then LDS
  float pr[4][4];
#pragma unroll
  for (int m = 0; m < 4; ++m)
#pragma unroll
    for (int j = 0; j < 4; ++j) {
      float v = acc[m][0][j] * acc[m][0][j] + acc[m][1][j] * acc[m][1][j] +
                acc[m][2][j] * acc[m][2][j] + acc[m][3][j] * acc[m][3][j];
      pr[m][j] = v;
    }
#pragma unroll
  for (int off = 8; off >= 1; off >>= 1)
#pragma unroll
    for (int m = 0; m < 4; ++m)
#pragma unroll
      for (int j = 0; j < 4; ++j) pr[m][j] += __shfl_xor(pr[m][j], off);
  if (c_ == 0) {
#pragma unroll
    for (int m = 0; m < 4; ++m)
#pragma unroll
      for (int j = 0; j < 4; ++j) redL[wave][m * 16 + rq * 4 + j] = pr[m][j];
  }
  __syncthreads();
  if (tid < 64) {
    float ssum = 0.f;
#pragma unroll
    for (int w8 = 0; w8 < 8; ++w8) ssum += redL[w8][tid];
    invL[tid] = 1.f / fmaxf(sqrtf(ssum), 1e-12f);
  }
  __syncthreads();
#pragma unroll
  for (int n = 0; n < 4; ++n) {
    const int col = wave * 64 + n * 16 + c_;
#pragma unroll
    for (int m = 0; m < 4; ++m)
#pragma unroll
      for (int j = 0; j < 4; ++j) {
        const int row = m * 16 + rq * 4 + j;
        const size_t off = (size_t)(row0 + row) * DIM + col;
        XB[off] = pack1bf(acc[m][n][j] * invL[row]);
      }
  }
}

// Fused prototype branch: per-episode block (64 thr). LDS-stage bf16 P,
// 20x20 gram via MFMA, per-row serial top-5 + softmax, LDS-gather message.
__global__ __launch_bounds__(64) void p_branch_kernel(
    const u16* __restrict__ PB, u16* __restrict__ PMSGB) {
  const int b = blockIdx.x;
  const int lane = threadIdx.x;
  __shared__ __align__(16) u16 Pl[32][520];  // pad 520: break b128 bank conflict
  __shared__ float Gl[NWAYS][NWAYS];
  __shared__ float Wl[NWAYS][KNEI];
  __shared__ int Il[NWAYS][KNEI];
  const u16* Pb = PB + (size_t)b * NWAYS * DIM;
  for (int c = lane; c < 32 * 64; c += 64) {
    int m = c >> 6, ko = (c & 63) * 8;
    uint4 v = {0, 0, 0, 0};
    if (m < NWAYS) v = *(const uint4*)(Pb + (size_t)m * DIM + ko);
    *(uint4*)&Pl[m][ko] = v;
  }
  __syncthreads();
  f32x4 acc[2][2];
#pragma unroll
  for (int m = 0; m < 2; ++m)
#pragma unroll
    for (int n = 0; n < 2; ++n) acc[m][n] = (f32x4){0.f, 0.f, 0.f, 0.f};
  for (int kk = 0; kk < DIM; kk += 32) {
    s16x8 f[2];
#pragma unroll
    for (int m = 0; m < 2; ++m)
      f[m] = ldfrag(&Pl[m * 16 + (lane & 15)][kk + (lane >> 4) * 8]);
#pragma unroll
    for (int m = 0; m < 2; ++m)
#pragma unroll
      for (int n = 0; n < 2; ++n)
        acc[m][n] = __builtin_amdgcn_mfma_f32_16x16x32_bf16(f[m], f[n],
                                                            acc[m][n], 0, 0, 0);
  }
  const int r_ = (lane >> 4) * 4, c_ = lane & 15;
#pragma unroll
  for (int m = 0; m < 2; ++m)
#pragma unroll
    for (int n = 0; n < 2; ++n)
#pragma unroll
      for (int j = 0; j < 4; ++j) {
        int r = m * 16 + r_ + j, c = n * 16 + c_;
        if (r < NWAYS && c < NWAYS) Gl[r][c] = acc[m][n][j];
      }
  __syncthreads();
  if (lane < NWAYS) {
    float sims[NWAYS];
#pragma unroll
    for (int m = 0; m < NWAYS; ++m) sims[m] = Gl[lane][m];
    float topv[KNEI];
    int topi[KNEI];
#pragma unroll
    for (int t = 0; t < KNEI; ++t) {
      float bv = -INFINITY;
      int bi = 0;
#pragma unroll
      for (int m = 0; m < NWAYS; ++m)
        if (sims[m] > bv) { bv = sims[m]; bi = m; }
      sims[bi] = -INFINITY;
      topv[t] = bv;
      topi[t] = bi;
    }
    float w[KNEI], wsum = 0.f;
#pragma unroll
    for (int t = 0; t < KNEI; ++t) {
      w[t] = __expf((topv[t] - topv[0]) * TAU_INV);
      wsum += w[t];
    }
    const float invs = 1.f / wsum;
#pragma unroll
    for (int t = 0; t < KNEI; ++t) {
      Wl[lane][t] = w[t] * invs;
      Il[lane][t] = topi[t];
    }
  }
  __syncthreads();
  u16* outp = PMSGB + (size_t)b * NWAYS * DIM;
#pragma unroll 4
  for (int n = 0; n < NWAYS; ++n) {
    float a8[8] = {0.f, 0.f, 0.f, 0.f, 0.f, 0.f, 0.f, 0.f};
#pragma unroll
    for (int t = 0; t < KNEI; ++t) {
      const float w = Wl[n][t];
      uint4 v = *(const uint4*)&Pl[Il[n][t]][8 * lane];
      a8[0] += w * bflo(v.x); a8[1] += w * bfhi(v.x);
      a8[2] += w * bflo(v.y); a8[3] += w * bfhi(v.y);
      a8[4] += w * bflo(v.z); a8[5] += w * bfhi(v.z);
      a8[6] += w * bflo(v.w); a8[7] += w * bfhi(v.w);
    }
    uint4 r;
    r.x = pack2bf(a8[0], a8[1]);
    r.y = pack2bf(a8[2], a8[3]);
    r.z = pack2bf(a8[4], a8[5]);
    r.w = pack2bf(a8[6], a8[7]);
    *(uint4*)(outp + (size_t)n * DIM + 8 * lane) = r;
  }
}

// Fused: VC = l2n(mean_k VB[b,n*5+k]); Pa = l2n(alpha*PB + (1-alpha)*VC) -> bf16
__global__ void vcpa_kernel(const u16* __restrict__ VB,
                            const u16* __restrict__ PB,
                            const float* __restrict__ alpha_ptr,
                            u16* __restrict__ PAB) {
  const int row = blockIdx.x;  // b*NWAYS + n
  const int bb = row / NWAYS, n = row - bb * NWAYS;
  const int lane = threadIdx.x;
  const u16* base = VB + ((size_t)bb * NT + (size_t)n * KSHOT) * DIM;
  float a8[8] = {0.f, 0.f, 0.f, 0.f, 0.f, 0.f, 0.f, 0.f};
#pragma unroll
  for (int k = 0; k < KSHOT; ++k) {
    uint2 x0 = *(const uint2*)(base + (size_t)k * DIM + 4 * lane);
    uint2 x1 = *(const uint2*)(base + (size_t)k * DIM + 256 + 4 * lane);
    a8[0] += bflo(x0.x); a8[1] += bfhi(x0.x);
    a8[2] += bflo(x0.y); a8[3] += bfhi(x0.y);
    a8[4] += bflo(x1.x); a8[5] += bfhi(x1.x);
    a8[6] += bflo(x1.y); a8[7] += bfhi(x1.y);
  }
  float ss = 0.f;
#pragma unroll
  for (int t = 0; t < 8; ++t) ss += a8[t] * a8[t];
  ss = waveReduceSum(ss);
  const float inv = 1.f / fmaxf(sqrtf(ss), 1e-12f);  // mean scale cancels in l2n
#pragma unroll
  for (int t = 0; t < 8; ++t) a8[t] *= inv;
  const float alpha = *alpha_ptr, oma = 1.f - alpha;
  {
    uint2 p0 = *(const uint2*)(PB + (size_t)row * DIM + 4 * lane);
    uint2 p1 = *(const uint2*)(PB + (size_t)row * DIM + 256 + 4 * lane);
    a8[0] = alpha * bflo(p0.x) + oma * a8[0];
    a8[1] = alpha * bfhi(p0.x) + oma * a8[1];
    a8[2] = alpha * bflo(p0.y) + oma * a8[2];
    a8[3] = alpha * bfhi(p0.y) + oma * a8[3];
    a8[4] = alpha * bflo(p1.x) + oma * a8[4];
    a8[5] = alpha * bfhi(p1.x) + oma * a8[5];
    a8[6] = alpha * bflo(p1.y) + oma * a8[6];
    a8[7] = alpha * bfhi(p1.y) + oma * a8[7];
  }
  float s2 = 0.f;
#pragma unroll
  for (int t = 0; t < 8; ++t) s2 += a8[t] * a8[t];
  s2 = waveReduceSum(s2);
  const float inv2 = 1.f / fmaxf(sqrtf(s2), 1e-12f);
  uint2 pa, pb;
  pa.x = pack2bf(a8[0] * inv2, a8[1] * inv2);
  pa.y = pack2bf(a8[2] * inv2, a8[3] * inv2);
  pb.x = pack2bf(a8[4] * inv2, a8[5] * inv2);
  pb.y = pack2bf(a8[6] * inv2, a8[7] * inv2);
  *(uint2*)(PAB + (size_t)row * DIM + 4 * lane) = pa;
  *(uint2*)(PAB + (size_t)row * DIM + 256 + 4 * lane) = pb;
}

// SIMS[b,r,n] = V[b,r]·Pa[b,n], MFMA, 64-row tile per 1-wave block.
__global__ __launch_bounds__(64) void sims_kernel(const u16* __restrict__ VB,
                                                  const u16* __restrict__ PAB,
                                                  float* __restrict__ SIMS) {
  const int it = blockIdx.x, b = blockIdx.y;
  const int lane = threadIdx.x;
  __shared__ __align__(16) u16 As[64][32];
  __shared__ __align__(16) u16 Bs[32][32];
  const u16* Vb = VB + (size_t)b * NT * DIM;
  const u16* Pb = PAB + (size_t)b * NWAYS * DIM;
  f32x4 acc[4][2];
#pragma unroll
  for (int m = 0; m < 4; ++m)
#pragma unroll
    for (int n = 0; n < 2; ++n) acc[m][n] = (f32x4){0.f, 0.f, 0.f, 0.f};
  const int ra = it * 64 + lane;
  const int rb = lane & 31, kb = (lane >> 5) * 16;
  for (int kk = 0; kk < DIM; kk += 32) {
    if (ra < NT) {
      const uint4* g = (const uint4*)(Vb + (size_t)ra * DIM + kk);
#pragma unroll
      for (int q = 0; q < 4; ++q) *(uint4*)&As[lane][8 * q] = g[q];
    } else {
      uint4 z = {0, 0, 0, 0};
#pragma unroll
      for (int q = 0; q < 4; ++q) *(uint4*)&As[lane][8 * q] = z;
    }
    if (rb < NWAYS) {
      const uint4* g = (const uint4*)(Pb + (size_t)rb * DIM + kk + kb);
      *(uint4*)&Bs[rb][kb] = g[0];
      *(uint4*)&Bs[rb][kb + 8] = g[1];
    } else {
      uint4 z = {0, 0, 0, 0};
      *(uint4*)&Bs[rb][kb] = z;
      *(uint4*)&Bs[rb][kb + 8] = z;
    }
    __syncthreads();
    s16x8 fa[4], fb[2];
#pragma unroll
    for (int m = 0; m < 4; ++m)
      fa[m] = ldfrag(&As[m * 16 + (lane & 15)][(lane >> 4) * 8]);
#pragma unroll
    for (int n = 0; n < 2; ++n)
      fb[n] = ldfrag(&Bs[n * 16 + (lane & 15)][(lane >> 4) * 8]);
#pragma unroll
    for (int m = 0; m < 4; ++m)
#pragma unroll
      for (int n = 0; n < 2; ++n)
        acc[m][n] = __builtin_amdgcn_mfma_f32_16x16x32_bf16(fa[m], fb[n],
                                                            acc[m][n], 0, 0, 0);
    __syncthreads();
  }
  const int r_ = (lane >> 4) * 4, c_ = lane & 15;
#pragma unroll
  for (int m = 0; m < 4; ++m)
#pragma unroll
    for (int n = 0; n < 2; ++n)
#pragma unroll
      for (int j = 0; j < 4; ++j) {
        int r = it * 64 + m * 16 + r_ + j, c = n * 16 + c_;
        if (r < NT && c < NWAYS)
          SIMS[((size_t)b * NT + r) * NWAYS + c] = acc[m][n][j];
      }
}

// G[b] = Pa·Pa^T (20x20), one wave per episode.
__global__ __launch_bounds__(64) void gram_kernel(const u16* __restrict__ PAB,
                                                  float* __restrict__ G) {
  const int b = blockIdx.x;
  const int lane = threadIdx.x;
  __shared__ __align__(16) u16 Ps[32][32];
  const u16* Pb = PAB + (size_t)b * NWAYS * DIM;
  f32x4 acc[2][2];
#pragma unroll
  for (int m = 0; m < 2; ++m)
#pragma unroll
    for (int n = 0; n < 2; ++n) acc[m][n] = (f32x4){0.f, 0.f, 0.f, 0.f};
  const int rb = lane & 31, kb = (lane >> 5) * 16;
  for (int kk = 0; kk < DIM; kk += 32) {
    if (rb < NWAYS) {
      const uint4* g = (const uint4*)(Pb + (size_t)rb * DIM + kk + kb);
      *(uint4*)&Ps[rb][kb] = g[0];
      *(uint4*)&Ps[rb][kb + 8] = g[1];
    } else {
      uint4 z = {0, 0, 0, 0};
      *(uint4*)&Ps[rb][kb] = z;
      *(uint4*)&Ps[rb][kb + 8] = z;
    }
    __syncthreads();
    s16x8 f[2];
#pragma unroll
    for (int m = 0; m < 2; ++m)
      f[m] = ldfrag(&Ps[m * 16 + (lane & 15)][(lane >> 4) * 8]);
#pragma unroll
    for (int m = 0; m < 2; ++m)
#pragma unroll
      for (int n = 0; n < 2; ++n)
        acc[m][n] = __builtin_amdgcn_mfma_f32_16x16x32_bf16(f[m], f[n],
                                                            acc[m][n], 0, 0, 0);
    __syncthreads();
  }
  const int r_ = (lane >> 4) * 4, c_ = lane & 15;
#pragma unroll
  for (int m = 0; m < 2; ++m)
#pragma unroll
    for (int n = 0; n < 2; ++n)
#pragma unroll
      for (int j = 0; j < 4; ++j) {
        int r = m * 16 + r_ + j, c = n * 16 + c_;
        if (r < NWAYS && c < NWAYS)
          G[(size_t)b * 400 + r * NWAYS + c] = acc[m][n][j];
      }
}

// Softmax + CE from scalars; ONE atomicAdd per block.
__global__ __launch_bounds__(256) void softce_kernel(
    const float* __restrict__ SIMS, const float* __restrict__ G,
    const int* __restrict__ qy, const float* __restrict__ beta_ptr,
    u16* __restrict__ S, float* __restrict__ INVN, float* __restrict__ accum,
    int is_last) {
  const int b = blockIdx.x, yq = blockIdx.y;
  const int tid = threadIdx.x;
  const int wave = tid >> 6, lane = tid & 63;
  const int half = lane >> 5, n = lane & 31;
  __shared__ float gl[NWAYS][32];
  __shared__ float red[8];
  for (int c = tid; c < NWAYS * 32; c += 256) {
    int m = c >> 5, nn2 = c & 31;
    gl[m][nn2] = (nn2 < NWAYS) ? G[(size_t)b * 400 + m * NWAYS + nn2] : 0.f;
  }
  __syncthreads();
  const float beta = *beta_ptr, omb = 1.f - beta;
  const int r0 = 44 * yq;
  const int rend = min(44 * (yq + 1), NT);
  const int npairs = (rend - r0 + 1) >> 1;
  float ce_acc = 0.f, ac_acc = 0.f;
  for (int pr = wave; pr < npairs; pr += 4) {
    const int r = r0 + 2 * pr + half;
    if (r < rend) {
      float s = (n < NWAYS) ? SIMS[((size_t)b * NT + r) * NWAYS + n] : -1e30f;
      float mx = s;
#pragma unroll
      for (int off = 16; off >= 1; off >>= 1)
        mx = fmaxf(mx, __shfl_xor(mx, off, 32));
      float e = __expf((s - mx) * TAU_INV);
      float wsum = e, dsum = e * s;
#pragma unroll
      for (int off = 16; off >= 1; off >>= 1) {
        wsum += __shfl_xor(wsum, off, 32);
        dsum += __shfl_xor(dsum, off, 32);
      }
      float sg = 0.f;
#pragma unroll
      for (int m = 0; m < NWAYS; ++m) sg += __shfl(e, m, 32) * gl[m][n];
      float qsum = e * sg;
#pragma unroll
      for (int off = 16; off >= 1; off >>= 1)
        qsum += __shfl_xor(qsum, off, 32);
      const float iw = 1.f / wsum;
      const float dN = dsum * iw;
      const float qN = qsum * iw * iw;
      const float nn2 = beta * beta + 2.f * beta * omb * dN + omb * omb * qN;
      const float invn = 1.f / fmaxf(sqrtf(nn2), 1e-12f);
      S[((size_t)b * NT + r) * 32 + n] = pack1bf(e * iw);
      if (n == 0) INVN[(size_t)b * NT + r] = invn;
      if (r >= NKS) {
        float l = (n < NWAYS)
                      ? LOGIT_SCALE * invn * (beta * s + omb * sg * iw)
                      : -1e30f;
        float bv = l;
        int bi = n;
#pragma unroll
        for (int off = 16; off >= 1; off >>= 1) {
          float ov = __shfl_xor(bv, off, 32);
          int oi = __shfl_xor(bi, off, 32);
          if (ov > bv || (ov == bv && oi < bi)) { bv = ov; bi = oi; }
        }
        float se = __expf(l - bv);
#pragma unroll
        for (int off = 16; off >= 1; off >>= 1) se += __shfl_xor(se, off, 32);
        const int y = qy[b * NQ + (r - NKS)];
        const float ly = __shfl(l, y, 32);
        if (n == 0) {
          ce_acc += bv + __logf(se) - ly;
          ac_acc += (bi == y) ? 1.f : 0.f;
        }
      }
    }
  }
  ce_acc = waveReduceSum(ce_acc);
  ac_acc = waveReduceSum(ac_acc);
  if (lane == 0) {
    red[wave] = ce_acc;
    red[4 + wave] = ac_acc;
  }
  __syncthreads();
  if (tid == 0) {
    float ce = red[0] + red[1] + red[2] + red[3];
    atomicAdd(&accum[0], ce);
    if (is_last) {
      float ac = red[4] + red[5] + red[6] + red[7];
      atomicAdd(&accum[1], ac);
    }
  }
}

// VB = bf16(invn*(beta*VB + (1-beta)*S·Pa)) — bf16 master in/out.
__global__ __launch_bounds__(256) void vupdate_kernel(
    u16* __restrict__ VB, const u16* __restrict__ PAB,
    const u16* __restrict__ S, const float* __restrict__ INVN,
    const float* __restrict__ beta_ptr) {
  const int b = blockIdx.x, yc = blockIdx.y;  // 0..6
  const int tid = threadIdx.x, wave = tid >> 6, lane = tid & 63;
  __shared__ __align__(16) u16 palds[NWAYS][DIM];
  __shared__ __align__(16) u16 slds[25][32];
  __shared__ float ilds[25];
  const int r0 = 25 * yc;
  for (int c = tid; c < NWAYS * (DIM / 8); c += 256) {
    int m = c >> 6, ko = (c & 63) * 8;
    *(uint4*)&palds[m][ko] =
        *(const uint4*)(PAB + ((size_t)b * NWAYS + m) * DIM + ko);
  }
  for (int c = tid; c < 100; c += 256) {
    *(uint4*)&slds[0][c * 8] =
        *(const uint4*)(S + ((size_t)b * NT + r0) * 32 + c * 8);
  }
  if (tid < 25) ilds[tid] = INVN[(size_t)b * NT + r0 + tid];
  __syncthreads();
  const float beta = *beta_ptr, omb = 1.f - beta;
  for (int t = wave; t < 25; t += 4) {
    const int r = r0 + t;
    u16* vrow = VB + ((size_t)b * NT + r) * DIM;
    uint2 v0 = *(const uint2*)(vrow + 4 * lane);
    uint2 v1 = *(const uint2*)(vrow + 256 + 4 * lane);
    float vl[4] = {bflo(v0.x), bfhi(v0.x), bflo(v0.y), bfhi(v0.y)};
    float vh[4] = {bflo(v1.x), bfhi(v1.x), bflo(v1.y), bfhi(v1.y)};
    float gL[4] = {0.f, 0.f, 0.f, 0.f}, gH[4] = {0.f, 0.f, 0.f, 0.f};
#pragma unroll
    for (int m = 0; m < NWAYS; ++m) {
      const float w = bf1(slds[t][m]);
      uint2 p0 = *(const uint2*)&palds[m][4 * lane];
      uint2 p1 = *(const uint2*)&palds[m][256 + 4 * lane];
      gL[0] += w * bflo(p0.x); gL[1] += w * bfhi(p0.x);
      gL[2] += w * bflo(p0.y); gL[3] += w * bfhi(p0.y);
      gH[0] += w * bflo(p1.x); gH[1] += w * bfhi(p1.x);
      gH[2] += w * bflo(p1.y); gH[3] += w * bfhi(p1.y);
    }
    const float inv = ilds[t];
    float yl[4], yh[4];
#pragma unroll
    for (int q = 0; q < 4; ++q) {
      yl[q] = inv * (beta * vl[q] + omb * gL[q]);
      yh[q] = inv * (beta * vh[q] + omb * gH[q]);
    }
    uint2 pa, pb;
    pa.x = pack2bf(yl[0], yl[1]); pa.y = pack2bf(yl[2], yl[3]);
    pb.x = pack2bf(yh[0], yh[1]); pb.y = pack2bf(yh[2], yh[3]);
    *(uint2*)(vrow + 4 * lane) = pa;
    *(uint2*)(vrow + 256 + 4 * lane) = pb;
  }
}

__global__ void finalize_kernel(const float* __restrict__ acc,
                                float* __restrict__ out) {
  out[0] = acc[0] / (float)(NLAYERS * B_EP * NQ);
  out[1] = acc[1] / (float)(B_EP * NQ);
}

extern "C" void kernel_launch(void* const* d_in, const int* in_sizes, int n_in,
                              void* d_out, int out_size, void* d_ws,
                              size_t ws_size, hipStream_t stream) {
  const float* V_feat = (const float*)d_in[0];
  const float* P_feat = (const float*)d_in[1];
  const int* query_y = (const int*)d_in[2];
  const float* igb_W = (const float*)d_in[3];
  const float* igb_b = (const float*)d_in[4];
  const float* igb_s = (const float*)d_in[5];
  const float* pgb_W = (const float*)d_in[6];
  const float* pgb_b = (const float*)d_in[7];
  const float* pgb_s = (const float*)d_in[8];
  const float* alpha = (const float*)d_in[9];
  const float* beta = (const float*)d_in[10];
  float* out = (float*)d_out;

  float* ws = (float*)d_ws;
  const size_t vsz = (size_t)B_EP * NT * DIM;       // 22,937,600
  const size_t psz = (size_t)B_EP * NWAYS * DIM;    // 2,621,440
  const size_t ssz = (size_t)B_EP * NT * NT;        // 7,840,000
  const size_t wsz = (size_t)NLAYERS * DIM * DIM;   // 1,048,576
  float* ACC = ws;
  float* SIM = ws + 16;
  float* SIMS = SIM + ssz;                      // B*NT*20
  float* G = SIMS + (size_t)B_EP * NT * NWAYS;  // B*400
  float* INVN = G + (size_t)B_EP * 400;         // B*NT
  u16* VB = (u16*)(INVN + (size_t)B_EP * NT);
  u16* V0B = VB + vsz;
  u16* MSGB = V0B + vsz;
  u16* PB = MSGB + vsz;
  u16* P0B = PB + psz;
  u16* PMSGB = P0B + psz;
  u16* PAB = PMSGB + psz;
  u16* WB = PAB + psz;
  u16* WPB = WB + wsz;
  u16* S = WPB + wsz;  // B*NT*32 u16

  init_accum_kernel<<<1, 64, 0, stream>>>(ACC);
  l2n_init_kernel<<<B_EP * NT, 64, 0, stream>>>(V_feat, VB, V0B);
  l2n_init_kernel<<<B_EP * NWAYS, 64, 0, stream>>>(P_feat, PB, P0B);
  cvt_bf16_kernel<<<(int)(wsz / 8 / 256), 256, 0, stream>>>(igb_W, WB,
                                                            (int)(wsz / 8));
  cvt_bf16_kernel<<<(int)(wsz / 8 / 256), 256, 0, stream>>>(pgb_W, WPB,
                                                            (int)(wsz / 8));

  for (int i = 0; i < NLAYERS; ++i) {
    sim_mfma_kernel<<<dim3(3, 3, B_EP), 64, 0, stream>>>(VB, SIM);
    topk_msg_kernel<<<8 * B_EP, 256, 0, stream>>>(SIM, VB, MSGB);
    gemm_fused_kernel<<<B_EP * NT / 64, 512, 0, stream>>>(
        MSGB, WB + (size_t)i * DIM * DIM, igb_b + (size_t)i * DIM, igb_s + i,
        VB, V0B);

    p_branch_kernel<<<B_EP, 64, 0, stream>>>(PB, PMSGB);
    gemm_fused_kernel<<<B_EP * NWAYS / 64, 512, 0, stream>>>(
        PMSGB, WPB + (size_t)i * DIM * DIM, pgb_b + (size_t)i * DIM, pgb_s + i,
        PB, P0B);

    vcpa_kernel<<<B_EP * NWAYS, 64, 0, stream>>>(VB, PB, alpha, PAB);

    sims_kernel<<<dim3(3, B_EP), 64, 0, stream>>>(VB, PAB, SIMS);
    gram_kernel<<<B_EP, 64, 0, stream>>>(PAB, G);
    softce_kernel<<<dim3(B_EP, 4), 256, 0, stream>>>(
        SIMS, G, query_y, beta, S, INVN, ACC, (i == NLAYERS - 1) ? 1 : 0);
    vupdate_kernel<<<dim3(B_EP, 7), 256, 0, stream>>>(VB, PAB, S, INVN, beta);
  }
  finalize_kernel<<<1, 1, 0, stream>>>(ACC, out);
}

// Round 9
// 1109.755 us; speedup vs baseline: 7.1505x; 1.1252x over previous
//
#include <hip/hip_runtime.h>
#include <math.h>

#define B_EP 256
#define NT 175
#define NWAYS 20
#define KSHOT 5
#define NKS 100          // N_WAYS * N_SHOTS
#define NQ 75
#define DIM 512
#define NLAYERS 4
#define TAU_INV 10.0f
#define LOGIT_SCALE 5.0f
#define KNEI 5

typedef unsigned int u32;
typedef unsigned short u16;
typedef __attribute__((ext_vector_type(8))) short s16x8;   // 8 bf16 in 4 VGPRs
typedef __attribute__((ext_vector_type(4))) float f32x4;

__device__ __forceinline__ float waveReduceSum(float v) {
#pragma unroll
  for (int off = 32; off >= 1; off >>= 1) v += __shfl_xor(v, off);
  return v;
}

__device__ __forceinline__ u32 pack2bf(float a, float b) {
  u32 ua = __float_as_uint(a), ub = __float_as_uint(b);
  ua = (ua + 0x7FFFu + ((ua >> 16) & 1u)) >> 16;
  ub = (ub + 0x7FFFu + ((ub >> 16) & 1u)) >> 16;
  return ua | (ub << 16);
}

__device__ __forceinline__ u16 pack1bf(float a) {
  u32 ua = __float_as_uint(a);
  return (u16)((ua + 0x7FFFu + ((ua >> 16) & 1u)) >> 16);
}

__device__ __forceinline__ float bflo(u32 u) { return __uint_as_float(u << 16); }
__device__ __forceinline__ float bfhi(u32 u) { return __uint_as_float(u & 0xFFFF0000u); }
__device__ __forceinline__ float bf1(u16 h) { return __uint_as_float((u32)h << 16); }

__device__ __forceinline__ float tanh_fast(float x) {
  float e = __expf(2.f * x);
  return 1.f - 2.f * __builtin_amdgcn_rcpf(e + 1.f);
}

__device__ __forceinline__ s16x8 ldfrag(const u16* p) {
  return __builtin_bit_cast(s16x8, *(const uint4*)p);
}

// async global->LDS, 16B per lane. LDS dest = wave-uniform base + lane*16.
__device__ __forceinline__ void gload16(const u16* g, u16* l) {
  __builtin_amdgcn_global_load_lds(
      (const __attribute__((address_space(1))) void*)g,
      (__attribute__((address_space(3))) void*)l, 16, 0, 0);
}

__global__ void init_accum_kernel(float* acc) {
  if (threadIdx.x < 16) acc[threadIdx.x] = 0.f;
}

// f32 -> bf16 (RNE), 8 elems/thread (weights only)
__global__ void cvt_bf16_kernel(const float* __restrict__ in,
                                u16* __restrict__ out, int n8) {
  int t = blockIdx.x * 256 + threadIdx.x;
  if (t >= n8) return;
  const float4* p = (const float4*)(in + (size_t)t * 8);
  float4 a = p[0], b = p[1];
  uint4 r;
  r.x = pack2bf(a.x, a.y);
  r.y = pack2bf(a.z, a.w);
  r.z = pack2bf(b.x, b.y);
  r.w = pack2bf(b.z, b.w);
  *(uint4*)(out + (size_t)t * 8) = r;
}

// l2-normalize rows (512 wide) from f32 input -> bf16 master + bf16 residual.
__global__ void l2n_init_kernel(const float* __restrict__ in,
                                u16* __restrict__ outb,
                                u16* __restrict__ out0b) {
  const size_t row = blockIdx.x;
  const int lane = threadIdx.x;
  const float* src = in + row * DIM;
  float4 a = *(const float4*)(src + 4 * lane);
  float4 b = *(const float4*)(src + 256 + 4 * lane);
  float ss = a.x * a.x + a.y * a.y + a.z * a.z + a.w * a.w +
             b.x * b.x + b.y * b.y + b.z * b.z + b.w * b.w;
  ss = waveReduceSum(ss);
  const float inv = 1.f / fmaxf(sqrtf(ss), 1e-12f);
  a.x *= inv; a.y *= inv; a.z *= inv; a.w *= inv;
  b.x *= inv; b.y *= inv; b.z *= inv; b.w *= inv;
  uint2 pa, pb;
  pa.x = pack2bf(a.x, a.y); pa.y = pack2bf(a.z, a.w);
  pb.x = pack2bf(b.x, b.y); pb.y = pack2bf(b.z, b.w);
  *(uint2*)(outb + row * DIM + 4 * lane) = pa;
  *(uint2*)(outb + row * DIM + 256 + 4 * lane) = pb;
  *(uint2*)(out0b + row * DIM + 4 * lane) = pa;
  *(uint2*)(out0b + row * DIM + 256 + 4 * lane) = pb;
}

// SIM = V·V^T per episode via bf16 MFMA, 64x64 tile per 1-wave block.
// 1D grid: b = p&255 so all 9 tiles of an episode share one XCD (L2 reuse).
__global__ __launch_bounds__(64) void sim_mfma_kernel(
    const u16* __restrict__ VB, float* __restrict__ SIM) {
  const int p = blockIdx.x;
  const int b = p & 255, t = p >> 8;  // t 0..8
  const int it = t / 3, jt = t - it * 3;
  const int lane = threadIdx.x;
  __shared__ __align__(16) u16 As2[4][64][8];
  __shared__ __align__(16) u16 Bs2[4][64][8];
  const u16* Vb = VB + (size_t)b * NT * DIM;
  f32x4 acc[4][4];
#pragma unroll
  for (int m = 0; m < 4; ++m)
#pragma unroll
    for (int n = 0; n < 4; ++n) acc[m][n] = (f32x4){0.f, 0.f, 0.f, 0.f};
  const int ra = it * 64 + lane, rb = jt * 64 + lane;
  for (int kk = 0; kk < DIM; kk += 32) {
    if (ra < NT) {
#pragma unroll
      for (int q = 0; q < 4; ++q)
        gload16(Vb + (size_t)ra * DIM + kk + q * 8, &As2[q][lane][0]);
    }
    if (rb < NT) {
#pragma unroll
      for (int q = 0; q < 4; ++q)
        gload16(Vb + (size_t)rb * DIM + kk + q * 8, &Bs2[q][lane][0]);
    }
    __syncthreads();
    s16x8 fa[4], fb[4];
#pragma unroll
    for (int m = 0; m < 4; ++m)
      fa[m] = ldfrag(&As2[lane >> 4][m * 16 + (lane & 15)][0]);
#pragma unroll
    for (int n = 0; n < 4; ++n)
      fb[n] = ldfrag(&Bs2[lane >> 4][n * 16 + (lane & 15)][0]);
#pragma unroll
    for (int m = 0; m < 4; ++m)
#pragma unroll
      for (int n = 0; n < 4; ++n)
        acc[m][n] = __builtin_amdgcn_mfma_f32_16x16x32_bf16(fa[m], fb[n],
                                                            acc[m][n], 0, 0, 0);
    __syncthreads();
  }
  const int r_ = (lane >> 4) * 4, c_ = lane & 15;
#pragma unroll
  for (int m = 0; m < 4; ++m)
#pragma unroll
    for (int n = 0; n < 4; ++n)
#pragma unroll
      for (int j = 0; j < 4; ++j) {
        int r = it * 64 + m * 16 + r_ + j, c = jt * 64 + n * 16 + c_;
        if (r < NT && c < NT) SIM[((size_t)b * NT + r) * NT + c] = acc[m][n][j];
      }
}

// Per (b,i): top-5 via packed sortable keys (value<<8 | 255-idx), softmax/tau,
// MSGB[b,i,:] = sum w_k*VB[idx_k]. 8 blocks x 4 waves per episode; b=p&255
// keeps all blocks of an episode on one XCD for L2 gather locality.
__global__ __launch_bounds__(256) void topk_msg_kernel(
    const float* __restrict__ SIM, const u16* __restrict__ VB,
    u16* __restrict__ MSGB) {
  const int p = blockIdx.x;
  const int b = p & 255, yq = p >> 8;  // yq 0..7
  const int tid = threadIdx.x, wave = tid >> 6, lane = tid & 63;
  const int wq = yq * 4 + wave;  // 0..31
  const u16* Vb = VB + (size_t)b * NT * DIM;
  for (int row = wq; row < NT; row += 32) {
    const float* srow = SIM + ((size_t)b * NT + row) * NT;
    u32 pk[3];
#pragma unroll
    for (int t = 0; t < 3; ++t) {
      int j = lane + 64 * t;
      if (j < NT) {
        u32 bits = __float_as_uint(srow[j]);
        u32 key = bits ^ ((bits >> 31) ? 0xFFFFFFFFu : 0x80000000u);
        pk[t] = (key & 0xFFFFFF00u) | (u32)(255 - j);
      } else {
        pk[t] = 0u;
      }
    }
    float topv[KNEI];
    int topi[KNEI];
#pragma unroll
    for (int t = 0; t < KNEI; ++t) {
      u32 c = max(pk[0], max(pk[1], pk[2]));
#pragma unroll
      for (int off = 32; off >= 1; off >>= 1)
        c = max(c, (u32)__shfl_xor((int)c, off));
#pragma unroll
      for (int u = 0; u < 3; ++u)
        if (pk[u] == c) pk[u] = 0u;
      const u32 vk = c & 0xFFFFFF00u;
      const u32 bits = (vk & 0x80000000u) ? (vk ^ 0x80000000u) : ~vk;
      topv[t] = __uint_as_float(bits);
      topi[t] = 255 - (int)(c & 0xFFu);
    }
    float w[KNEI];
    float wsum = 0.f;
#pragma unroll
    for (int t = 0; t < KNEI; ++t) {
      w[t] = __expf((topv[t] - topv[0]) * TAU_INV);
      wsum += w[t];
    }
    const float invs = 1.f / wsum;
    float a8[8] = {0.f, 0.f, 0.f, 0.f, 0.f, 0.f, 0.f, 0.f};
#pragma unroll
    for (int t = 0; t < KNEI; ++t) {
      uint4 v = *(const uint4*)(Vb + (size_t)topi[t] * DIM + 8 * lane);
      a8[0] += w[t] * bflo(v.x); a8[1] += w[t] * bfhi(v.x);
      a8[2] += w[t] * bflo(v.y); a8[3] += w[t] * bfhi(v.y);
      a8[4] += w[t] * bflo(v.z); a8[5] += w[t] * bfhi(v.z);
      a8[6] += w[t] * bflo(v.w); a8[7] += w[t] * bfhi(v.w);
    }
    uint4 r;
    r.x = pack2bf(a8[0] * invs, a8[1] * invs);
    r.y = pack2bf(a8[2] * invs, a8[3] * invs);
    r.z = pack2bf(a8[4] * invs, a8[5] * invs);
    r.w = pack2bf(a8[6] * invs, a8[7] * invs);
    *(uint4*)(MSGB + ((size_t)b * NT + row) * DIM + 8 * lane) = r;
  }
}

// Fused GNN layer tail, bf16 master:
// XB = bf16(l2n(0.8*(XB + s*tanh(A·W^T + bias)) + 0.2*X0B)).
// Block = 64 rows x 512 cols, 512 threads. GEMM stages As/Bs in smem; the
// same 64KB smem is then reused as U[64][512] (bf16, chunk-XOR-swizzled).
// Epilogue: phase1 scatters u=s*tanh(acc+b) to U; phase2 is fully vectorized
// (uint4 global loads/stores, width-8 shuffle row-norm).
__global__ __launch_bounds__(512) void gemm_fused_kernel(
    const u16* __restrict__ A, const u16* __restrict__ W,
    const float* __restrict__ bias, const float* __restrict__ scale_ptr,
    u16* __restrict__ XB, const u16* __restrict__ X0B) {
  const int row0 = blockIdx.x * 64;
  const int tid = threadIdx.x, wave = tid >> 6, lane = tid & 63;
  __shared__ __align__(16) u16 smem[64 * 512];  // 64KB; As/Bs then U
  u16* As = smem;          // 64x32 u16 (2048)
  u16* Bs = smem + 2048;   // 512x32 u16 (16384)
  f32x4 acc[4][4];
#pragma unroll
  for (int m = 0; m < 4; ++m)
#pragma unroll
    for (int n = 0; n < 4; ++n) acc[m][n] = (f32x4){0.f, 0.f, 0.f, 0.f};
  const int rsrc = lane >> 2;        // 0..15
  const int ksrc = (lane & 3) * 8;   // 0,8,16,24
  for (int kk = 0; kk < DIM; kk += 32) {
#pragma unroll
    for (int q = 0; q < 4; ++q) {
      const int t = wave * 4 + q;  // 0..31 covers all 512 W rows
      gload16(W + (size_t)(t * 16 + rsrc) * DIM + kk + ksrc, Bs + t * 512);
    }
    if (wave < 4)
      gload16(A + (size_t)(row0 + wave * 16 + rsrc) * DIM + kk + ksrc,
              As + wave * 512);
    __syncthreads();
    s16x8 fa[4], fb[4];
#pragma unroll
    for (int m = 0; m < 4; ++m)
      fa[m] = ldfrag(&As[(m * 16 + (lane & 15)) * 32 + (lane >> 4) * 8]);
#pragma unroll
    for (int n = 0; n < 4; ++n)
      fb[n] = ldfrag(
          &Bs[(wave * 64 + n * 16 + (lane & 15)) * 32 + (lane >> 4) * 8]);
#pragma unroll
    for (int m = 0; m < 4; ++m)
#pragma unroll
      for (int n = 0; n < 4; ++n)
        acc[m][n] = __builtin_amdgcn_mfma_f32_16x16x32_bf16(fa[m], fb[n],
                                                            acc[m][n], 0, 0, 0);
    __syncthreads();
  }
  const float s = *scale_ptr;
  const int rq = lane >> 4, c_ = lane & 15;
  // phase 1: U[row][col] = bf16(s*tanh(acc+bias)), chunk-swizzled:
  // chunk c' = c ^ (((row>>2)&3)<<1)  (c = col>>3)
#pragma unroll
  for (int n = 0; n < 4; ++n) {
    const int col = wave * 64 + n * 16 + c_;
    const float bc = bias[col];
    const int cbase = col >> 3, wof = col & 7;
#pragma unroll
    for (int m = 0; m < 4; ++m)
#pragma unroll
      for (int j = 0; j < 4; ++j) {
        const int row = m * 16 + rq * 4 + j;
        const int cS = cbase ^ (((row >> 2) & 3) << 1);
        smem[row * 512 + cS * 8 + wof] = pack1bf(s * tanh_fast(acc[m][n][j] + bc));
      }
  }
  __syncthreads();
  // phase 2: thread = (prow, sub); chunks c = sub + 8i, cols c*8..c*8+7
  const int prow = tid >> 3, sub = tid & 7;
  const int rq2 = ((prow >> 2) & 3) << 1;
  const u16* xrow = XB + (size_t)(row0 + prow) * DIM;
  const u16* x0row = X0B + (size_t)(row0 + prow) * DIM;
  float ss = 0.f;
#pragma unroll
  for (int i = 0; i < 8; ++i) {
    const int c = sub + 8 * i;
    uint4 xb = *(const uint4*)(xrow + c * 8);
    uint4 x0 = *(const uint4*)(x0row + c * 8);
    uint4 uu = *(const uint4*)&smem[prow * 512 + (c ^ rq2) * 8];
    float t0 = 0.8f * (bflo(xb.x) + bflo(uu.x)) + 0.2f * bflo(x0.x);
    float t1 = 0.8f * (bfhi(xb.x) + bfhi(uu.x)) + 0.2f * bfhi(x0.x);
    float t2 = 0.8f * (bflo(xb.y) + bflo(uu.y)) + 0.2f * bflo(x0.y);
    float t3 = 0.8f * (bfhi(xb.y) + bfhi(uu.y)) + 0.2f * bfhi(x0.y);
    float t4 = 0.8f * (bflo(xb.z) + bflo(uu.z)) + 0.2f * bflo(x0.z);
    float t5 = 0.8f * (bfhi(xb.z) + bfhi(uu.z)) + 0.2f * bfhi(x0.z);
    float t6 = 0.8f * (bflo(xb.w) + bflo(uu.w)) + 0.2f * bflo(x0.w);
    float t7 = 0.8f * (bfhi(xb.w) + bfhi(uu.w)) + 0.2f * bfhi(x0.w);
    ss += t0 * t0 + t1 * t1 + t2 * t2 + t3 * t3 + t4 * t4 + t5 * t5 +
          t6 * t6 + t7 * t7;
    uint4 tp;
    tp.x = pack2bf(t0, t1); tp.y = pack2bf(t2, t3);
    tp.z = pack2bf(t4, t5); tp.w = pack2bf(t6, t7);
    *(uint4*)&smem[prow * 512 + (c ^ rq2) * 8] = tp;
  }
#pragma unroll
  for (int off = 4; off >= 1; off >>= 1) ss += __shfl_xor(ss, off);
  const float inv = 1.f / fmaxf(sqrtf(ss), 1e-12f);
  u16* orow = XB + (size_t)(row0 + prow) * DIM;
#pragma unroll
  for (int i = 0; i < 8; ++i) {
    const int c = sub + 8 * i;
    uint4 tp = *(const uint4*)&smem[prow * 512 + (c ^ rq2) * 8];
    uint4 r;
    r.x = pack2bf(bflo(tp.x) * inv, bfhi(tp.x) * inv);
    r.y = pack2bf(bflo(tp.y) * inv, bfhi(tp.y) * inv);
    r.z = pack2bf(bflo(tp.z) * inv, bfhi(tp.z) * inv);
    r.w = pack2bf(bflo(tp.w) * inv, bfhi(tp.w) * inv);
    *(uint4*)(orow + c * 8) = r;
  }
}

// Fused prototype branch: per-episode block (64 thr). LDS-stage bf16 P,
// 20x20 gram via MFMA, per-row serial top-5 + softmax, LDS-gather message.
__global__ __launch_bounds__(64) void p_branch_kernel(
    const u16* __restrict__ PB, u16* __restrict__ PMSGB) {
  const int b = blockIdx.x;
  const int lane = threadIdx.x;
  __shared__ __align__(16) u16 Pl[32][520];  // pad 520: break b128 bank conflict
  __shared__ float Gl[NWAYS][NWAYS];
  __shared__ float Wl[NWAYS][KNEI];
  __shared__ int Il[NWAYS][KNEI];
  const u16* Pb = PB + (size_t)b * NWAYS * DIM;
  for (int c = lane; c < 32 * 64; c += 64) {
    int m = c >> 6, ko = (c & 63) * 8;
    uint4 v = {0, 0, 0, 0};
    if (m < NWAYS) v = *(const uint4*)(Pb + (size_t)m * DIM + ko);
    *(uint4*)&Pl[m][ko] = v;
  }
  __syncthreads();
  f32x4 acc[2][2];
#pragma unroll
  for (int m = 0; m < 2; ++m)
#pragma unroll
    for (int n = 0; n < 2; ++n) acc[m][n] = (f32x4){0.f, 0.f, 0.f, 0.f};
  for (int kk = 0; kk < DIM; kk += 32) {
    s16x8 f[2];
#pragma unroll
    for (int m = 0; m < 2; ++m)
      f[m] = ldfrag(&Pl[m * 16 + (lane & 15)][kk + (lane >> 4) * 8]);
#pragma unroll
    for (int m = 0; m < 2; ++m)
#pragma unroll
      for (int n = 0; n < 2; ++n)
        acc[m][n] = __builtin_amdgcn_mfma_f32_16x16x32_bf16(f[m], f[n],
                                                            acc[m][n], 0, 0, 0);
  }
  const int r_ = (lane >> 4) * 4, c_ = lane & 15;
#pragma unroll
  for (int m = 0; m < 2; ++m)
#pragma unroll
    for (int n = 0; n < 2; ++n)
#pragma unroll
      for (int j = 0; j < 4; ++j) {
        int r = m * 16 + r_ + j, c = n * 16 + c_;
        if (r < NWAYS && c < NWAYS) Gl[r][c] = acc[m][n][j];
      }
  __syncthreads();
  if (lane < NWAYS) {
    float sims[NWAYS];
#pragma unroll
    for (int m = 0; m < NWAYS; ++m) sims[m] = Gl[lane][m];
    float topv[KNEI];
    int topi[KNEI];
#pragma unroll
    for (int t = 0; t < KNEI; ++t) {
      float bv = -INFINITY;
      int bi = 0;
#pragma unroll
      for (int m = 0; m < NWAYS; ++m)
        if (sims[m] > bv) { bv = sims[m]; bi = m; }
      sims[bi] = -INFINITY;
      topv[t] = bv;
      topi[t] = bi;
    }
    float w[KNEI], wsum = 0.f;
#pragma unroll
    for (int t = 0; t < KNEI; ++t) {
      w[t] = __expf((topv[t] - topv[0]) * TAU_INV);
      wsum += w[t];
    }
    const float invs = 1.f / wsum;
#pragma unroll
    for (int t = 0; t < KNEI; ++t) {
      Wl[lane][t] = w[t] * invs;
      Il[lane][t] = topi[t];
    }
  }
  __syncthreads();
  u16* outp = PMSGB + (size_t)b * NWAYS * DIM;
#pragma unroll 4
  for (int n = 0; n < NWAYS; ++n) {
    float a8[8] = {0.f, 0.f, 0.f, 0.f, 0.f, 0.f, 0.f, 0.f};
#pragma unroll
    for (int t = 0; t < KNEI; ++t) {
      const float w = Wl[n][t];
      uint4 v = *(const uint4*)&Pl[Il[n][t]][8 * lane];
      a8[0] += w * bflo(v.x); a8[1] += w * bfhi(v.x);
      a8[2] += w * bflo(v.y); a8[3] += w * bfhi(v.y);
      a8[4] += w * bflo(v.z); a8[5] += w * bfhi(v.z);
      a8[6] += w * bflo(v.w); a8[7] += w * bfhi(v.w);
    }
    uint4 r;
    r.x = pack2bf(a8[0], a8[1]);
    r.y = pack2bf(a8[2], a8[3]);
    r.z = pack2bf(a8[4], a8[5]);
    r.w = pack2bf(a8[6], a8[7]);
    *(uint4*)(outp + (size_t)n * DIM + 8 * lane) = r;
  }
}

// Fused: VC = l2n(mean_k VB[b,n*5+k]); Pa = l2n(alpha*PB + (1-alpha)*VC) -> bf16
__global__ void vcpa_kernel(const u16* __restrict__ VB,
                            const u16* __restrict__ PB,
                            const float* __restrict__ alpha_ptr,
                            u16* __restrict__ PAB) {
  const int row = blockIdx.x;  // b*NWAYS + n
  const int bb = row / NWAYS, n = row - bb * NWAYS;
  const int lane = threadIdx.x;
  const u16* base = VB + ((size_t)bb * NT + (size_t)n * KSHOT) * DIM;
  float a8[8] = {0.f, 0.f, 0.f, 0.f, 0.f, 0.f, 0.f, 0.f};
#pragma unroll
  for (int k = 0; k < KSHOT; ++k) {
    uint2 x0 = *(const uint2*)(base + (size_t)k * DIM + 4 * lane);
    uint2 x1 = *(const uint2*)(base + (size_t)k * DIM + 256 + 4 * lane);
    a8[0] += bflo(x0.x); a8[1] += bfhi(x0.x);
    a8[2] += bflo(x0.y); a8[3] += bfhi(x0.y);
    a8[4] += bflo(x1.x); a8[5] += bfhi(x1.x);
    a8[6] += bflo(x1.y); a8[7] += bfhi(x1.y);
  }
  float ss = 0.f;
#pragma unroll
  for (int t = 0; t < 8; ++t) ss += a8[t] * a8[t];
  ss = waveReduceSum(ss);
  const float inv = 1.f / fmaxf(sqrtf(ss), 1e-12f);  // mean scale cancels in l2n
#pragma unroll
  for (int t = 0; t < 8; ++t) a8[t] *= inv;
  const float alpha = *alpha_ptr, oma = 1.f - alpha;
  {
    uint2 p0 = *(const uint2*)(PB + (size_t)row * DIM + 4 * lane);
    uint2 p1 = *(const uint2*)(PB + (size_t)row * DIM + 256 + 4 * lane);
    a8[0] = alpha * bflo(p0.x) + oma * a8[0];
    a8[1] = alpha * bfhi(p0.x) + oma * a8[1];
    a8[2] = alpha * bflo(p0.y) + oma * a8[2];
    a8[3] = alpha * bfhi(p0.y) + oma * a8[3];
    a8[4] = alpha * bflo(p1.x) + oma * a8[4];
    a8[5] = alpha * bfhi(p1.x) + oma * a8[5];
    a8[6] = alpha * bflo(p1.y) + oma * a8[6];
    a8[7] = alpha * bfhi(p1.y) + oma * a8[7];
  }
  float s2 = 0.f;
#pragma unroll
  for (int t = 0; t < 8; ++t) s2 += a8[t] * a8[t];
  s2 = waveReduceSum(s2);
  const float inv2 = 1.f / fmaxf(sqrtf(s2), 1e-12f);
  uint2 pa, pb;
  pa.x = pack2bf(a8[0] * inv2, a8[1] * inv2);
  pa.y = pack2bf(a8[2] * inv2, a8[3] * inv2);
  pb.x = pack2bf(a8[4] * inv2, a8[5] * inv2);
  pb.y = pack2bf(a8[6] * inv2, a8[7] * inv2);
  *(uint2*)(PAB + (size_t)row * DIM + 4 * lane) = pa;
  *(uint2*)(PAB + (size_t)row * DIM + 256 + 4 * lane) = pb;
}

// SIMS[b,r,n] = V[b,r]·Pa[b,n], MFMA, 64-row tile per 1-wave block.
__global__ __launch_bounds__(64) void sims_kernel(const u16* __restrict__ VB,
                                                  const u16* __restrict__ PAB,
                                                  float* __restrict__ SIMS) {
  const int it = blockIdx.x, b = blockIdx.y;
  const int lane = threadIdx.x;
  __shared__ __align__(16) u16 As[64][32];
  __shared__ __align__(16) u16 Bs[32][32];
  const u16* Vb = VB + (size_t)b * NT * DIM;
  const u16* Pb = PAB + (size_t)b * NWAYS * DIM;
  f32x4 acc[4][2];
#pragma unroll
  for (int m = 0; m < 4; ++m)
#pragma unroll
    for (int n = 0; n < 2; ++n) acc[m][n] = (f32x4){0.f, 0.f, 0.f, 0.f};
  const int ra = it * 64 + lane;
  const int rb = lane & 31, kb = (lane >> 5) * 16;
  for (int kk = 0; kk < DIM; kk += 32) {
    if (ra < NT) {
      const uint4* g = (const uint4*)(Vb + (size_t)ra * DIM + kk);
#pragma unroll
      for (int q = 0; q < 4; ++q) *(uint4*)&As[lane][8 * q] = g[q];
    } else {
      uint4 z = {0, 0, 0, 0};
#pragma unroll
      for (int q = 0; q < 4; ++q) *(uint4*)&As[lane][8 * q] = z;
    }
    if (rb < NWAYS) {
      const uint4* g = (const uint4*)(Pb + (size_t)rb * DIM + kk + kb);
      *(uint4*)&Bs[rb][kb] = g[0];
      *(uint4*)&Bs[rb][kb + 8] = g[1];
    } else {
      uint4 z = {0, 0, 0, 0};
      *(uint4*)&Bs[rb][kb] = z;
      *(uint4*)&Bs[rb][kb + 8] = z;
    }
    __syncthreads();
    s16x8 fa[4], fb[2];
#pragma unroll
    for (int m = 0; m < 4; ++m)
      fa[m] = ldfrag(&As[m * 16 + (lane & 15)][(lane >> 4) * 8]);
#pragma unroll
    for (int n = 0; n < 2; ++n)
      fb[n] = ldfrag(&Bs[n * 16 + (lane & 15)][(lane >> 4) * 8]);
#pragma unroll
    for (int m = 0; m < 4; ++m)
#pragma unroll
      for (int n = 0; n < 2; ++n)
        acc[m][n] = __builtin_amdgcn_mfma_f32_16x16x32_bf16(fa[m], fb[n],
                                                            acc[m][n], 0, 0, 0);
    __syncthreads();
  }
  const int r_ = (lane >> 4) * 4, c_ = lane & 15;
#pragma unroll
  for (int m = 0; m < 4; ++m)
#pragma unroll
    for (int n = 0; n < 2; ++n)
#pragma unroll
      for (int j = 0; j < 4; ++j) {
        int r = it * 64 + m * 16 + r_ + j, c = n * 16 + c_;
        if (r < NT && c < NWAYS)
          SIMS[((size_t)b * NT + r) * NWAYS + c] = acc[m][n][j];
      }
}

// G[b] = Pa·Pa^T (20x20), one wave per episode.
__global__ __launch_bounds__(64) void gram_kernel(const u16* __restrict__ PAB,
                                                  float* __restrict__ G) {
  const int b = blockIdx.x;
  const int lane = threadIdx.x;
  __shared__ __align__(16) u16 Ps[32][32];
  const u16* Pb = PAB + (size_t)b * NWAYS * DIM;
  f32x4 acc[2][2];
#pragma unroll
  for (int m = 0; m < 2; ++m)
#pragma unroll
    for (int n = 0; n < 2; ++n) acc[m][n] = (f32x4){0.f, 0.f, 0.f, 0.f};
  const int rb = lane & 31, kb = (lane >> 5) * 16;
  for (int kk = 0; kk < DIM; kk += 32) {
    if (rb < NWAYS) {
      const uint4* g = (const uint4*)(Pb + (size_t)rb * DIM + kk + kb);
      *(uint4*)&Ps[rb][kb] = g[0];
      *(uint4*)&Ps[rb][kb + 8] = g[1];
    } else {
      uint4 z = {0, 0, 0, 0};
      *(uint4*)&Ps[rb][kb] = z;
      *(uint4*)&Ps[rb][kb + 8] = z;
    }
    __syncthreads();
    s16x8 f[2];
#pragma unroll
    for (int m = 0; m < 2; ++m)
      f[m] = ldfrag(&Ps[m * 16 + (lane & 15)][(lane >> 4) * 8]);
#pragma unroll
    for (int m = 0; m < 2; ++m)
#pragma unroll
      for (int n = 0; n < 2; ++n)
        acc[m][n] = __builtin_amdgcn_mfma_f32_16x16x32_bf16(f[m], f[n],
                                                            acc[m][n], 0, 0, 0);
    __syncthreads();
  }
  const int r_ = (lane >> 4) * 4, c_ = lane & 15;
#pragma unroll
  for (int m = 0; m < 2; ++m)
#pragma unroll
    for (int n = 0; n < 2; ++n)
#pragma unroll
      for (int j = 0; j < 4; ++j) {
        int r = m * 16 + r_ + j, c = n * 16 + c_;
        if (r < NWAYS && c < NWAYS)
          G[(size_t)b * 400 + r * NWAYS + c] = acc[m][n][j];
      }
}

// Softmax + CE from scalars; ONE atomicAdd per block.
__global__ __launch_bounds__(256) void softce_kernel(
    const float* __restrict__ SIMS, const float* __restrict__ G,
    const int* __restrict__ qy, const float* __restrict__ beta_ptr,
    u16* __restrict__ S, float* __restrict__ INVN, float* __restrict__ accum,
    int is_last) {
  const int b = blockIdx.x, yq = blockIdx.y;
  const int tid = threadIdx.x;
  const int wave = tid >> 6, lane = tid & 63;
  const int half = lane >> 5, n = lane & 31;
  __shared__ float gl[NWAYS][32];
  __shared__ float red[8];
  for (int c = tid; c < NWAYS * 32; c += 256) {
    int m = c >> 5, nn2 = c & 31;
    gl[m][nn2] = (nn2 < NWAYS) ? G[(size_t)b * 400 + m * NWAYS + nn2] : 0.f;
  }
  __syncthreads();
  const float beta = *beta_ptr, omb = 1.f - beta;
  const int r0 = 44 * yq;
  const int rend = min(44 * (yq + 1), NT);
  const int npairs = (rend - r0 + 1) >> 1;
  float ce_acc = 0.f, ac_acc = 0.f;
  for (int pr = wave; pr < npairs; pr += 4) {
    const int r = r0 + 2 * pr + half;
    if (r < rend) {
      float s = (n < NWAYS) ? SIMS[((size_t)b * NT + r) * NWAYS + n] : -1e30f;
      float mx = s;
#pragma unroll
      for (int off = 16; off >= 1; off >>= 1)
        mx = fmaxf(mx, __shfl_xor(mx, off, 32));
      float e = __expf((s - mx) * TAU_INV);
      float wsum = e, dsum = e * s;
#pragma unroll
      for (int off = 16; off >= 1; off >>= 1) {
        wsum += __shfl_xor(wsum, off, 32);
        dsum += __shfl_xor(dsum, off, 32);
      }
      float sg = 0.f;
#pragma unroll
      for (int m = 0; m < NWAYS; ++m) sg += __shfl(e, m, 32) * gl[m][n];
      float qsum = e * sg;
#pragma unroll
      for (int off = 16; off >= 1; off >>= 1)
        qsum += __shfl_xor(qsum, off, 32);
      const float iw = 1.f / wsum;
      const float dN = dsum * iw;
      const float qN = qsum * iw * iw;
      const float nn2 = beta * beta + 2.f * beta * omb * dN + omb * omb * qN;
      const float invn = 1.f / fmaxf(sqrtf(nn2), 1e-12f);
      S[((size_t)b * NT + r) * 32 + n] = pack1bf(e * iw);
      if (n == 0) INVN[(size_t)b * NT + r] = invn;
      if (r >= NKS) {
        float l = (n < NWAYS)
                      ? LOGIT_SCALE * invn * (beta * s + omb * sg * iw)
                      : -1e30f;
        float bv = l;
        int bi = n;
#pragma unroll
        for (int off = 16; off >= 1; off >>= 1) {
          float ov = __shfl_xor(bv, off, 32);
          int oi = __shfl_xor(bi, off, 32);
          if (ov > bv || (ov == bv && oi < bi)) { bv = ov; bi = oi; }
        }
        float se = __expf(l - bv);
#pragma unroll
        for (int off = 16; off >= 1; off >>= 1) se += __shfl_xor(se, off, 32);
        const int y = qy[b * NQ + (r - NKS)];
        const float ly = __shfl(l, y, 32);
        if (n == 0) {
          ce_acc += bv + __logf(se) - ly;
          ac_acc += (bi == y) ? 1.f : 0.f;
        }
      }
    }
  }
  ce_acc = waveReduceSum(ce_acc);
  ac_acc = waveReduceSum(ac_acc);
  if (lane == 0) {
    red[wave] = ce_acc;
    red[4 + wave] = ac_acc;
  }
  __syncthreads();
  if (tid == 0) {
    float ce = red[0] + red[1] + red[2] + red[3];
    atomicAdd(&accum[0], ce);
    if (is_last) {
      float ac = red[4] + red[5] + red[6] + red[7];
      atomicAdd(&accum[1], ac);
    }
  }
}

// VB = bf16(invn*(beta*VB + (1-beta)*S·Pa)) — bf16 master in/out.
__global__ __launch_bounds__(256) void vupdate_kernel(
    u16* __restrict__ VB, const u16* __restrict__ PAB,
    const u16* __restrict__ S, const float* __restrict__ INVN,
    const float* __restrict__ beta_ptr) {
  const int b = blockIdx.x, yc = blockIdx.y;  // 0..6
  const int tid = threadIdx.x, wave = tid >> 6, lane = tid & 63;
  __shared__ __align__(16) u16 palds[NWAYS][DIM];
  __shared__ __align__(16) u16 slds[25][32];
  __shared__ float ilds[25];
  const int r0 = 25 * yc;
  for (int c = tid; c < NWAYS * (DIM / 8); c += 256) {
    int m = c >> 6, ko = (c & 63) * 8;
    *(uint4*)&palds[m][ko] =
        *(const uint4*)(PAB + ((size_t)b * NWAYS + m) * DIM + ko);
  }
  for (int c = tid; c < 100; c += 256) {
    *(uint4*)&slds[0][c * 8] =
        *(const uint4*)(S + ((size_t)b * NT + r0) * 32 + c * 8);
  }
  if (tid < 25) ilds[tid] = INVN[(size_t)b * NT + r0 + tid];
  __syncthreads();
  const float beta = *beta_ptr, omb = 1.f - beta;
  for (int t = wave; t < 25; t += 4) {
    const int r = r0 + t;
    u16* vrow = VB + ((size_t)b * NT + r) * DIM;
    uint2 v0 = *(const uint2*)(vrow + 4 * lane);
    uint2 v1 = *(const uint2*)(vrow + 256 + 4 * lane);
    float vl[4] = {bflo(v0.x), bfhi(v0.x), bflo(v0.y), bfhi(v0.y)};
    float vh[4] = {bflo(v1.x), bfhi(v1.x), bflo(v1.y), bfhi(v1.y)};
    float gL[4] = {0.f, 0.f, 0.f, 0.f}, gH[4] = {0.f, 0.f, 0.f, 0.f};
#pragma unroll
    for (int m = 0; m < NWAYS; ++m) {
      const float w = bf1(slds[t][m]);
      uint2 p0 = *(const uint2*)&palds[m][4 * lane];
      uint2 p1 = *(const uint2*)&palds[m][256 + 4 * lane];
      gL[0] += w * bflo(p0.x); gL[1] += w * bfhi(p0.x);
      gL[2] += w * bflo(p0.y); gL[3] += w * bfhi(p0.y);
      gH[0] += w * bflo(p1.x); gH[1] += w * bfhi(p1.x);
      gH[2] += w * bflo(p1.y); gH[3] += w * bfhi(p1.y);
    }
    const float inv = ilds[t];
    float yl[4], yh[4];
#pragma unroll
    for (int q = 0; q < 4; ++q) {
      yl[q] = inv * (beta * vl[q] + omb * gL[q]);
      yh[q] = inv * (beta * vh[q] + omb * gH[q]);
    }
    uint2 pa, pb;
    pa.x = pack2bf(yl[0], yl[1]); pa.y = pack2bf(yl[2], yl[3]);
    pb.x = pack2bf(yh[0], yh[1]); pb.y = pack2bf(yh[2], yh[3]);
    *(uint2*)(vrow + 4 * lane) = pa;
    *(uint2*)(vrow + 256 + 4 * lane) = pb;
  }
}

__global__ void finalize_kernel(const float* __restrict__ acc,
                                float* __restrict__ out) {
  out[0] = acc[0] / (float)(NLAYERS * B_EP * NQ);
  out[1] = acc[1] / (float)(B_EP * NQ);
}

extern "C" void kernel_launch(void* const* d_in, const int* in_sizes, int n_in,
                              void* d_out, int out_size, void* d_ws,
                              size_t ws_size, hipStream_t stream) {
  const float* V_feat = (const float*)d_in[0];
  const float* P_feat = (const float*)d_in[1];
  const int* query_y = (const int*)d_in[2];
  const float* igb_W = (const float*)d_in[3];
  const float* igb_b = (const float*)d_in[4];
  const float* igb_s = (const float*)d_in[5];
  const float* pgb_W = (const float*)d_in[6];
  const float* pgb_b = (const float*)d_in[7];
  const float* pgb_s = (const float*)d_in[8];
  const float* alpha = (const float*)d_in[9];
  const float* beta = (const float*)d_in[10];
  float* out = (float*)d_out;

  float* ws = (float*)d_ws;
  const size_t vsz = (size_t)B_EP * NT * DIM;       // 22,937,600
  const size_t psz = (size_t)B_EP * NWAYS * DIM;    // 2,621,440
  const size_t ssz = (size_t)B_EP * NT * NT;        // 7,840,000
  const size_t wsz = (size_t)NLAYERS * DIM * DIM;   // 1,048,576
  float* ACC = ws;
  float* SIM = ws + 16;
  float* SIMS = SIM + ssz;                      // B*NT*20
  float* G = SIMS + (size_t)B_EP * NT * NWAYS;  // B*400
  float* INVN = G + (size_t)B_EP * 400;         // B*NT
  u16* VB = (u16*)(INVN + (size_t)B_EP * NT);
  u16* V0B = VB + vsz;
  u16* MSGB = V0B + vsz;
  u16* PB = MSGB + vsz;
  u16* P0B = PB + psz;
  u16* PMSGB = P0B + psz;
  u16* PAB = PMSGB + psz;
  u16* WB = PAB + psz;
  u16* WPB = WB + wsz;
  u16* S = WPB + wsz;  // B*NT*32 u16

  init_accum_kernel<<<1, 64, 0, stream>>>(ACC);
  l2n_init_kernel<<<B_EP * NT, 64, 0, stream>>>(V_feat, VB, V0B);
  l2n_init_kernel<<<B_EP * NWAYS, 64, 0, stream>>>(P_feat, PB, P0B);
  cvt_bf16_kernel<<<(int)(wsz / 8 / 256), 256, 0, stream>>>(igb_W, WB,
                                                            (int)(wsz / 8));
  cvt_bf16_kernel<<<(int)(wsz / 8 / 256), 256, 0, stream>>>(pgb_W, WPB,
                                                            (int)(wsz / 8));

  for (int i = 0; i < NLAYERS; ++i) {
    sim_mfma_kernel<<<9 * B_EP, 64, 0, stream>>>(VB, SIM);
    topk_msg_kernel<<<8 * B_EP, 256, 0, stream>>>(SIM, VB, MSGB);
    gemm_fused_kernel<<<B_EP * NT / 64, 512, 0, stream>>>(
        MSGB, WB + (size_t)i * DIM * DIM, igb_b + (size_t)i * DIM, igb_s + i,
        VB, V0B);

    p_branch_kernel<<<B_EP, 64, 0, stream>>>(PB, PMSGB);
    gemm_fused_kernel<<<B_EP * NWAYS / 64, 512, 0, stream>>>(
        PMSGB, WPB + (size_t)i * DIM * DIM, pgb_b + (size_t)i * DIM, pgb_s + i,
        PB, P0B);

    vcpa_kernel<<<B_EP * NWAYS, 64, 0, stream>>>(VB, PB, alpha, PAB);

    sims_kernel<<<dim3(3, B_EP), 64, 0, stream>>>(VB, PAB, SIMS);
    gram_kernel<<<B_EP, 64, 0, stream>>>(PAB, G);
    softce_kernel<<<dim3(B_EP, 4), 256, 0, stream>>>(
        SIMS, G, query_y, beta, S, INVN, ACC, (i == NLAYERS - 1) ? 1 : 0);
    vupdate_kernel<<<dim3(B_EP, 7), 256, 0, stream>>>(VB, PAB, S, INVN, beta);
  }
  finalize_kernel<<<1, 1, 0, stream>>>(ACC, out);
}